// Round 1
// baseline (879.069 us; speedup 1.0000x reference)
//
#include <hip/hip_runtime.h>
#include <math.h>

// ---------------------------------------------------------------------------
// FastNN: sparse block conv net, fp32 baseline.
// Stage kernels: one 256-thread workgroup per 16x16 block, fully fused:
//   conv1x1 -> [active? bottleneck(1x1, 3x3-in-block, 1x1)] -> maxpool2.
// Weights pre-transposed (prep kernel) to [ci][tap][co] so inner-loop weight
// reads are wave-uniform scalar loads; activations in padded LDS (stride 36
// floats -> only 2-way bank aliasing, free on CDNA4).
// ---------------------------------------------------------------------------

// ws layout (float offsets)
#define X1P_OFF 0           // [16][16][16][16][16][16] = 16,777,216 floats (stage1 pooled, pre-blocked)
#define X2_OFF  16777216    // [16][8][128][128] = 2,097,152 floats (stage2 pooled, NCHW)
#define LG_OFF  18874368    // 160 logits
#define P_OFF   18874624    // prepped params

// param region offsets (floats, within P)
enum : int {
  WT_S1D2 = 0,        // [ci32][9][co32] = 9216
  WT_S2D2 = 9216,     // [ci16][9][co16] = 2304
  WT_S1D1 = 11520,    // [ci16][co32]    = 512
  WT_S1D3 = 12032,    // [ci32][co16]    = 512
  WT_S1C  = 12544,    // [ci3][co16]     = 48
  WT_S2C  = 12592,    // [ci16][co8]     = 128
  WT_S2D1 = 12720,    // [ci8][co16]     = 128
  WT_S2D3 = 12848,    // [ci16][co8]     = 128
  SC_S1BN0 = 12976,   // scale16+shift16
  SC_S1BN1 = 13008,   // 32+32
  SC_S1BN2 = 13072,   // 32+32
  SC_S1BN3 = 13136,   // 16+16
  SC_S2BN0 = 13168,   // 8+8
  SC_S2BN1 = 13184,   // 16+16
  SC_S2BN2 = 13216,   // 16+16
  SC_S2BN3 = 13248,   // 8+8
  P_TOTAL  = 13264
};

__device__ __forceinline__ float relu_f(float v) { return v > 0.f ? v : 0.f; }

__device__ __forceinline__ void prep_bn(const float* __restrict__ p, int C,
                                        float* __restrict__ dst, int t) {
  for (int i = t; i < C; i += 256) {
    float g = p[i], b = p[C + i], m = p[2 * C + i], v = p[3 * C + i];
    float s = g / sqrtf(v + 1e-5f);
    dst[i] = s;
    dst[C + i] = b - s * m;
  }
}

__global__ __launch_bounds__(256) void prep_kernel(
    const float* __restrict__ s1_cw, const float* __restrict__ s1_d1w,
    const float* __restrict__ s1_d2w, const float* __restrict__ s1_d3w,
    const float* __restrict__ s2_cw, const float* __restrict__ s2_d1w,
    const float* __restrict__ s2_d2w, const float* __restrict__ s2_d3w,
    const float* __restrict__ s1_bn0, const float* __restrict__ s1_bn1,
    const float* __restrict__ s1_bn2, const float* __restrict__ s1_bn3,
    const float* __restrict__ s2_bn0, const float* __restrict__ s2_bn1,
    const float* __restrict__ s2_bn2, const float* __restrict__ s2_bn3,
    float* __restrict__ P) {
  const int t = threadIdx.x;
  for (int i = t; i < 9216; i += 256) { int co = i / 288, r = i % 288, ci = r / 9, pos = r % 9;
    P[WT_S1D2 + (ci * 9 + pos) * 32 + co] = s1_d2w[i]; }
  for (int i = t; i < 2304; i += 256) { int co = i / 144, r = i % 144, ci = r / 9, pos = r % 9;
    P[WT_S2D2 + (ci * 9 + pos) * 16 + co] = s2_d2w[i]; }
  for (int i = t; i < 512; i += 256) { int co = i / 16, ci = i % 16; P[WT_S1D1 + ci * 32 + co] = s1_d1w[i]; }
  for (int i = t; i < 512; i += 256) { int co = i / 32, ci = i % 32; P[WT_S1D3 + ci * 16 + co] = s1_d3w[i]; }
  for (int i = t; i < 48;  i += 256) { int co = i / 3,  ci = i % 3;  P[WT_S1C  + ci * 16 + co] = s1_cw[i]; }
  for (int i = t; i < 128; i += 256) { int co = i / 16, ci = i % 16; P[WT_S2C  + ci * 8  + co] = s2_cw[i]; }
  for (int i = t; i < 128; i += 256) { int co = i / 8,  ci = i % 8;  P[WT_S2D1 + ci * 16 + co] = s2_d1w[i]; }
  for (int i = t; i < 128; i += 256) { int co = i / 16, ci = i % 16; P[WT_S2D3 + ci * 8  + co] = s2_d3w[i]; }
  prep_bn(s1_bn0, 16, P + SC_S1BN0, t);
  prep_bn(s1_bn1, 32, P + SC_S1BN1, t);
  prep_bn(s1_bn2, 32, P + SC_S1BN2, t);
  prep_bn(s1_bn3, 16, P + SC_S1BN3, t);
  prep_bn(s2_bn0, 8,  P + SC_S2BN0, t);
  prep_bn(s2_bn1, 16, P + SC_S2BN1, t);
  prep_bn(s2_bn2, 16, P + SC_S2BN2, t);
  prep_bn(s2_bn3, 8,  P + SC_S2BN3, t);
}

// ---------------- stage 1: 512x512, 3 -> 16 ch, blocks 16x16 ----------------
__global__ __launch_bounds__(256) void stage1_kernel(
    const float* __restrict__ x, const float* __restrict__ mask,
    const float* __restrict__ cb, const float* __restrict__ d1b,
    const float* __restrict__ d2b, const float* __restrict__ d3b,
    const float* __restrict__ P, float* __restrict__ x1p) {
  __shared__ float lds[11664];  // [18][18][36] padded activations, 46.6 KB
  __shared__ float red[4];
  __shared__ int actflag;

  const int t = threadIdx.x;
  const int ty = t >> 4, tx = t & 15;
  const int b = blockIdx.x;
  const int n = b >> 10;
  const int by = (b >> 5) & 31, bx = b & 31;
  const int gy = by * 16 + ty, gx = bx * 16 + tx;

  // --- block active = mean(mask block) > 0.5  <=>  sum > 128
  float s = mask[(size_t)(n * 512 + gy) * 512 + gx];
  #pragma unroll
  for (int off = 32; off > 0; off >>= 1) s += __shfl_down(s, off, 64);
  if ((t & 63) == 0) red[t >> 6] = s;
  __syncthreads();
  if (t == 0) actflag = (red[0] + red[1] + red[2] + red[3]) > 128.0f;
  __syncthreads();
  const bool active = (actflag != 0);

  // --- input pixel (3 ch)
  float xin[3];
  #pragma unroll
  for (int c = 0; c < 3; ++c)
    xin[c] = x[(size_t)((n * 3 + c) * 512 + gy) * 512 + gx];

  // --- conv1x1 3->16 + bias, relu, bn0
  const float* wc = P + WT_S1C;
  const float* sc0 = P + SC_S1BN0;
  float xc[16];
  {
    float a[16];
    #pragma unroll
    for (int o = 0; o < 16; ++o) a[o] = cb[o];
    #pragma unroll
    for (int c = 0; c < 3; ++c) {
      const float v = xin[c];
      #pragma unroll
      for (int o = 0; o < 16; ++o) a[o] = fmaf(wc[c * 16 + o], v, a[o]);
    }
    #pragma unroll
    for (int o = 0; o < 16; ++o) xc[o] = fmaf(sc0[o], relu_f(a[o]), sc0[16 + o]);
  }

  float out[16];
  if (active) {
    // conv1x1 16->32 + bias, relu, bn1
    const float* w1 = P + WT_S1D1;
    const float* sc1 = P + SC_S1BN1;
    float g1[32];
    #pragma unroll
    for (int o = 0; o < 32; ++o) g1[o] = d1b[o];
    #pragma unroll
    for (int c = 0; c < 16; ++c) {
      const float v = xc[c];
      #pragma unroll
      for (int o = 0; o < 32; ++o) g1[o] = fmaf(w1[c * 32 + o], v, g1[o]);
    }
    #pragma unroll
    for (int o = 0; o < 32; ++o) g1[o] = fmaf(sc1[o], relu_f(g1[o]), sc1[32 + o]);

    // zero padded LDS, then write interior [ty+1][tx+1][0..32]
    const float4 z4 = make_float4(0.f, 0.f, 0.f, 0.f);
    for (int i = t; i < 2916; i += 256) ((float4*)lds)[i] = z4;
    __syncthreads();
    {
      float* dst = &lds[((ty + 1) * 18 + (tx + 1)) * 36];
      #pragma unroll
      for (int k = 0; k < 8; ++k)
        ((float4*)dst)[k] = make_float4(g1[4 * k], g1[4 * k + 1], g1[4 * k + 2], g1[4 * k + 3]);
    }
    __syncthreads();

    // conv3x3 32->32 (zero pad at block edge via halo)
    float acc[32];
    #pragma unroll
    for (int o = 0; o < 32; ++o) acc[o] = d2b[o];
    for (int dy = 0; dy < 3; ++dy)
      for (int dx = 0; dx < 3; ++dx) {
        const float* arow = &lds[((ty + dy) * 18 + (tx + dx)) * 36];
        const float* wp = P + WT_S1D2 + (dy * 3 + dx) * 32;  // + ci*288 + co
        #pragma unroll
        for (int c4 = 0; c4 < 8; ++c4) {
          const float4 a4 = *(const float4*)(arow + c4 * 4);
          const float av[4] = {a4.x, a4.y, a4.z, a4.w};
          #pragma unroll
          for (int e = 0; e < 4; ++e) {
            const float* wr = wp + (c4 * 4 + e) * 288;
            const float v = av[e];
            #pragma unroll
            for (int o = 0; o < 32; ++o) acc[o] = fmaf(wr[o], v, acc[o]);
          }
        }
      }
    const float* sc2 = P + SC_S1BN2;
    float g2[32];
    #pragma unroll
    for (int o = 0; o < 32; ++o) g2[o] = fmaf(sc2[o], relu_f(acc[o]), sc2[32 + o]);

    // conv1x1 32->16 + bias, relu, bn3
    const float* w3 = P + WT_S1D3;
    const float* sc3 = P + SC_S1BN3;
    float a3[16];
    #pragma unroll
    for (int o = 0; o < 16; ++o) a3[o] = d3b[o];
    #pragma unroll
    for (int c = 0; c < 32; ++c) {
      const float v = g2[c];
      #pragma unroll
      for (int o = 0; o < 16; ++o) a3[o] = fmaf(w3[c * 16 + o], v, a3[o]);
    }
    #pragma unroll
    for (int o = 0; o < 16; ++o) out[o] = fmaf(sc3[o], relu_f(a3[o]), sc3[16 + o]);
  } else {
    #pragma unroll
    for (int o = 0; o < 16; ++o) out[o] = xc[o];
  }

  // --- maxpool 2x2 within block -> x1p[n][by/2][bx/2][c][(by&1)*8+py][(bx&1)*8+px]
  __syncthreads();  // protect LDS reuse (branch is block-uniform)
  {
    float* pw = &lds[t * 20];
    #pragma unroll
    for (int c = 0; c < 16; ++c) pw[c] = out[c];
  }
  __syncthreads();
  {
    const int pp = t & 63, cg = t >> 6;          // 64 px * 4 channel-groups
    const int py = pp >> 3, px = pp & 7;
    const float* r0 = &lds[((2 * py) * 16 + 2 * px) * 20 + cg * 4];
    const float* r2 = &lds[((2 * py + 1) * 16 + 2 * px) * 20 + cg * 4];
    const float4 v0 = *(const float4*)(r0);
    const float4 v1 = *(const float4*)(r0 + 20);
    const float4 v2 = *(const float4*)(r2);
    const float4 v3 = *(const float4*)(r2 + 20);
    const float m0 = fmaxf(fmaxf(v0.x, v1.x), fmaxf(v2.x, v3.x));
    const float m1 = fmaxf(fmaxf(v0.y, v1.y), fmaxf(v2.y, v3.y));
    const float m2 = fmaxf(fmaxf(v0.z, v1.z), fmaxf(v2.z, v3.z));
    const float m3 = fmaxf(fmaxf(v0.w, v1.w), fmaxf(v2.w, v3.w));
    const size_t ob = ((((size_t)n * 16 + (by >> 1)) * 16 + (bx >> 1)) * 16 + cg * 4) * 256
                      + (size_t)((by & 1) * 8 + py) * 16 + ((bx & 1) * 8 + px);
    x1p[ob]       = m0;
    x1p[ob + 256] = m1;
    x1p[ob + 512] = m2;
    x1p[ob + 768] = m3;
  }
}

// ---------------- stage 2: 256x256, 16 -> 8 ch, blocks 16x16 ----------------
__global__ __launch_bounds__(256) void stage2_kernel(
    const float* __restrict__ mask,
    const float* __restrict__ cb, const float* __restrict__ d1b,
    const float* __restrict__ d2b, const float* __restrict__ d3b,
    const float* __restrict__ P, const float* __restrict__ x1p,
    float* __restrict__ x2) {
  __shared__ float lds[6480];  // [18][18][20]
  __shared__ float red[4];
  __shared__ int actflag;

  const int t = threadIdx.x;
  const int ty = t >> 4, tx = t & 15;
  const int b = blockIdx.x;
  const int n = b >> 8;
  const int BY = (b >> 4) & 15, BX = b & 15;

  // mask2 = maxpool2(mask); active = mean over 16x16 of mask2 > 0.5
  const int my = (BY * 16 + ty) * 2, mx = (BX * 16 + tx) * 2;
  const float* mp = &mask[(size_t)(n * 512 + my) * 512 + mx];
  float s = fmaxf(fmaxf(mp[0], mp[1]), fmaxf(mp[512], mp[513]));
  #pragma unroll
  for (int off = 32; off > 0; off >>= 1) s += __shfl_down(s, off, 64);
  if ((t & 63) == 0) red[t >> 6] = s;
  __syncthreads();
  if (t == 0) actflag = (red[0] + red[1] + red[2] + red[3]) > 128.0f;
  __syncthreads();
  const bool active = (actflag != 0);

  // load x1 (16 ch) from pre-blocked layout (contiguous per block)
  const float* xb = x1p + (size_t)((n * 16 + BY) * 16 + BX) * 4096 + ty * 16 + tx;
  float xin[16];
  #pragma unroll
  for (int c = 0; c < 16; ++c) xin[c] = xb[c * 256];

  const float* wc = P + WT_S2C;
  const float* sc0 = P + SC_S2BN0;
  float xc[8];
  {
    float a[8];
    #pragma unroll
    for (int o = 0; o < 8; ++o) a[o] = cb[o];
    #pragma unroll
    for (int c = 0; c < 16; ++c) {
      const float v = xin[c];
      #pragma unroll
      for (int o = 0; o < 8; ++o) a[o] = fmaf(wc[c * 8 + o], v, a[o]);
    }
    #pragma unroll
    for (int o = 0; o < 8; ++o) xc[o] = fmaf(sc0[o], relu_f(a[o]), sc0[8 + o]);
  }

  float out[8];
  if (active) {
    const float* w1 = P + WT_S2D1;
    const float* sc1 = P + SC_S2BN1;
    float g1[16];
    #pragma unroll
    for (int o = 0; o < 16; ++o) g1[o] = d1b[o];
    #pragma unroll
    for (int c = 0; c < 8; ++c) {
      const float v = xc[c];
      #pragma unroll
      for (int o = 0; o < 16; ++o) g1[o] = fmaf(w1[c * 16 + o], v, g1[o]);
    }
    #pragma unroll
    for (int o = 0; o < 16; ++o) g1[o] = fmaf(sc1[o], relu_f(g1[o]), sc1[16 + o]);

    const float4 z4 = make_float4(0.f, 0.f, 0.f, 0.f);
    for (int i = t; i < 1620; i += 256) ((float4*)lds)[i] = z4;
    __syncthreads();
    {
      float* dst = &lds[((ty + 1) * 18 + (tx + 1)) * 20];
      #pragma unroll
      for (int k = 0; k < 4; ++k)
        ((float4*)dst)[k] = make_float4(g1[4 * k], g1[4 * k + 1], g1[4 * k + 2], g1[4 * k + 3]);
    }
    __syncthreads();

    float acc[16];
    #pragma unroll
    for (int o = 0; o < 16; ++o) acc[o] = d2b[o];
    for (int dy = 0; dy < 3; ++dy)
      for (int dx = 0; dx < 3; ++dx) {
        const float* arow = &lds[((ty + dy) * 18 + (tx + dx)) * 20];
        const float* wp = P + WT_S2D2 + (dy * 3 + dx) * 16;  // + ci*144 + co
        #pragma unroll
        for (int c4 = 0; c4 < 4; ++c4) {
          const float4 a4 = *(const float4*)(arow + c4 * 4);
          const float av[4] = {a4.x, a4.y, a4.z, a4.w};
          #pragma unroll
          for (int e = 0; e < 4; ++e) {
            const float* wr = wp + (c4 * 4 + e) * 144;
            const float v = av[e];
            #pragma unroll
            for (int o = 0; o < 16; ++o) acc[o] = fmaf(wr[o], v, acc[o]);
          }
        }
      }
    const float* sc2 = P + SC_S2BN2;
    float g2[16];
    #pragma unroll
    for (int o = 0; o < 16; ++o) g2[o] = fmaf(sc2[o], relu_f(acc[o]), sc2[16 + o]);

    const float* w3 = P + WT_S2D3;
    const float* sc3 = P + SC_S2BN3;
    float a3[8];
    #pragma unroll
    for (int o = 0; o < 8; ++o) a3[o] = d3b[o];
    #pragma unroll
    for (int c = 0; c < 16; ++c) {
      const float v = g2[c];
      #pragma unroll
      for (int o = 0; o < 8; ++o) a3[o] = fmaf(w3[c * 8 + o], v, a3[o]);
    }
    #pragma unroll
    for (int o = 0; o < 8; ++o) out[o] = fmaf(sc3[o], relu_f(a3[o]), sc3[8 + o]);
  } else {
    #pragma unroll
    for (int o = 0; o < 8; ++o) out[o] = xc[o];
  }

  __syncthreads();
  {
    float* pw = &lds[t * 12];
    #pragma unroll
    for (int c = 0; c < 8; ++c) pw[c] = out[c];
  }
  __syncthreads();
  if (t < 128) {
    const int pp = t & 63, cg = t >> 6;  // 64 px * 2 channel-groups
    const int py = pp >> 3, px = pp & 7;
    const float* r0 = &lds[((2 * py) * 16 + 2 * px) * 12 + cg * 4];
    const float* r2 = &lds[((2 * py + 1) * 16 + 2 * px) * 12 + cg * 4];
    const float4 v0 = *(const float4*)(r0);
    const float4 v1 = *(const float4*)(r0 + 12);
    const float4 v2 = *(const float4*)(r2);
    const float4 v3 = *(const float4*)(r2 + 12);
    const float m0 = fmaxf(fmaxf(v0.x, v1.x), fmaxf(v2.x, v3.x));
    const float m1 = fmaxf(fmaxf(v0.y, v1.y), fmaxf(v2.y, v3.y));
    const float m2 = fmaxf(fmaxf(v0.z, v1.z), fmaxf(v2.z, v3.z));
    const float m3 = fmaxf(fmaxf(v0.w, v1.w), fmaxf(v2.w, v3.w));
    // x2 NCHW [16][8][128][128] so FC flatten order matches reference
    const size_t ob = ((size_t)(n * 8 + cg * 4) * 128 + (BY * 8 + py)) * 128 + BX * 8 + px;
    x2[ob]         = m0;
    x2[ob + 16384] = m1;
    x2[ob + 32768] = m2;
    x2[ob + 49152] = m3;
  }
}

// ---------------- FC: logits[n][k] = x2[n] . fc_w[k] + fc_b[k] ----------------
__global__ __launch_bounds__(256) void fc_kernel(const float* __restrict__ x2,
                                                 const float* __restrict__ fcw,
                                                 const float* __restrict__ fcb,
                                                 float* __restrict__ logits) {
  __shared__ float red[4];
  const int wg = blockIdx.x, n = wg / 10, k = wg % 10, t = threadIdx.x;
  const float4* xa = (const float4*)(x2 + (size_t)n * 131072);
  const float4* wa = (const float4*)(fcw + (size_t)k * 131072);
  float s = 0.f;
  for (int i = t; i < 32768; i += 256) {
    const float4 a = xa[i], b = wa[i];
    s = fmaf(a.x, b.x, fmaf(a.y, b.y, fmaf(a.z, b.z, fmaf(a.w, b.w, s))));
  }
  #pragma unroll
  for (int off = 32; off > 0; off >>= 1) s += __shfl_down(s, off, 64);
  if ((t & 63) == 0) red[t >> 6] = s;
  __syncthreads();
  if (t == 0) logits[n * 10 + k] = red[0] + red[1] + red[2] + red[3] + fcb[k];
}

__global__ void softmax_kernel(const float* __restrict__ logits, float* __restrict__ out) {
  const int t = threadIdx.x;
  if (t < 16) {
    float l[10], mx = -1e30f;
    #pragma unroll
    for (int k = 0; k < 10; ++k) { l[k] = logits[t * 10 + k]; mx = fmaxf(mx, l[k]); }
    float sum = 0.f;
    #pragma unroll
    for (int k = 0; k < 10; ++k) { l[k] = expf(l[k] - mx); sum += l[k]; }
    const float inv = 1.f / sum;
    #pragma unroll
    for (int k = 0; k < 10; ++k) out[t * 10 + k] = l[k] * inv;
  }
}

extern "C" void kernel_launch(void* const* d_in, const int* in_sizes, int n_in,
                              void* d_out, int out_size, void* d_ws, size_t ws_size,
                              hipStream_t stream) {
  const float* x      = (const float*)d_in[0];
  const float* mask   = (const float*)d_in[1];
  const float* s1_cw  = (const float*)d_in[2];
  const float* s1_cb  = (const float*)d_in[3];
  const float* s1_bn0 = (const float*)d_in[4];
  const float* s1_d1w = (const float*)d_in[5];
  const float* s1_d1b = (const float*)d_in[6];
  const float* s1_bn1 = (const float*)d_in[7];
  const float* s1_d2w = (const float*)d_in[8];
  const float* s1_d2b = (const float*)d_in[9];
  const float* s1_bn2 = (const float*)d_in[10];
  const float* s1_d3w = (const float*)d_in[11];
  const float* s1_d3b = (const float*)d_in[12];
  const float* s1_bn3 = (const float*)d_in[13];
  const float* s2_cw  = (const float*)d_in[14];
  const float* s2_cb  = (const float*)d_in[15];
  const float* s2_bn0 = (const float*)d_in[16];
  const float* s2_d1w = (const float*)d_in[17];
  const float* s2_d1b = (const float*)d_in[18];
  const float* s2_bn1 = (const float*)d_in[19];
  const float* s2_d2w = (const float*)d_in[20];
  const float* s2_d2b = (const float*)d_in[21];
  const float* s2_bn2 = (const float*)d_in[22];
  const float* s2_d3w = (const float*)d_in[23];
  const float* s2_d3b = (const float*)d_in[24];
  const float* s2_bn3 = (const float*)d_in[25];
  const float* fc_w   = (const float*)d_in[26];
  const float* fc_b   = (const float*)d_in[27];

  float* ws  = (float*)d_ws;
  float* x1p = ws + X1P_OFF;
  float* x2  = ws + X2_OFF;
  float* lg  = ws + LG_OFF;
  float* P   = ws + P_OFF;

  prep_kernel<<<1, 256, 0, stream>>>(s1_cw, s1_d1w, s1_d2w, s1_d3w,
                                     s2_cw, s2_d1w, s2_d2w, s2_d3w,
                                     s1_bn0, s1_bn1, s1_bn2, s1_bn3,
                                     s2_bn0, s2_bn1, s2_bn2, s2_bn3, P);
  stage1_kernel<<<16 * 32 * 32, 256, 0, stream>>>(x, mask, s1_cb, s1_d1b, s1_d2b, s1_d3b, P, x1p);
  stage2_kernel<<<16 * 16 * 16, 256, 0, stream>>>(mask, s2_cb, s2_d1b, s2_d2b, s2_d3b, P, x1p, x2);
  fc_kernel<<<160, 256, 0, stream>>>(x2, fc_w, fc_b, lg);
  softmax_kernel<<<1, 64, 0, stream>>>(lg, (float*)d_out);
}

// Round 2
// 446.294 us; speedup vs baseline: 1.9697x; 1.9697x over previous
//
#include <hip/hip_runtime.h>
#include <math.h>

// ---------------------------------------------------------------------------
// FastNN: sparse block conv net. MFMA version.
// Stage kernels: one 256-thread workgroup per 16x16 block, fully fused:
//   conv1x1 (VALU) -> [active? d1 1x1 (VALU) -> 3x3 (MFMA bf16) -> d3 1x1
//   (MFMA bf16)] -> maxpool2 (in-lane for active path).
// 3x3-in-block as per-block GEMM: M=256 px, N=co, K = taps*ci; each K-step of
// 32 is one tap reading a shifted window of the padded LDS activation tile.
// MFMA layouts (m89/m91-verified): A: row=lane&15, k=(lane>>4)*8+j;
// B: n=lane&15, k=(lane>>4)*8+j; D: col=lane&15, row=(lane>>4)*4+reg.
// ---------------------------------------------------------------------------

typedef __attribute__((ext_vector_type(8))) short bf16x8;
typedef __attribute__((ext_vector_type(4))) float f32x4;

// ws layout (float offsets)
#define X1P_OFF 0           // [16][16][16][16][16][16] stage1 pooled, pre-blocked
#define X2_OFF  16777216    // [16][8][128][128] stage2 pooled, NCHW
#define LG_OFF  18874368    // 160 logits
#define P_OFF   18874624    // prepped params (f32 region, then bf16 region)

// f32 param region offsets (floats, within P)
enum : int {
  WT_S1D1 = 11520,    // [ci16][co32] = 512
  WT_S1C  = 12544,    // [ci3][co16]  = 48
  WT_S2C  = 12592,    // [ci16][co8]  = 128
  WT_S2D1 = 12720,    // [ci8][co16]  = 128
  SC_S1BN0 = 12976,   // scale16+shift16
  SC_S1BN1 = 13008,   // 32+32
  SC_S1BN2 = 13072,   // 32+32
  SC_S1BN3 = 13136,   // 16+16
  SC_S2BN0 = 13168,   // 8+8
  SC_S2BN1 = 13184,   // 16+16
  SC_S2BN2 = 13216,   // 16+16
  SC_S2BN3 = 13248,   // 8+8
  PH_F     = 13264    // bf16 (ushort) region starts here (float offset)
};
// bf16 region offsets (ushorts, within PH)
enum : int {
  H_S1D2 = 0,       // [9 tap][32 co][32 ci] = 9216
  H_S1D3 = 9216,    // [16 co][32 ci]        = 512
  H_S2D2 = 9728,    // [5 pair][16 co][32 k] = 2560 (k<16: tap 2p, k>=16: tap 2p+1; pair4 hi = 0)
  H_S2D3 = 12288,   // [16 n][16 k]          = 256  (n>=8 zero)
  PH_TOTAL = 12544
};

__device__ __forceinline__ float relu_f(float v) { return v > 0.f ? v : 0.f; }

__device__ __forceinline__ unsigned short f2bf(float f) {
  unsigned int u = __float_as_uint(f);
  unsigned int r = (u + 0x7fffu + ((u >> 16) & 1u)) >> 16;  // RNE
  return (unsigned short)r;
}

__device__ __forceinline__ void prep_bn(const float* __restrict__ p, int C,
                                        float* __restrict__ dst, int t) {
  for (int i = t; i < C; i += 256) {
    float g = p[i], b = p[C + i], m = p[2 * C + i], v = p[3 * C + i];
    float s = g / sqrtf(v + 1e-5f);
    dst[i] = s;
    dst[C + i] = b - s * m;
  }
}

__global__ __launch_bounds__(256) void prep_kernel(
    const float* __restrict__ s1_cw, const float* __restrict__ s1_d1w,
    const float* __restrict__ s1_d2w, const float* __restrict__ s1_d3w,
    const float* __restrict__ s2_cw, const float* __restrict__ s2_d1w,
    const float* __restrict__ s2_d2w, const float* __restrict__ s2_d3w,
    const float* __restrict__ s1_bn0, const float* __restrict__ s1_bn1,
    const float* __restrict__ s1_bn2, const float* __restrict__ s1_bn3,
    const float* __restrict__ s2_bn0, const float* __restrict__ s2_bn1,
    const float* __restrict__ s2_bn2, const float* __restrict__ s2_bn3,
    float* __restrict__ P) {
  const int t = threadIdx.x;
  unsigned short* PH = (unsigned short*)(P + PH_F);
  // f32 weights for VALU 1x1s: [ci][co] transposes
  for (int i = t; i < 512; i += 256) { int co = i / 16, ci = i % 16; P[WT_S1D1 + ci * 32 + co] = s1_d1w[i]; }
  for (int i = t; i < 48;  i += 256) { int co = i / 3,  ci = i % 3;  P[WT_S1C  + ci * 16 + co] = s1_cw[i]; }
  for (int i = t; i < 128; i += 256) { int co = i / 16, ci = i % 16; P[WT_S2C  + ci * 8  + co] = s2_cw[i]; }
  for (int i = t; i < 128; i += 256) { int co = i / 8,  ci = i % 8;  P[WT_S2D1 + ci * 16 + co] = s2_d1w[i]; }
  // bf16 MFMA B matrices
  // s1_d2w [32o][32i][3][3] -> [tap][o][i]
  for (int i = t; i < 9216; i += 256) {
    int tap = i >> 10, o = (i >> 5) & 31, ci = i & 31;
    PH[H_S1D2 + i] = f2bf(s1_d2w[o * 288 + ci * 9 + tap]);
  }
  // s1_d3w [16o][32i] -> [o][i]
  for (int i = t; i < 512; i += 256) PH[H_S1D3 + i] = f2bf(s1_d3w[i]);
  // s2_d2w [16o][16i][3][3] -> [pair][o][k32]
  for (int i = t; i < 2560; i += 256) {
    int p = i >> 9, o = (i >> 5) & 15, k = i & 31;
    int tp = 2 * p + (k >> 4);
    PH[H_S2D2 + i] = (tp < 9) ? f2bf(s2_d2w[o * 144 + (k & 15) * 9 + tp]) : 0;
  }
  // s2_d3w [8o][16i] -> [n16][k16], n>=8 zero
  for (int i = t; i < 256; i += 256) {
    int n = i >> 4, k = i & 15;
    PH[H_S2D3 + i] = (n < 8) ? f2bf(s2_d3w[n * 16 + k]) : 0;
  }
  prep_bn(s1_bn0, 16, P + SC_S1BN0, t);
  prep_bn(s1_bn1, 32, P + SC_S1BN1, t);
  prep_bn(s1_bn2, 32, P + SC_S1BN2, t);
  prep_bn(s1_bn3, 16, P + SC_S1BN3, t);
  prep_bn(s2_bn0, 8,  P + SC_S2BN0, t);
  prep_bn(s2_bn1, 16, P + SC_S2BN1, t);
  prep_bn(s2_bn2, 16, P + SC_S2BN2, t);
  prep_bn(s2_bn3, 8,  P + SC_S2BN3, t);
}

// ---------------- stage 1: 512x512, 3 -> 16 ch, blocks 16x16 ----------------
// LDS activation tile: bf16 [18 rows][18 cols][40 ch-pad] = 25920 B.
// Pixel stride 80 B (16B-aligned b128 ops; bank starts px*20 mod 32 -> 2-way).
__global__ __launch_bounds__(256, 3) void stage1_kernel(
    const float* __restrict__ x, const float* __restrict__ mask,
    const float* __restrict__ cbv, const float* __restrict__ d1b,
    const float* __restrict__ d2b, const float* __restrict__ d3b,
    const float* __restrict__ P, float* __restrict__ x1p) {
  __shared__ __align__(16) unsigned char ldsb[25920];
  __shared__ float red[4];
  __shared__ int actflag;

  const int t = threadIdx.x;
  const int ty = t >> 4, tx = t & 15;
  const int b = blockIdx.x;
  const int n = b >> 10;
  const int by = (b >> 5) & 31, bx = b & 31;
  const int gy = by * 16 + ty, gx = bx * 16 + tx;

  // --- block active = mean(mask block) > 0.5  <=>  sum > 128
  float s = mask[(size_t)(n * 512 + gy) * 512 + gx];
  #pragma unroll
  for (int off = 32; off > 0; off >>= 1) s += __shfl_down(s, off, 64);
  if ((t & 63) == 0) red[t >> 6] = s;
  __syncthreads();
  if (t == 0) actflag = (red[0] + red[1] + red[2] + red[3]) > 128.0f;
  __syncthreads();
  const bool active = (actflag != 0);

  // --- input pixel (3 ch)
  float xin[3];
  #pragma unroll
  for (int c = 0; c < 3; ++c)
    xin[c] = x[(size_t)((n * 3 + c) * 512 + gy) * 512 + gx];

  // --- conv1x1 3->16 + bias, relu, bn0
  const float* wc = P + WT_S1C;
  const float* sc0 = P + SC_S1BN0;
  float xc[16];
  {
    float a[16];
    #pragma unroll
    for (int o = 0; o < 16; ++o) a[o] = cbv[o];
    #pragma unroll
    for (int c = 0; c < 3; ++c) {
      const float v = xin[c];
      #pragma unroll
      for (int o = 0; o < 16; ++o) a[o] = fmaf(wc[c * 16 + o], v, a[o]);
    }
    #pragma unroll
    for (int o = 0; o < 16; ++o) xc[o] = fmaf(sc0[o], relu_f(a[o]), sc0[16 + o]);
  }

  if (active) {
    const int w = t >> 6, lane = t & 63;
    const int lr = lane & 15, cb = lane >> 4;
    const unsigned short* PH = (const unsigned short*)(P + PH_F);

    // resident MFMA B fragments (L1/L2-hot; issued early to hide under VALU)
    bf16x8 bw[9][2];
    #pragma unroll
    for (int tap = 0; tap < 9; ++tap)
      #pragma unroll
      for (int nt = 0; nt < 2; ++nt)
        bw[tap][nt] = *(const bf16x8*)(PH + H_S1D2 + ((tap * 32 + nt * 16 + lr) * 32 + cb * 8));
    bf16x8 b3 = *(const bf16x8*)(PH + H_S1D3 + lr * 32 + cb * 8);
    const float bias2[2] = { d2b[lr], d2b[16 + lr] };
    const float bias3v = d3b[lr];
    const float sc2v[2] = { P[SC_S1BN2 + lr], P[SC_S1BN2 + 16 + lr] };
    const float sh2v[2] = { P[SC_S1BN2 + 32 + lr], P[SC_S1BN2 + 48 + lr] };
    const float sc3v = P[SC_S1BN3 + lr], sh3v = P[SC_S1BN3 + 16 + lr];

    // --- d1: conv1x1 16->32 + bias, relu, bn1 (VALU, pixel-per-thread)
    const float* w1 = P + WT_S1D1;
    const float* sc1 = P + SC_S1BN1;
    float g1[32];
    #pragma unroll
    for (int o = 0; o < 32; ++o) g1[o] = d1b[o];
    #pragma unroll
    for (int c = 0; c < 16; ++c) {
      const float v = xc[c];
      #pragma unroll
      for (int o = 0; o < 32; ++o) g1[o] = fmaf(w1[c * 32 + o], v, g1[o]);
    }
    #pragma unroll
    for (int o = 0; o < 32; ++o) g1[o] = fmaf(sc1[o], relu_f(g1[o]), sc1[32 + o]);

    // --- zero padded LDS tile (halo), then write interior as bf16
    {
      const uint4 z4 = make_uint4(0u, 0u, 0u, 0u);
      for (int i = t; i < 1620; i += 256) ((uint4*)ldsb)[i] = z4;
    }
    __syncthreads();
    {
      unsigned int pk[16];
      #pragma unroll
      for (int i = 0; i < 16; ++i)
        pk[i] = (unsigned int)f2bf(g1[2 * i]) | ((unsigned int)f2bf(g1[2 * i + 1]) << 16);
      uint4* dst = (uint4*)(ldsb + ((ty + 1) * 18 + (tx + 1)) * 80);
      dst[0] = make_uint4(pk[0], pk[1], pk[2], pk[3]);
      dst[1] = make_uint4(pk[4], pk[5], pk[6], pk[7]);
      dst[2] = make_uint4(pk[8], pk[9], pk[10], pk[11]);
      dst[3] = make_uint4(pk[12], pk[13], pk[14], pk[15]);
    }
    __syncthreads();

    // --- 3x3 conv as MFMA GEMM: per wave 4 m-tiles x 2 n-tiles, K-step = tap
    f32x4 acc[4][2];
    #pragma unroll
    for (int mt = 0; mt < 4; ++mt)
      #pragma unroll
      for (int nt = 0; nt < 2; ++nt) {
        const float bz = bias2[nt];
        acc[mt][nt][0] = bz; acc[mt][nt][1] = bz; acc[mt][nt][2] = bz; acc[mt][nt][3] = bz;
      }
    #pragma unroll
    for (int tap = 0; tap < 9; ++tap) {
      const int dy = tap / 3, dx = tap % 3;
      bf16x8 af[4];
      #pragma unroll
      for (int mt = 0; mt < 4; ++mt)
        af[mt] = *(const bf16x8*)(ldsb + ((w * 4 + mt + dy) * 18 + lr + dx) * 80 + cb * 16);
      #pragma unroll
      for (int mt = 0; mt < 4; ++mt)
        #pragma unroll
        for (int nt = 0; nt < 2; ++nt)
          acc[mt][nt] = __builtin_amdgcn_mfma_f32_16x16x32_bf16(af[mt], bw[tap][nt], acc[mt][nt], 0, 0, 0);
    }
    __syncthreads();  // all waves done reading activation tile

    // --- bn2+relu -> g2 bf16 to LDS in A-frag layout [pix][40ch-pad]
    #pragma unroll
    for (int mt = 0; mt < 4; ++mt)
      #pragma unroll
      for (int nt = 0; nt < 2; ++nt)
        #pragma unroll
        for (int r = 0; r < 4; ++r) {
          const float g = fmaf(sc2v[nt], relu_f(acc[mt][nt][r]), sh2v[nt]);
          const int pix = w * 64 + mt * 16 + cb * 4 + r;
          *(unsigned short*)(ldsb + pix * 80 + (nt * 16 + lr) * 2) = f2bf(g);
        }
    __syncthreads();

    // --- d3: conv1x1 32->16 as MFMA (4 m-tiles x 1 n-tile)
    f32x4 acc3[4];
    #pragma unroll
    for (int mt = 0; mt < 4; ++mt) {
      acc3[mt][0] = bias3v; acc3[mt][1] = bias3v; acc3[mt][2] = bias3v; acc3[mt][3] = bias3v;
      const bf16x8 a3 = *(const bf16x8*)(ldsb + (w * 64 + mt * 16 + lr) * 80 + cb * 16);
      acc3[mt] = __builtin_amdgcn_mfma_f32_16x16x32_bf16(a3, b3, acc3[mt], 0, 0, 0);
    }

    // --- bn3+relu + in-lane maxpool2 + store (lane: ch=lr, rows cb*4+r)
    #pragma unroll
    for (int mtp = 0; mtp < 2; ++mtp) {
      float o0[4], o1[4];
      #pragma unroll
      for (int r = 0; r < 4; ++r) {
        o0[r] = fmaf(sc3v, relu_f(acc3[2 * mtp][r]), sh3v);
        o1[r] = fmaf(sc3v, relu_f(acc3[2 * mtp + 1][r]), sh3v);
      }
      #pragma unroll
      for (int rp = 0; rp < 2; ++rp) {
        const float m = fmaxf(fmaxf(o0[2 * rp], o0[2 * rp + 1]),
                              fmaxf(o1[2 * rp], o1[2 * rp + 1]));
        const int pyp = w * 2 + mtp;        // pooled y within block (0..7)
        const int pxp = cb * 2 + rp;        // pooled x within block (0..7)
        const size_t ob = ((((size_t)n * 16 + (by >> 1)) * 16 + (bx >> 1)) * 16 + lr) * 256
                          + (size_t)((by & 1) * 8 + pyp) * 16 + ((bx & 1) * 8 + pxp);
        x1p[ob] = m;
      }
    }
  } else {
    // inactive: out = xc; maxpool via LDS (f32 view)
    float* ldsf = (float*)ldsb;  // [256][20] = 20480 B
    {
      float* pw = &ldsf[t * 20];
      #pragma unroll
      for (int c = 0; c < 16; ++c) pw[c] = xc[c];
    }
    __syncthreads();
    {
      const int pp = t & 63, cg = t >> 6;
      const int py = pp >> 3, px = pp & 7;
      const float* r0 = &ldsf[((2 * py) * 16 + 2 * px) * 20 + cg * 4];
      const float* r2 = &ldsf[((2 * py + 1) * 16 + 2 * px) * 20 + cg * 4];
      const float4 v0 = *(const float4*)(r0);
      const float4 v1 = *(const float4*)(r0 + 20);
      const float4 v2 = *(const float4*)(r2);
      const float4 v3 = *(const float4*)(r2 + 20);
      const float m0 = fmaxf(fmaxf(v0.x, v1.x), fmaxf(v2.x, v3.x));
      const float m1 = fmaxf(fmaxf(v0.y, v1.y), fmaxf(v2.y, v3.y));
      const float m2 = fmaxf(fmaxf(v0.z, v1.z), fmaxf(v2.z, v3.z));
      const float m3 = fmaxf(fmaxf(v0.w, v1.w), fmaxf(v2.w, v3.w));
      const size_t ob = ((((size_t)n * 16 + (by >> 1)) * 16 + (bx >> 1)) * 16 + cg * 4) * 256
                        + (size_t)((by & 1) * 8 + py) * 16 + ((bx & 1) * 8 + px);
      x1p[ob]       = m0;
      x1p[ob + 256] = m1;
      x1p[ob + 512] = m2;
      x1p[ob + 768] = m3;
    }
  }
}

// ---------------- stage 2: 256x256, 16 -> 8 ch, blocks 16x16 ----------------
// LDS activation tile: bf16 [18][18][24 ch-pad] = 15552 B (48 B pixel stride).
__global__ __launch_bounds__(256, 4) void stage2_kernel(
    const float* __restrict__ mask,
    const float* __restrict__ cbv, const float* __restrict__ d1b,
    const float* __restrict__ d2b, const float* __restrict__ d3b,
    const float* __restrict__ P, const float* __restrict__ x1p,
    float* __restrict__ x2) {
  __shared__ __align__(16) unsigned char ldsb2[15552];
  __shared__ float red[4];
  __shared__ int actflag;

  const int t = threadIdx.x;
  const int ty = t >> 4, tx = t & 15;
  const int b = blockIdx.x;
  const int n = b >> 8;
  const int BY = (b >> 4) & 15, BX = b & 15;

  // mask2 = maxpool2(mask); active = mean over 16x16 of mask2 > 0.5
  const int my = (BY * 16 + ty) * 2, mx = (BX * 16 + tx) * 2;
  const float* mp = &mask[(size_t)(n * 512 + my) * 512 + mx];
  float s = fmaxf(fmaxf(mp[0], mp[1]), fmaxf(mp[512], mp[513]));
  #pragma unroll
  for (int off = 32; off > 0; off >>= 1) s += __shfl_down(s, off, 64);
  if ((t & 63) == 0) red[t >> 6] = s;
  __syncthreads();
  if (t == 0) actflag = (red[0] + red[1] + red[2] + red[3]) > 128.0f;
  __syncthreads();
  const bool active = (actflag != 0);

  // load x1 (16 ch) from pre-blocked layout
  const float* xb = x1p + (size_t)((n * 16 + BY) * 16 + BX) * 4096 + ty * 16 + tx;
  float xin[16];
  #pragma unroll
  for (int c = 0; c < 16; ++c) xin[c] = xb[c * 256];

  // conv1x1 16->8 + bias, relu, bn0
  const float* wc = P + WT_S2C;
  const float* sc0 = P + SC_S2BN0;
  float xc[8];
  {
    float a[8];
    #pragma unroll
    for (int o = 0; o < 8; ++o) a[o] = cbv[o];
    #pragma unroll
    for (int c = 0; c < 16; ++c) {
      const float v = xin[c];
      #pragma unroll
      for (int o = 0; o < 8; ++o) a[o] = fmaf(wc[c * 8 + o], v, a[o]);
    }
    #pragma unroll
    for (int o = 0; o < 8; ++o) xc[o] = fmaf(sc0[o], relu_f(a[o]), sc0[8 + o]);
  }

  if (active) {
    const int w = t >> 6, lane = t & 63;
    const int lr = lane & 15, cb = lane >> 4;
    const unsigned short* PH = (const unsigned short*)(P + PH_F);

    bf16x8 bw2[5];
    #pragma unroll
    for (int p = 0; p < 5; ++p)
      bw2[p] = *(const bf16x8*)(PH + H_S2D2 + ((p * 16 + lr) * 32 + cb * 8));
    bf16x8 b3;
    if (cb < 2) b3 = *(const bf16x8*)(PH + H_S2D3 + lr * 16 + cb * 8);
    else        b3 = (bf16x8)(short)0;
    const float bias2v = d2b[lr];
    const float bias3v = (lr < 8) ? d3b[lr] : 0.f;
    const float sc2v = P[SC_S2BN2 + lr], sh2v = P[SC_S2BN2 + 16 + lr];
    const float sc3v = (lr < 8) ? P[SC_S2BN3 + lr] : 0.f;
    const float sh3v = (lr < 8) ? P[SC_S2BN3 + 8 + lr] : 0.f;

    // d1: 8->16 VALU
    const float* w1 = P + WT_S2D1;
    const float* sc1 = P + SC_S2BN1;
    float g1[16];
    #pragma unroll
    for (int o = 0; o < 16; ++o) g1[o] = d1b[o];
    #pragma unroll
    for (int c = 0; c < 8; ++c) {
      const float v = xc[c];
      #pragma unroll
      for (int o = 0; o < 16; ++o) g1[o] = fmaf(w1[c * 16 + o], v, g1[o]);
    }
    #pragma unroll
    for (int o = 0; o < 16; ++o) g1[o] = fmaf(sc1[o], relu_f(g1[o]), sc1[16 + o]);

    {
      const uint4 z4 = make_uint4(0u, 0u, 0u, 0u);
      for (int i = t; i < 972; i += 256) ((uint4*)ldsb2)[i] = z4;
    }
    __syncthreads();
    {
      unsigned int pk[8];
      #pragma unroll
      for (int i = 0; i < 8; ++i)
        pk[i] = (unsigned int)f2bf(g1[2 * i]) | ((unsigned int)f2bf(g1[2 * i + 1]) << 16);
      uint4* dst = (uint4*)(ldsb2 + ((ty + 1) * 18 + (tx + 1)) * 48);
      dst[0] = make_uint4(pk[0], pk[1], pk[2], pk[3]);
      dst[1] = make_uint4(pk[4], pk[5], pk[6], pk[7]);
    }
    __syncthreads();

    // 3x3 as MFMA: 5 tap-PAIRS per K=32 step; lane's tap = 2p + (cb>>1)
    f32x4 acc[4];
    #pragma unroll
    for (int mt = 0; mt < 4; ++mt) {
      acc[mt][0] = bias2v; acc[mt][1] = bias2v; acc[mt][2] = bias2v; acc[mt][3] = bias2v;
    }
    #pragma unroll
    for (int p = 0; p < 5; ++p) {
      const int tp = (p < 4) ? (2 * p + (cb >> 1)) : 8;
      const int dy = (tp >= 6) ? 2 : ((tp >= 3) ? 1 : 0);
      const int dx = tp - dy * 3;
      bf16x8 af[4];
      #pragma unroll
      for (int mt = 0; mt < 4; ++mt)
        af[mt] = *(const bf16x8*)(ldsb2 + ((w * 4 + mt + dy) * 18 + lr + dx) * 48 + (cb & 1) * 16);
      #pragma unroll
      for (int mt = 0; mt < 4; ++mt)
        acc[mt] = __builtin_amdgcn_mfma_f32_16x16x32_bf16(af[mt], bw2[p], acc[mt], 0, 0, 0);
    }
    __syncthreads();

    // bn2+relu -> g2 bf16 [pix][24ch-pad]
    #pragma unroll
    for (int mt = 0; mt < 4; ++mt)
      #pragma unroll
      for (int r = 0; r < 4; ++r) {
        const float g = fmaf(sc2v, relu_f(acc[mt][r]), sh2v);
        const int pix = w * 64 + mt * 16 + cb * 4 + r;
        *(unsigned short*)(ldsb2 + pix * 48 + lr * 2) = f2bf(g);
      }
    __syncthreads();

    // d3: 16->8 as MFMA (K=16 zero-padded to 32 on both A and B)
    f32x4 acc3[4];
    #pragma unroll
    for (int mt = 0; mt < 4; ++mt) {
      acc3[mt][0] = bias3v; acc3[mt][1] = bias3v; acc3[mt][2] = bias3v; acc3[mt][3] = bias3v;
      bf16x8 a3;
      if (cb < 2) a3 = *(const bf16x8*)(ldsb2 + (w * 64 + mt * 16 + lr) * 48 + cb * 16);
      else        a3 = (bf16x8)(short)0;
      acc3[mt] = __builtin_amdgcn_mfma_f32_16x16x32_bf16(a3, b3, acc3[mt], 0, 0, 0);
    }

    // bn3+relu + in-lane maxpool + store (ch = lr < 8)
    if (lr < 8) {
      #pragma unroll
      for (int mtp = 0; mtp < 2; ++mtp) {
        float o0[4], o1[4];
        #pragma unroll
        for (int r = 0; r < 4; ++r) {
          o0[r] = fmaf(sc3v, relu_f(acc3[2 * mtp][r]), sh3v);
          o1[r] = fmaf(sc3v, relu_f(acc3[2 * mtp + 1][r]), sh3v);
        }
        #pragma unroll
        for (int rp = 0; rp < 2; ++rp) {
          const float m = fmaxf(fmaxf(o0[2 * rp], o0[2 * rp + 1]),
                                fmaxf(o1[2 * rp], o1[2 * rp + 1]));
          const int pyp = w * 2 + mtp, pxp = cb * 2 + rp;
          const size_t ob = ((size_t)(n * 8 + lr) * 128 + (BY * 8 + pyp)) * 128 + BX * 8 + pxp;
          x2[ob] = m;
        }
      }
    }
  } else {
    float* ldsf = (float*)ldsb2;  // [256][12] = 12288 B
    {
      float* pw = &ldsf[t * 12];
      #pragma unroll
      for (int c = 0; c < 8; ++c) pw[c] = xc[c];
    }
    __syncthreads();
    if (t < 128) {
      const int pp = t & 63, cg = t >> 6;
      const int py = pp >> 3, px = pp & 7;
      const float* r0 = &ldsf[((2 * py) * 16 + 2 * px) * 12 + cg * 4];
      const float* r2 = &ldsf[((2 * py + 1) * 16 + 2 * px) * 12 + cg * 4];
      const float4 v0 = *(const float4*)(r0);
      const float4 v1 = *(const float4*)(r0 + 12);
      const float4 v2 = *(const float4*)(r2);
      const float4 v3 = *(const float4*)(r2 + 12);
      const float m0 = fmaxf(fmaxf(v0.x, v1.x), fmaxf(v2.x, v3.x));
      const float m1 = fmaxf(fmaxf(v0.y, v1.y), fmaxf(v2.y, v3.y));
      const float m2 = fmaxf(fmaxf(v0.z, v1.z), fmaxf(v2.z, v3.z));
      const float m3 = fmaxf(fmaxf(v0.w, v1.w), fmaxf(v2.w, v3.w));
      const size_t ob = ((size_t)(n * 8 + cg * 4) * 128 + (BY * 8 + py)) * 128 + BX * 8 + px;
      x2[ob]         = m0;
      x2[ob + 16384] = m1;
      x2[ob + 32768] = m2;
      x2[ob + 49152] = m3;
    }
  }
}

// ---------------- FC + softmax ----------------
__global__ __launch_bounds__(256) void fc_kernel(const float* __restrict__ x2,
                                                 const float* __restrict__ fcw,
                                                 const float* __restrict__ fcb,
                                                 float* __restrict__ logits) {
  __shared__ float red[4];
  const int wg = blockIdx.x, n = wg / 10, k = wg % 10, t = threadIdx.x;
  const float4* xa = (const float4*)(x2 + (size_t)n * 131072);
  const float4* wa = (const float4*)(fcw + (size_t)k * 131072);
  float s = 0.f;
  for (int i = t; i < 32768; i += 256) {
    const float4 a = xa[i], b = wa[i];
    s = fmaf(a.x, b.x, fmaf(a.y, b.y, fmaf(a.z, b.z, fmaf(a.w, b.w, s))));
  }
  #pragma unroll
  for (int off = 32; off > 0; off >>= 1) s += __shfl_down(s, off, 64);
  if ((t & 63) == 0) red[t >> 6] = s;
  __syncthreads();
  if (t == 0) logits[n * 10 + k] = red[0] + red[1] + red[2] + red[3] + fcb[k];
}

__global__ void softmax_kernel(const float* __restrict__ logits, float* __restrict__ out) {
  const int t = threadIdx.x;
  if (t < 16) {
    float l[10], mx = -1e30f;
    #pragma unroll
    for (int k = 0; k < 10; ++k) { l[k] = logits[t * 10 + k]; mx = fmaxf(mx, l[k]); }
    float sum = 0.f;
    #pragma unroll
    for (int k = 0; k < 10; ++k) { l[k] = expf(l[k] - mx); sum += l[k]; }
    const float inv = 1.f / sum;
    #pragma unroll
    for (int k = 0; k < 10; ++k) out[t * 10 + k] = l[k] * inv;
  }
}

extern "C" void kernel_launch(void* const* d_in, const int* in_sizes, int n_in,
                              void* d_out, int out_size, void* d_ws, size_t ws_size,
                              hipStream_t stream) {
  const float* x      = (const float*)d_in[0];
  const float* mask   = (const float*)d_in[1];
  const float* s1_cw  = (const float*)d_in[2];
  const float* s1_cb  = (const float*)d_in[3];
  const float* s1_bn0 = (const float*)d_in[4];
  const float* s1_d1w = (const float*)d_in[5];
  const float* s1_d1b = (const float*)d_in[6];
  const float* s1_bn1 = (const float*)d_in[7];
  const float* s1_d2w = (const float*)d_in[8];
  const float* s1_d2b = (const float*)d_in[9];
  const float* s1_bn2 = (const float*)d_in[10];
  const float* s1_d3w = (const float*)d_in[11];
  const float* s1_d3b = (const float*)d_in[12];
  const float* s1_bn3 = (const float*)d_in[13];
  const float* s2_cw  = (const float*)d_in[14];
  const float* s2_cb  = (const float*)d_in[15];
  const float* s2_bn0 = (const float*)d_in[16];
  const float* s2_d1w = (const float*)d_in[17];
  const float* s2_d1b = (const float*)d_in[18];
  const float* s2_bn1 = (const float*)d_in[19];
  const float* s2_d2w = (const float*)d_in[20];
  const float* s2_d2b = (const float*)d_in[21];
  const float* s2_bn2 = (const float*)d_in[22];
  const float* s2_d3w = (const float*)d_in[23];
  const float* s2_d3b = (const float*)d_in[24];
  const float* s2_bn3 = (const float*)d_in[25];
  const float* fc_w   = (const float*)d_in[26];
  const float* fc_b   = (const float*)d_in[27];

  float* ws  = (float*)d_ws;
  float* x1p = ws + X1P_OFF;
  float* x2  = ws + X2_OFF;
  float* lg  = ws + LG_OFF;
  float* P   = ws + P_OFF;

  prep_kernel<<<1, 256, 0, stream>>>(s1_cw, s1_d1w, s1_d2w, s1_d3w,
                                     s2_cw, s2_d1w, s2_d2w, s2_d3w,
                                     s1_bn0, s1_bn1, s1_bn2, s1_bn3,
                                     s2_bn0, s2_bn1, s2_bn2, s2_bn3, P);
  stage1_kernel<<<16 * 32 * 32, 256, 0, stream>>>(x, mask, s1_cb, s1_d1b, s1_d2b, s1_d3b, P, x1p);
  stage2_kernel<<<16 * 16 * 16, 256, 0, stream>>>(mask, s2_cb, s2_d1b, s2_d2b, s2_d3b, P, x1p, x2);
  fc_kernel<<<160, 256, 0, stream>>>(x2, fc_w, fc_b, lg);
  softmax_kernel<<<1, 64, 0, stream>>>(lg, (float*)d_out);
}

// Round 3
// 295.446 us; speedup vs baseline: 2.9754x; 1.5106x over previous
//
#include <hip/hip_runtime.h>
#include <math.h>

// ---------------------------------------------------------------------------
// FastNN: sparse block conv net. MFMA v2.
// One 256-thread WG per 16x16 block, fused: conv1x1 (VALU) -> [active?
// d1 1x1 (MFMA) -> 3x3 (MFMA, co-split across waves) -> d3 1x1 (MFMA)]
// -> maxpool2 -> coalesced uint4 store via LDS staging.
// MFMA layouts (verified in round 2): A: row=lane&15, k=(lane>>4)*8+j;
// B: n=lane&15, k same; D: col=lane&15, row=(lane>>4)*4+reg.
// d1/d2 use A=weights, B=activations so D holds co=cb*4+r per lane ->
// bn params via float4 loads, epilogue packs co-pairs (cvt_pk + b32 writes).
// ---------------------------------------------------------------------------

typedef __attribute__((ext_vector_type(8))) short bf16x8;
typedef __attribute__((ext_vector_type(4))) float f32x4;

// ws layout (float offsets)
#define X1P_OFF 0           // [16][16][16][16][16][16] stage1 pooled, pre-blocked
#define X2_OFF  16777216    // [16][8][128][128] stage2 pooled, NCHW
#define LG_OFF  18874368    // 160 logits
#define P_OFF   18874624    // prepped params (f32 region, then bf16 region)

// f32 param region offsets (floats, within P)
enum : int {
  WT_S1C  = 0,      // [ci3][co16]  = 48
  WT_S2C  = 48,     // [ci16][co8]  = 128
  SC_S1BN0 = 176,   // scale16+shift16
  SC_S1BN1 = 208,   // 32+32
  SC_S1BN2 = 272,   // 32+32
  SC_S1BN3 = 336,   // 16+16
  SC_S2BN0 = 368,   // 8+8
  SC_S2BN1 = 384,   // 16+16
  SC_S2BN2 = 416,   // 16+16
  SC_S2BN3 = 448,   // 8+8
  PH_F     = 464    // bf16 (ushort) region starts here (float offset)
};
// bf16 region offsets (ushorts, within PH)
enum : int {
  H_S1D2 = 0,       // [9 tap][32 co][32 ci] = 9216
  H_S1D3 = 9216,    // [16 co][32 ci]        = 512
  H_S2D2 = 9728,    // [5 pair][16 co][32 k] = 2560 (k<16: tap 2p, else 2p+1; pair4 hi=0)
  H_S2D3 = 12288,   // [16 n][16 k]          = 256  (n>=8 zero)
  H_S1D1 = 12544,   // [32 co][32 k]         = 1024 (k>=16 zero)
  H_S2D1 = 13568,   // [16 co][32 k]         = 512  (k>=8 zero)
  PH_END = 14080
};

__device__ __forceinline__ float relu_f(float v) { return v > 0.f ? v : 0.f; }

__device__ __forceinline__ unsigned short f2bf(float f) {
  unsigned int u = __float_as_uint(f);
  unsigned int r = (u + 0x7fffu + ((u >> 16) & 1u)) >> 16;  // RNE
  return (unsigned short)r;
}

// packed pair: low half = lo, high half = hi (v_cvt_pk_bf16_f32, RNE)
__device__ __forceinline__ unsigned int pk2(float lo, float hi) {
  unsigned int r;
  asm("v_cvt_pk_bf16_f32 %0, %1, %2" : "=v"(r) : "v"(lo), "v"(hi));
  return r;
}

__device__ __forceinline__ void prep_bn(const float* __restrict__ p, int C,
                                        float* __restrict__ dst, int t) {
  for (int i = t; i < C; i += 256) {
    float g = p[i], b = p[C + i], m = p[2 * C + i], v = p[3 * C + i];
    float s = g / sqrtf(v + 1e-5f);
    dst[i] = s;
    dst[C + i] = b - s * m;
  }
}

__global__ __launch_bounds__(256) void prep_kernel(
    const float* __restrict__ s1_cw, const float* __restrict__ s1_d1w,
    const float* __restrict__ s1_d2w, const float* __restrict__ s1_d3w,
    const float* __restrict__ s2_cw, const float* __restrict__ s2_d1w,
    const float* __restrict__ s2_d2w, const float* __restrict__ s2_d3w,
    const float* __restrict__ s1_bn0, const float* __restrict__ s1_bn1,
    const float* __restrict__ s1_bn2, const float* __restrict__ s1_bn3,
    const float* __restrict__ s2_bn0, const float* __restrict__ s2_bn1,
    const float* __restrict__ s2_bn2, const float* __restrict__ s2_bn3,
    float* __restrict__ P, float* __restrict__ lg) {
  const int t = threadIdx.x;
  unsigned short* PH = (unsigned short*)(P + PH_F);
  // f32 weights for VALU conv0s
  for (int i = t; i < 48;  i += 256) { int co = i / 3,  ci = i % 3;  P[WT_S1C + ci * 16 + co] = s1_cw[i]; }
  for (int i = t; i < 128; i += 256) { int co = i / 16, ci = i % 16; P[WT_S2C + ci * 8  + co] = s2_cw[i]; }
  // s1_d2w [32o][32i][3][3] -> [tap][o][i]
  for (int i = t; i < 9216; i += 256) {
    int tap = i >> 10, o = (i >> 5) & 31, ci = i & 31;
    PH[H_S1D2 + i] = f2bf(s1_d2w[o * 288 + ci * 9 + tap]);
  }
  // s1_d3w [16o][32i] -> [o][i]
  for (int i = t; i < 512; i += 256) PH[H_S1D3 + i] = f2bf(s1_d3w[i]);
  // s2_d2w [16o][16i][3][3] -> [pair][o][k32]
  for (int i = t; i < 2560; i += 256) {
    int p = i >> 9, o = (i >> 5) & 15, k = i & 31;
    int tp = 2 * p + (k >> 4);
    PH[H_S2D2 + i] = (tp < 9) ? f2bf(s2_d2w[o * 144 + (k & 15) * 9 + tp]) : 0;
  }
  // s2_d3w [8o][16i] -> [n16][k16], n>=8 zero
  for (int i = t; i < 256; i += 256) {
    int nn = i >> 4, k = i & 15;
    PH[H_S2D3 + i] = (nn < 8) ? f2bf(s2_d3w[nn * 16 + k]) : 0;
  }
  // s1_d1w [32o][16i] -> [o][k32], k>=16 zero
  for (int i = t; i < 1024; i += 256) {
    int o = i >> 5, k = i & 31;
    PH[H_S1D1 + i] = (k < 16) ? f2bf(s1_d1w[o * 16 + k]) : 0;
  }
  // s2_d1w [16o][8i] -> [o][k32], k>=8 zero
  for (int i = t; i < 512; i += 256) {
    int o = i >> 5, k = i & 31;
    PH[H_S2D1 + i] = (k < 8) ? f2bf(s2_d1w[o * 8 + k]) : 0;
  }
  prep_bn(s1_bn0, 16, P + SC_S1BN0, t);
  prep_bn(s1_bn1, 32, P + SC_S1BN1, t);
  prep_bn(s1_bn2, 32, P + SC_S1BN2, t);
  prep_bn(s1_bn3, 16, P + SC_S1BN3, t);
  prep_bn(s2_bn0, 8,  P + SC_S2BN0, t);
  prep_bn(s2_bn1, 16, P + SC_S2BN1, t);
  prep_bn(s2_bn2, 16, P + SC_S2BN2, t);
  prep_bn(s2_bn3, 8,  P + SC_S2BN3, t);
  if (t < 160) lg[t] = 0.f;  // fc uses atomicAdd
}

// ---------------- stage 1: 512x512, 3 -> 16 ch, blocks 16x16 ----------------
// LDS: halo tile bf16 [18][18][40 ch-pad] (80 B/px) 25,920 B; reused flat
// [256 px][80 B] for g2, pool staging f32 [16 ch][68 w] at byte 20480.
__global__ __launch_bounds__(256, 3) void stage1_kernel(
    const float* __restrict__ x, const float* __restrict__ mask,
    const float* __restrict__ cbv, const float* __restrict__ d1b,
    const float* __restrict__ d2b, const float* __restrict__ d3b,
    const float* __restrict__ P, float* __restrict__ x1p) {
  __shared__ __align__(16) unsigned char ldsb[25920];
  __shared__ float red[4];
  __shared__ int actflag;

  const int t = threadIdx.x;
  const int ty = t >> 4, tx = t & 15;
  const int b = blockIdx.x;
  const int n = b >> 10;
  const int by = (b >> 5) & 31, bx = b & 31;
  const int gy = by * 16 + ty, gx = bx * 16 + tx;

  // --- block active = mean(mask block) > 0.5  <=>  sum > 128
  float s = mask[(size_t)(n * 512 + gy) * 512 + gx];
  #pragma unroll
  for (int off = 32; off > 0; off >>= 1) s += __shfl_down(s, off, 64);
  if ((t & 63) == 0) red[t >> 6] = s;
  __syncthreads();
  if (t == 0) actflag = (red[0] + red[1] + red[2] + red[3]) > 128.0f;
  __syncthreads();
  const bool active = (actflag != 0);

  // --- input pixel (3 ch)
  float xin[3];
  #pragma unroll
  for (int c = 0; c < 3; ++c)
    xin[c] = x[(size_t)((n * 3 + c) * 512 + gy) * 512 + gx];

  // --- conv1x1 3->16 + bias, relu, bn0 (VALU)
  const float* wc = P + WT_S1C;
  const float* sc0 = P + SC_S1BN0;
  float xc[16];
  {
    float a[16];
    #pragma unroll
    for (int o = 0; o < 16; ++o) a[o] = cbv[o];
    #pragma unroll
    for (int c = 0; c < 3; ++c) {
      const float v = xin[c];
      #pragma unroll
      for (int o = 0; o < 16; ++o) a[o] = fmaf(wc[c * 16 + o], v, a[o]);
    }
    #pragma unroll
    for (int o = 0; o < 16; ++o) xc[o] = fmaf(sc0[o], relu_f(a[o]), sc0[16 + o]);
  }

  float* const poolf = (float*)(ldsb + 20480);  // [16 ch][68 words]

  if (active) {
    const int w = t >> 6, lane = t & 63;
    const int lr = lane & 15, cb = lane >> 4;
    const unsigned short* PH = (const unsigned short*)(P + PH_F);

    // --- zero only the halo ring (68 px x 64 B = ch 0..31)
    if (t < 68) {
      int row, col;
      if (t < 18)      { row = 0;      col = t;      }
      else if (t < 36) { row = 17;     col = t - 18; }
      else if (t < 52) { row = t - 35; col = 0;      }
      else             { row = t - 51; col = 17;     }
      uint4* z = (uint4*)(ldsb + (row * 18 + col) * 80);
      const uint4 z4 = make_uint4(0u, 0u, 0u, 0u);
      z[0] = z4; z[1] = z4; z[2] = z4; z[3] = z4;
    }
    // --- xc -> interior ch 0..15 bf16 (wave-local consumption by d1)
    {
      unsigned int pk[8];
      #pragma unroll
      for (int i = 0; i < 8; ++i) pk[i] = pk2(xc[2 * i], xc[2 * i + 1]);
      uint4* dst = (uint4*)(ldsb + ((ty + 1) * 18 + (tx + 1)) * 80);
      dst[0] = make_uint4(pk[0], pk[1], pk[2], pk[3]);
      dst[1] = make_uint4(pk[4], pk[5], pk[6], pk[7]);
    }

    // --- d1: 16->32 as MFMA, A=weights. K=16 zero-padded (both sides clean).
    bf16x8 w1f[2];
    #pragma unroll
    for (int ct = 0; ct < 2; ++ct)
      w1f[ct] = *(const bf16x8*)(PH + H_S1D1 + (ct * 16 + lr) * 32 + cb * 8);
    f32x4 acc1[2][4];
    #pragma unroll
    for (int ct = 0; ct < 2; ++ct) {
      const float4 bb = *(const float4*)(d1b + ct * 16 + cb * 4);
      #pragma unroll
      for (int nt = 0; nt < 4; ++nt) {
        acc1[ct][nt][0] = bb.x; acc1[ct][nt][1] = bb.y;
        acc1[ct][nt][2] = bb.z; acc1[ct][nt][3] = bb.w;
      }
    }
    #pragma unroll
    for (int nt = 0; nt < 4; ++nt) {
      bf16x8 xcf;
      if (cb < 2) xcf = *(const bf16x8*)(ldsb + ((w * 4 + nt + 1) * 18 + lr + 1) * 80 + cb * 16);
      else        xcf = (bf16x8)(short)0;
      #pragma unroll
      for (int ct = 0; ct < 2; ++ct)
        acc1[ct][nt] = __builtin_amdgcn_mfma_f32_16x16x32_bf16(w1f[ct], xcf, acc1[ct][nt], 0, 0, 0);
    }
    // bn1 + pack co-pairs -> g1 into halo interior (ch = ct*16+cb*4+r)
    #pragma unroll
    for (int ct = 0; ct < 2; ++ct) {
      const float4 s1s = *(const float4*)(P + SC_S1BN1 + ct * 16 + cb * 4);
      const float4 s1h = *(const float4*)(P + SC_S1BN1 + 32 + ct * 16 + cb * 4);
      #pragma unroll
      for (int nt = 0; nt < 4; ++nt) {
        const unsigned base = ((w * 4 + nt + 1) * 18 + lr + 1) * 80 + (ct * 16 + cb * 4) * 2;
        *(unsigned int*)(ldsb + base) =
            pk2(fmaf(s1s.x, relu_f(acc1[ct][nt][0]), s1h.x),
                fmaf(s1s.y, relu_f(acc1[ct][nt][1]), s1h.y));
        *(unsigned int*)(ldsb + base + 4) =
            pk2(fmaf(s1s.z, relu_f(acc1[ct][nt][2]), s1h.z),
                fmaf(s1s.w, relu_f(acc1[ct][nt][3]), s1h.w));
      }
    }
    __syncthreads();

    // --- 3x3 as MFMA, co-split: wave = (co-tile ct3, pixel-half ph)
    const int ct3 = w & 1, ph = w >> 1;
    bf16x8 bw[9];
    #pragma unroll
    for (int tap = 0; tap < 9; ++tap)
      bw[tap] = *(const bf16x8*)(PH + H_S1D2 + (tap * 32 + ct3 * 16 + lr) * 32 + cb * 8);
    f32x4 acc2[8];
    {
      const float4 bb = *(const float4*)(d2b + ct3 * 16 + cb * 4);
      #pragma unroll
      for (int q = 0; q < 8; ++q) {
        acc2[q][0] = bb.x; acc2[q][1] = bb.y; acc2[q][2] = bb.z; acc2[q][3] = bb.w;
      }
    }
    #pragma unroll
    for (int tap = 0; tap < 9; ++tap) {
      const int dy = tap / 3, dx = tap % 3;
      #pragma unroll
      for (int q = 0; q < 8; ++q) {
        const bf16x8 af = *(const bf16x8*)(ldsb + ((ph * 8 + q + dy) * 18 + lr + dx) * 80 + cb * 16);
        acc2[q] = __builtin_amdgcn_mfma_f32_16x16x32_bf16(bw[tap], af, acc2[q], 0, 0, 0);
      }
    }
    __syncthreads();  // all waves done reading g1 tile

    // bn2 + pack co-pairs -> g2 flat [pix][80 B]
    {
      const float4 s2s = *(const float4*)(P + SC_S1BN2 + ct3 * 16 + cb * 4);
      const float4 s2h = *(const float4*)(P + SC_S1BN2 + 32 + ct3 * 16 + cb * 4);
      #pragma unroll
      for (int q = 0; q < 8; ++q) {
        const int pix = (ph * 8 + q) * 16 + lr;
        const unsigned base = pix * 80 + (ct3 * 16 + cb * 4) * 2;
        *(unsigned int*)(ldsb + base) =
            pk2(fmaf(s2s.x, relu_f(acc2[q][0]), s2h.x),
                fmaf(s2s.y, relu_f(acc2[q][1]), s2h.y));
        *(unsigned int*)(ldsb + base + 4) =
            pk2(fmaf(s2s.z, relu_f(acc2[q][2]), s2h.z),
                fmaf(s2s.w, relu_f(acc2[q][3]), s2h.w));
      }
    }
    __syncthreads();

    // --- d3: 32->16 as MFMA (A=activations), then bn3 + in-lane pool
    const bf16x8 b3 = *(const bf16x8*)(PH + H_S1D3 + lr * 32 + cb * 8);
    const float bias3v = d3b[lr];
    const float sc3v = P[SC_S1BN3 + lr], sh3v = P[SC_S1BN3 + 16 + lr];
    f32x4 acc3[4];
    #pragma unroll
    for (int mt = 0; mt < 4; ++mt) {
      acc3[mt][0] = bias3v; acc3[mt][1] = bias3v; acc3[mt][2] = bias3v; acc3[mt][3] = bias3v;
      const bf16x8 a3 = *(const bf16x8*)(ldsb + (w * 64 + mt * 16 + lr) * 80 + cb * 16);
      acc3[mt] = __builtin_amdgcn_mfma_f32_16x16x32_bf16(a3, b3, acc3[mt], 0, 0, 0);
    }
    #pragma unroll
    for (int mtp = 0; mtp < 2; ++mtp) {
      float o0[4], o1[4];
      #pragma unroll
      for (int r = 0; r < 4; ++r) {
        o0[r] = fmaf(sc3v, relu_f(acc3[2 * mtp][r]), sh3v);
        o1[r] = fmaf(sc3v, relu_f(acc3[2 * mtp + 1][r]), sh3v);
      }
      #pragma unroll
      for (int rp = 0; rp < 2; ++rp) {
        const float m = fmaxf(fmaxf(o0[2 * rp], o0[2 * rp + 1]),
                              fmaxf(o1[2 * rp], o1[2 * rp + 1]));
        poolf[lr * 68 + (w * 2 + mtp) * 8 + cb * 2 + rp] = m;
      }
    }
  } else {
    // inactive: out = xc; pool via LDS f32 view
    float* ldsf = (float*)ldsb;  // [256][20] = 20480 B
    {
      float* pw = &ldsf[t * 20];
      #pragma unroll
      for (int c = 0; c < 16; ++c) pw[c] = xc[c];
    }
    __syncthreads();
    {
      const int pp = t & 63, cg = t >> 6;
      const int py = pp >> 3, px = pp & 7;
      const float* r0 = &ldsf[((2 * py) * 16 + 2 * px) * 20 + cg * 4];
      const float* r2 = &ldsf[((2 * py + 1) * 16 + 2 * px) * 20 + cg * 4];
      const float4 v0 = *(const float4*)(r0);
      const float4 v1 = *(const float4*)(r0 + 20);
      const float4 v2 = *(const float4*)(r2);
      const float4 v3 = *(const float4*)(r2 + 20);
      poolf[(cg * 4 + 0) * 68 + py * 8 + px] = fmaxf(fmaxf(v0.x, v1.x), fmaxf(v2.x, v3.x));
      poolf[(cg * 4 + 1) * 68 + py * 8 + px] = fmaxf(fmaxf(v0.y, v1.y), fmaxf(v2.y, v3.y));
      poolf[(cg * 4 + 2) * 68 + py * 8 + px] = fmaxf(fmaxf(v0.z, v1.z), fmaxf(v2.z, v3.z));
      poolf[(cg * 4 + 3) * 68 + py * 8 + px] = fmaxf(fmaxf(v0.w, v1.w), fmaxf(v2.w, v3.w));
    }
  }

  __syncthreads();
  // --- coalesced store: [16 ch][8 y][8 x] -> x1p, uint4 per thread
  {
    const int ch = t >> 4, idx = t & 15, yy = idx >> 1, h = idx & 1;
    const uint4 v = *(const uint4*)(poolf + ch * 68 + yy * 8 + h * 4);
    const size_t ob = ((((size_t)n * 16 + (by >> 1)) * 16 + (bx >> 1)) * 16 + ch) * 256
                      + (size_t)((by & 1) * 8 + yy) * 16 + (bx & 1) * 8 + h * 4;
    *(uint4*)(x1p + ob) = v;
  }
}

// ---------------- stage 2: 256x256, 16 -> 8 ch, blocks 16x16 ----------------
// LDS: halo tile bf16 [18][18][24 ch-pad] (48 B/px) 15,552 B; g2 flat
// [256][48 B]; pool staging f32 [8 ch][68 w] at byte 12288.
__global__ __launch_bounds__(256, 4) void stage2_kernel(
    const float* __restrict__ mask,
    const float* __restrict__ cbv, const float* __restrict__ d1b,
    const float* __restrict__ d2b, const float* __restrict__ d3b,
    const float* __restrict__ P, const float* __restrict__ x1p,
    float* __restrict__ x2) {
  __shared__ __align__(16) unsigned char ldsb2[15552];
  __shared__ float red[4];
  __shared__ int actflag;

  const int t = threadIdx.x;
  const int ty = t >> 4, tx = t & 15;
  const int b = blockIdx.x;
  const int n = b >> 8;
  const int BY = (b >> 4) & 15, BX = b & 15;

  // mask2 = maxpool2(mask); active = mean over 16x16 of mask2 > 0.5
  const int my = (BY * 16 + ty) * 2, mx = (BX * 16 + tx) * 2;
  const float* mp = &mask[(size_t)(n * 512 + my) * 512 + mx];
  float s = fmaxf(fmaxf(mp[0], mp[1]), fmaxf(mp[512], mp[513]));
  #pragma unroll
  for (int off = 32; off > 0; off >>= 1) s += __shfl_down(s, off, 64);
  if ((t & 63) == 0) red[t >> 6] = s;
  __syncthreads();
  if (t == 0) actflag = (red[0] + red[1] + red[2] + red[3]) > 128.0f;
  __syncthreads();
  const bool active = (actflag != 0);

  // load x1 (16 ch) from pre-blocked layout
  const float* xb = x1p + (size_t)((n * 16 + BY) * 16 + BX) * 4096 + ty * 16 + tx;
  float xin[16];
  #pragma unroll
  for (int c = 0; c < 16; ++c) xin[c] = xb[c * 256];

  // conv1x1 16->8 + bias, relu, bn0 (VALU)
  const float* wc = P + WT_S2C;
  const float* sc0 = P + SC_S2BN0;
  float xc[8];
  {
    float a[8];
    #pragma unroll
    for (int o = 0; o < 8; ++o) a[o] = cbv[o];
    #pragma unroll
    for (int c = 0; c < 16; ++c) {
      const float v = xin[c];
      #pragma unroll
      for (int o = 0; o < 8; ++o) a[o] = fmaf(wc[c * 8 + o], v, a[o]);
    }
    #pragma unroll
    for (int o = 0; o < 8; ++o) xc[o] = fmaf(sc0[o], relu_f(a[o]), sc0[8 + o]);
  }

  float* const poolf = (float*)(ldsb2 + 12288);  // [8 ch][68 words]

  if (active) {
    const int w = t >> 6, lane = t & 63;
    const int lr = lane & 15, cb = lane >> 4;
    const unsigned short* PH = (const unsigned short*)(P + PH_F);

    // ring zero (68 px x 32 B = ch 0..15)
    if (t < 68) {
      int row, col;
      if (t < 18)      { row = 0;      col = t;      }
      else if (t < 36) { row = 17;     col = t - 18; }
      else if (t < 52) { row = t - 35; col = 0;      }
      else             { row = t - 51; col = 17;     }
      uint4* z = (uint4*)(ldsb2 + (row * 18 + col) * 48);
      const uint4 z4 = make_uint4(0u, 0u, 0u, 0u);
      z[0] = z4; z[1] = z4;
    }
    // xc (8 ch) -> interior bf16
    {
      unsigned int pk[4];
      #pragma unroll
      for (int i = 0; i < 4; ++i) pk[i] = pk2(xc[2 * i], xc[2 * i + 1]);
      *(uint4*)(ldsb2 + ((ty + 1) * 18 + (tx + 1)) * 48) = make_uint4(pk[0], pk[1], pk[2], pk[3]);
    }

    // d1: 8->16 as MFMA, A=weights, K=8 zero-padded
    const bf16x8 w1f = *(const bf16x8*)(PH + H_S2D1 + lr * 32 + cb * 8);
    f32x4 acc1[4];
    {
      const float4 bb = *(const float4*)(d1b + cb * 4);
      #pragma unroll
      for (int nt = 0; nt < 4; ++nt) {
        acc1[nt][0] = bb.x; acc1[nt][1] = bb.y; acc1[nt][2] = bb.z; acc1[nt][3] = bb.w;
      }
    }
    #pragma unroll
    for (int nt = 0; nt < 4; ++nt) {
      bf16x8 xcf;
      if (cb == 0) xcf = *(const bf16x8*)(ldsb2 + ((w * 4 + nt + 1) * 18 + lr + 1) * 48);
      else         xcf = (bf16x8)(short)0;
      acc1[nt] = __builtin_amdgcn_mfma_f32_16x16x32_bf16(w1f, xcf, acc1[nt], 0, 0, 0);
    }
    {
      const float4 s1s = *(const float4*)(P + SC_S2BN1 + cb * 4);
      const float4 s1h = *(const float4*)(P + SC_S2BN1 + 16 + cb * 4);
      #pragma unroll
      for (int nt = 0; nt < 4; ++nt) {
        const unsigned base = ((w * 4 + nt + 1) * 18 + lr + 1) * 48 + cb * 8;
        *(unsigned int*)(ldsb2 + base) =
            pk2(fmaf(s1s.x, relu_f(acc1[nt][0]), s1h.x),
                fmaf(s1s.y, relu_f(acc1[nt][1]), s1h.y));
        *(unsigned int*)(ldsb2 + base + 4) =
            pk2(fmaf(s1s.z, relu_f(acc1[nt][2]), s1h.z),
                fmaf(s1s.w, relu_f(acc1[nt][3]), s1h.w));
      }
    }
    __syncthreads();

    // 3x3 as MFMA: 5 tap-pairs per K=32; lane's tap = 2p + (cb>>1)
    bf16x8 bw2[5];
    #pragma unroll
    for (int p = 0; p < 5; ++p)
      bw2[p] = *(const bf16x8*)(PH + H_S2D2 + (p * 16 + lr) * 32 + cb * 8);
    f32x4 acc2[4];
    {
      const float4 bb = *(const float4*)(d2b + cb * 4);
      #pragma unroll
      for (int nt = 0; nt < 4; ++nt) {
        acc2[nt][0] = bb.x; acc2[nt][1] = bb.y; acc2[nt][2] = bb.z; acc2[nt][3] = bb.w;
      }
    }
    #pragma unroll
    for (int p = 0; p < 5; ++p) {
      const int tp = (p < 4) ? (2 * p + (cb >> 1)) : 8;
      const int dy = (tp >= 6) ? 2 : ((tp >= 3) ? 1 : 0);
      const int dx = tp - dy * 3;
      #pragma unroll
      for (int nt = 0; nt < 4; ++nt) {
        const bf16x8 af = *(const bf16x8*)(ldsb2 + ((w * 4 + nt + dy) * 18 + lr + dx) * 48 + (cb & 1) * 16);
        acc2[nt] = __builtin_amdgcn_mfma_f32_16x16x32_bf16(bw2[p], af, acc2[nt], 0, 0, 0);
      }
    }
    __syncthreads();

    // bn2 + pack -> g2 flat [pix][48 B]
    {
      const float4 s2s = *(const float4*)(P + SC_S2BN2 + cb * 4);
      const float4 s2h = *(const float4*)(P + SC_S2BN2 + 16 + cb * 4);
      #pragma unroll
      for (int nt = 0; nt < 4; ++nt) {
        const int pix = w * 64 + nt * 16 + lr;
        const unsigned base = pix * 48 + cb * 8;
        *(unsigned int*)(ldsb2 + base) =
            pk2(fmaf(s2s.x, relu_f(acc2[nt][0]), s2h.x),
                fmaf(s2s.y, relu_f(acc2[nt][1]), s2h.y));
        *(unsigned int*)(ldsb2 + base + 4) =
            pk2(fmaf(s2s.z, relu_f(acc2[nt][2]), s2h.z),
                fmaf(s2s.w, relu_f(acc2[nt][3]), s2h.w));
      }
    }
    __syncthreads();

    // d3: 16->8 as MFMA (K=16 zero-padded both sides)
    bf16x8 b3;
    if (cb < 2) b3 = *(const bf16x8*)(PH + H_S2D3 + lr * 16 + cb * 8);
    else        b3 = (bf16x8)(short)0;
    const float bias3v = (lr < 8) ? d3b[lr] : 0.f;
    const float sc3v = (lr < 8) ? P[SC_S2BN3 + lr] : 0.f;
    const float sh3v = (lr < 8) ? P[SC_S2BN3 + 8 + lr] : 0.f;
    f32x4 acc3[4];
    #pragma unroll
    for (int mt = 0; mt < 4; ++mt) {
      acc3[mt][0] = bias3v; acc3[mt][1] = bias3v; acc3[mt][2] = bias3v; acc3[mt][3] = bias3v;
      bf16x8 a3;
      if (cb < 2) a3 = *(const bf16x8*)(ldsb2 + (w * 64 + mt * 16 + lr) * 48 + cb * 16);
      else        a3 = (bf16x8)(short)0;
      acc3[mt] = __builtin_amdgcn_mfma_f32_16x16x32_bf16(a3, b3, acc3[mt], 0, 0, 0);
    }
    if (lr < 8) {
      #pragma unroll
      for (int mtp = 0; mtp < 2; ++mtp) {
        float o0[4], o1[4];
        #pragma unroll
        for (int r = 0; r < 4; ++r) {
          o0[r] = fmaf(sc3v, relu_f(acc3[2 * mtp][r]), sh3v);
          o1[r] = fmaf(sc3v, relu_f(acc3[2 * mtp + 1][r]), sh3v);
        }
        #pragma unroll
        for (int rp = 0; rp < 2; ++rp) {
          const float m = fmaxf(fmaxf(o0[2 * rp], o0[2 * rp + 1]),
                                fmaxf(o1[2 * rp], o1[2 * rp + 1]));
          poolf[lr * 68 + (w * 2 + mtp) * 8 + cb * 2 + rp] = m;
        }
      }
    }
  } else {
    float* ldsf = (float*)ldsb2;  // [256][12] = 12288 B
    {
      float* pw = &ldsf[t * 12];
      #pragma unroll
      for (int c = 0; c < 8; ++c) pw[c] = xc[c];
    }
    __syncthreads();
    if (t < 128) {
      const int pp = t & 63, cg = t >> 6;
      const int py = pp >> 3, px = pp & 7;
      const float* r0 = &ldsf[((2 * py) * 16 + 2 * px) * 12 + cg * 4];
      const float* r2 = &ldsf[((2 * py + 1) * 16 + 2 * px) * 12 + cg * 4];
      const float4 v0 = *(const float4*)(r0);
      const float4 v1 = *(const float4*)(r0 + 12);
      const float4 v2 = *(const float4*)(r2);
      const float4 v3 = *(const float4*)(r2 + 12);
      poolf[(cg * 4 + 0) * 68 + py * 8 + px] = fmaxf(fmaxf(v0.x, v1.x), fmaxf(v2.x, v3.x));
      poolf[(cg * 4 + 1) * 68 + py * 8 + px] = fmaxf(fmaxf(v0.y, v1.y), fmaxf(v2.y, v3.y));
      poolf[(cg * 4 + 2) * 68 + py * 8 + px] = fmaxf(fmaxf(v0.z, v1.z), fmaxf(v2.z, v3.z));
      poolf[(cg * 4 + 3) * 68 + py * 8 + px] = fmaxf(fmaxf(v0.w, v1.w), fmaxf(v2.w, v3.w));
    }
  }

  __syncthreads();
  // coalesced store: [8 ch][8 y][8 x] -> x2 NCHW, uint4 per thread
  if (t < 128) {
    const int ch = t >> 4, idx = t & 15, yy = idx >> 1, h = idx & 1;
    const uint4 v = *(const uint4*)(poolf + ch * 68 + yy * 8 + h * 4);
    const size_t ob = ((size_t)(n * 8 + ch) * 128 + (BY * 8 + yy)) * 128 + BX * 8 + h * 4;
    *(uint4*)(x2 + ob) = v;
  }
}

// ---------------- FC (split-K x8, atomicAdd) + softmax ----------------
__global__ __launch_bounds__(256) void fc_kernel(const float* __restrict__ x2,
                                                 const float* __restrict__ fcw,
                                                 const float* __restrict__ fcb,
                                                 float* __restrict__ logits) {
  __shared__ float red[4];
  const int wg = blockIdx.x, t = threadIdx.x;
  const int sp = wg & 7, k = (wg >> 3) % 10, n = wg / 80;
  const float4* xa = (const float4*)(x2 + (size_t)n * 131072) + sp * 4096;
  const float4* wa = (const float4*)(fcw + (size_t)k * 131072) + sp * 4096;
  float s = 0.f;
  #pragma unroll 4
  for (int i = t; i < 4096; i += 256) {
    const float4 a = xa[i], b = wa[i];
    s = fmaf(a.x, b.x, fmaf(a.y, b.y, fmaf(a.z, b.z, fmaf(a.w, b.w, s))));
  }
  #pragma unroll
  for (int off = 32; off > 0; off >>= 1) s += __shfl_down(s, off, 64);
  if ((t & 63) == 0) red[t >> 6] = s;
  __syncthreads();
  if (t == 0) {
    float tot = red[0] + red[1] + red[2] + red[3];
    if (sp == 0) tot += fcb[k];
    atomicAdd(&logits[n * 10 + k], tot);
  }
}

__global__ void softmax_kernel(const float* __restrict__ logits, float* __restrict__ out) {
  const int t = threadIdx.x;
  if (t < 16) {
    float l[10], mx = -1e30f;
    #pragma unroll
    for (int k = 0; k < 10; ++k) { l[k] = logits[t * 10 + k]; mx = fmaxf(mx, l[k]); }
    float sum = 0.f;
    #pragma unroll
    for (int k = 0; k < 10; ++k) { l[k] = expf(l[k] - mx); sum += l[k]; }
    const float inv = 1.f / sum;
    #pragma unroll
    for (int k = 0; k < 10; ++k) out[t * 10 + k] = l[k] * inv;
  }
}

extern "C" void kernel_launch(void* const* d_in, const int* in_sizes, int n_in,
                              void* d_out, int out_size, void* d_ws, size_t ws_size,
                              hipStream_t stream) {
  const float* x      = (const float*)d_in[0];
  const float* mask   = (const float*)d_in[1];
  const float* s1_cw  = (const float*)d_in[2];
  const float* s1_cb  = (const float*)d_in[3];
  const float* s1_bn0 = (const float*)d_in[4];
  const float* s1_d1w = (const float*)d_in[5];
  const float* s1_d1b = (const float*)d_in[6];
  const float* s1_bn1 = (const float*)d_in[7];
  const float* s1_d2w = (const float*)d_in[8];
  const float* s1_d2b = (const float*)d_in[9];
  const float* s1_bn2 = (const float*)d_in[10];
  const float* s1_d3w = (const float*)d_in[11];
  const float* s1_d3b = (const float*)d_in[12];
  const float* s1_bn3 = (const float*)d_in[13];
  const float* s2_cw  = (const float*)d_in[14];
  const float* s2_cb  = (const float*)d_in[15];
  const float* s2_bn0 = (const float*)d_in[16];
  const float* s2_d1w = (const float*)d_in[17];
  const float* s2_d1b = (const float*)d_in[18];
  const float* s2_bn1 = (const float*)d_in[19];
  const float* s2_d2w = (const float*)d_in[20];
  const float* s2_d2b = (const float*)d_in[21];
  const float* s2_bn2 = (const float*)d_in[22];
  const float* s2_d3w = (const float*)d_in[23];
  const float* s2_d3b = (const float*)d_in[24];
  const float* s2_bn3 = (const float*)d_in[25];
  const float* fc_w   = (const float*)d_in[26];
  const float* fc_b   = (const float*)d_in[27];

  float* ws  = (float*)d_ws;
  float* x1p = ws + X1P_OFF;
  float* x2  = ws + X2_OFF;
  float* lg  = ws + LG_OFF;
  float* P   = ws + P_OFF;

  prep_kernel<<<1, 256, 0, stream>>>(s1_cw, s1_d1w, s1_d2w, s1_d3w,
                                     s2_cw, s2_d1w, s2_d2w, s2_d3w,
                                     s1_bn0, s1_bn1, s1_bn2, s1_bn3,
                                     s2_bn0, s2_bn1, s2_bn2, s2_bn3, P, lg);
  stage1_kernel<<<16 * 32 * 32, 256, 0, stream>>>(x, mask, s1_cb, s1_d1b, s1_d2b, s1_d3b, P, x1p);
  stage2_kernel<<<16 * 16 * 16, 256, 0, stream>>>(mask, s2_cb, s2_d1b, s2_d2b, s2_d3b, P, x1p, x2);
  fc_kernel<<<1280, 256, 0, stream>>>(x2, fc_w, fc_b, lg);
  softmax_kernel<<<1, 64, 0, stream>>>(lg, (float*)d_out);
}

// Round 4
// 284.673 us; speedup vs baseline: 3.0880x; 1.0378x over previous
//
#include <hip/hip_runtime.h>
#include <math.h>

// ---------------------------------------------------------------------------
// FastNN: sparse block conv net. MFMA v3 (occupancy round).
// One 256-thread WG per 16x16 block, fused: conv1x1 (VALU) -> [active?
// d1 1x1 (MFMA) -> 3x3 (MFMA, co-split, weight-streamed) -> d3 1x1 (MFMA)]
// -> maxpool2 -> coalesced uint4 store via LDS staging.
// Register budget is the occupancy limiter (unified VGPR+AGPR on gfx950):
// weights streamed 3-at-a-time in a non-unrolled dy loop, epilogue scales
// loaded late, launch_bounds caps at 4 waves/SIMD.
// stage1 additionally pre-aggregates the maxpool2(mask) block-sums for
// stage2 (msum atomicAdd) so stage2 never touches the mask.
// ---------------------------------------------------------------------------

typedef __attribute__((ext_vector_type(8))) short bf16x8;
typedef __attribute__((ext_vector_type(4))) float f32x4;

// ws layout (float offsets)
#define X1P_OFF 0           // [16][16][16][16][16][16] stage1 pooled, pre-blocked
#define X2_OFF  16777216    // [16][8][128][128] stage2 pooled, NCHW
#define LG_OFF  18874368    // 160 logits
#define MS_OFF  18874624    // [16][16][16] stage2-block mask sums (4096)
#define P_OFF   18878720    // prepped params (f32 region, then bf16 region)

// f32 param region offsets (floats, within P)
enum : int {
  WT_S1C  = 0,      // [ci3][co16]  = 48
  WT_S2C  = 48,     // [ci16][co8]  = 128
  SC_S1BN0 = 176,   // scale16+shift16
  SC_S1BN1 = 208,   // 32+32
  SC_S1BN2 = 272,   // 32+32
  SC_S1BN3 = 336,   // 16+16
  SC_S2BN0 = 368,   // 8+8
  SC_S2BN1 = 384,   // 16+16
  SC_S2BN2 = 416,   // 16+16
  SC_S2BN3 = 448,   // 8+8
  PH_F     = 464    // bf16 (ushort) region starts here (float offset)
};
// bf16 region offsets (ushorts, within PH)
enum : int {
  H_S1D2 = 0,       // [9 tap][32 co][32 ci] = 9216
  H_S1D3 = 9216,    // [16 co][32 ci]        = 512
  H_S2D2 = 9728,    // [5 pair][16 co][32 k] = 2560 (k<16: tap 2p, else 2p+1; pair4 hi=0)
  H_S2D3 = 12288,   // [16 n][16 k]          = 256  (n>=8 zero)
  H_S1D1 = 12544,   // [32 co][32 k]         = 1024 (k>=16 zero)
  H_S2D1 = 13568,   // [16 co][32 k]         = 512  (k>=8 zero)
  PH_END = 14080
};

__device__ __forceinline__ float relu_f(float v) { return v > 0.f ? v : 0.f; }

__device__ __forceinline__ unsigned short f2bf(float f) {
  unsigned int u = __float_as_uint(f);
  unsigned int r = (u + 0x7fffu + ((u >> 16) & 1u)) >> 16;  // RNE
  return (unsigned short)r;
}

// packed pair: low half = lo, high half = hi (v_cvt_pk_bf16_f32, RNE)
__device__ __forceinline__ unsigned int pk2(float lo, float hi) {
  unsigned int r;
  asm("v_cvt_pk_bf16_f32 %0, %1, %2" : "=v"(r) : "v"(lo), "v"(hi));
  return r;
}

__device__ __forceinline__ void prep_bn(const float* __restrict__ p, int C,
                                        float* __restrict__ dst, int t) {
  for (int i = t; i < C; i += 256) {
    float g = p[i], b = p[C + i], m = p[2 * C + i], v = p[3 * C + i];
    float s = g / sqrtf(v + 1e-5f);
    dst[i] = s;
    dst[C + i] = b - s * m;
  }
}

__global__ __launch_bounds__(256) void prep_kernel(
    const float* __restrict__ s1_cw, const float* __restrict__ s1_d1w,
    const float* __restrict__ s1_d2w, const float* __restrict__ s1_d3w,
    const float* __restrict__ s2_cw, const float* __restrict__ s2_d1w,
    const float* __restrict__ s2_d2w, const float* __restrict__ s2_d3w,
    const float* __restrict__ s1_bn0, const float* __restrict__ s1_bn1,
    const float* __restrict__ s1_bn2, const float* __restrict__ s1_bn3,
    const float* __restrict__ s2_bn0, const float* __restrict__ s2_bn1,
    const float* __restrict__ s2_bn2, const float* __restrict__ s2_bn3,
    float* __restrict__ P, float* __restrict__ lg, float* __restrict__ ms) {
  const int t = threadIdx.x;
  unsigned short* PH = (unsigned short*)(P + PH_F);
  // f32 weights for VALU conv0s
  for (int i = t; i < 48;  i += 256) { int co = i / 3,  ci = i % 3;  P[WT_S1C + ci * 16 + co] = s1_cw[i]; }
  for (int i = t; i < 128; i += 256) { int co = i / 16, ci = i % 16; P[WT_S2C + ci * 8  + co] = s2_cw[i]; }
  // s1_d2w [32o][32i][3][3] -> [tap][o][i]
  for (int i = t; i < 9216; i += 256) {
    int tap = i >> 10, o = (i >> 5) & 31, ci = i & 31;
    PH[H_S1D2 + i] = f2bf(s1_d2w[o * 288 + ci * 9 + tap]);
  }
  // s1_d3w [16o][32i] -> [o][i]
  for (int i = t; i < 512; i += 256) PH[H_S1D3 + i] = f2bf(s1_d3w[i]);
  // s2_d2w [16o][16i][3][3] -> [pair][o][k32]
  for (int i = t; i < 2560; i += 256) {
    int p = i >> 9, o = (i >> 5) & 15, k = i & 31;
    int tp = 2 * p + (k >> 4);
    PH[H_S2D2 + i] = (tp < 9) ? f2bf(s2_d2w[o * 144 + (k & 15) * 9 + tp]) : 0;
  }
  // s2_d3w [8o][16i] -> [n16][k16], n>=8 zero
  for (int i = t; i < 256; i += 256) {
    int nn = i >> 4, k = i & 15;
    PH[H_S2D3 + i] = (nn < 8) ? f2bf(s2_d3w[nn * 16 + k]) : 0;
  }
  // s1_d1w [32o][16i] -> [o][k32], k>=16 zero
  for (int i = t; i < 1024; i += 256) {
    int o = i >> 5, k = i & 31;
    PH[H_S1D1 + i] = (k < 16) ? f2bf(s1_d1w[o * 16 + k]) : 0;
  }
  // s2_d1w [16o][8i] -> [o][k32], k>=8 zero
  for (int i = t; i < 512; i += 256) {
    int o = i >> 5, k = i & 31;
    PH[H_S2D1 + i] = (k < 8) ? f2bf(s2_d1w[o * 8 + k]) : 0;
  }
  prep_bn(s1_bn0, 16, P + SC_S1BN0, t);
  prep_bn(s1_bn1, 32, P + SC_S1BN1, t);
  prep_bn(s1_bn2, 32, P + SC_S1BN2, t);
  prep_bn(s1_bn3, 16, P + SC_S1BN3, t);
  prep_bn(s2_bn0, 8,  P + SC_S2BN0, t);
  prep_bn(s2_bn1, 16, P + SC_S2BN1, t);
  prep_bn(s2_bn2, 16, P + SC_S2BN2, t);
  prep_bn(s2_bn3, 8,  P + SC_S2BN3, t);
  if (t < 160) lg[t] = 0.f;                       // fc uses atomicAdd
  for (int i = t; i < 4096; i += 256) ms[i] = 0.f;  // stage1 mask pre-agg
}

// ---------------- stage 1: 512x512, 3 -> 16 ch, blocks 16x16 ----------------
// LDS: halo tile bf16 [18][18][40 ch-pad] (80 B/px) 25,920 B; reused flat
// [256 px][80 B] for g2, pool staging f32 [16 ch][68 w] at byte 20480.
__global__ __launch_bounds__(256, 4) void stage1_kernel(
    const float* __restrict__ x, const float* __restrict__ mask,
    const float* __restrict__ cbv, const float* __restrict__ d1b,
    const float* __restrict__ d2b, const float* __restrict__ d3b,
    const float* __restrict__ P, float* __restrict__ x1p,
    float* __restrict__ msum) {
  __shared__ __align__(16) unsigned char ldsb[25920];
  __shared__ float red_s[4], red_v[4];

  const int t = threadIdx.x;
  const int ty = t >> 4, tx = t & 15;
  const int b = blockIdx.x;
  const int n = b >> 10;
  const int by = (b >> 5) & 31, bx = b & 31;
  const int gy = by * 16 + ty, gx = bx * 16 + tx;

  // --- mask reductions: block sum (active test) + 2x2-max quadrant sum (for stage2)
  {
    const float m = mask[(size_t)(n * 512 + gy) * 512 + gx];
    float v = fmaxf(m, __shfl_xor(m, 1, 64));
    v = fmaxf(v, __shfl_xor(v, 16, 64));
    float s = m;
    #pragma unroll
    for (int off = 32; off > 0; off >>= 1) {
      s += __shfl_down(s, off, 64);
      v += __shfl_down(v, off, 64);
    }
    if ((t & 63) == 0) { red_s[t >> 6] = s; red_v[t >> 6] = v; }
  }
  __syncthreads();

  // --- input pixel (3 ch) + conv1x1 3->16 + bias, relu, bn0 (VALU)
  float xin[3];
  #pragma unroll
  for (int c = 0; c < 3; ++c)
    xin[c] = x[(size_t)((n * 3 + c) * 512 + gy) * 512 + gx];

  const float* wc = P + WT_S1C;
  const float* sc0 = P + SC_S1BN0;
  float xc[16];
  {
    float a[16];
    #pragma unroll
    for (int o = 0; o < 16; ++o) a[o] = cbv[o];
    #pragma unroll
    for (int c = 0; c < 3; ++c) {
      const float v = xin[c];
      #pragma unroll
      for (int o = 0; o < 16; ++o) a[o] = fmaf(wc[c * 16 + o], v, a[o]);
    }
    #pragma unroll
    for (int o = 0; o < 16; ++o) xc[o] = fmaf(sc0[o], relu_f(a[o]), sc0[16 + o]);
  }

  const bool active = (red_s[0] + red_s[1] + red_s[2] + red_s[3]) > 128.0f;
  if (t == 0)
    atomicAdd(&msum[n * 256 + (by >> 1) * 16 + (bx >> 1)],
              (red_v[0] + red_v[1] + red_v[2] + red_v[3]) * 0.25f);

  float* const poolf = (float*)(ldsb + 20480);  // [16 ch][68 words]

  if (active) {
    const int w = t >> 6, lane = t & 63;
    const int lr = lane & 15, cb = lane >> 4;
    const unsigned short* PH = (const unsigned short*)(P + PH_F);

    // --- zero only the halo ring (68 px x 64 B = ch 0..31)
    if (t < 68) {
      int row, col;
      if (t < 18)      { row = 0;      col = t;      }
      else if (t < 36) { row = 17;     col = t - 18; }
      else if (t < 52) { row = t - 35; col = 0;      }
      else             { row = t - 51; col = 17;     }
      uint4* z = (uint4*)(ldsb + (row * 18 + col) * 80);
      const uint4 z4 = make_uint4(0u, 0u, 0u, 0u);
      z[0] = z4; z[1] = z4; z[2] = z4; z[3] = z4;
    }
    // --- xc -> interior ch 0..15 bf16 (wave-local consumption by d1)
    {
      unsigned int pk[8];
      #pragma unroll
      for (int i = 0; i < 8; ++i) pk[i] = pk2(xc[2 * i], xc[2 * i + 1]);
      uint4* dst = (uint4*)(ldsb + ((ty + 1) * 18 + (tx + 1)) * 80);
      dst[0] = make_uint4(pk[0], pk[1], pk[2], pk[3]);
      dst[1] = make_uint4(pk[4], pk[5], pk[6], pk[7]);
    }

    // --- d1: 16->32 as MFMA, A=weights. K=16 zero-padded (both sides clean).
    {
      bf16x8 w1f[2];
      #pragma unroll
      for (int ct = 0; ct < 2; ++ct)
        w1f[ct] = *(const bf16x8*)(PH + H_S1D1 + (ct * 16 + lr) * 32 + cb * 8);
      f32x4 acc1[2][4];
      #pragma unroll
      for (int ct = 0; ct < 2; ++ct) {
        const float4 bb = *(const float4*)(d1b + ct * 16 + cb * 4);
        #pragma unroll
        for (int nt = 0; nt < 4; ++nt) {
          acc1[ct][nt][0] = bb.x; acc1[ct][nt][1] = bb.y;
          acc1[ct][nt][2] = bb.z; acc1[ct][nt][3] = bb.w;
        }
      }
      #pragma unroll
      for (int nt = 0; nt < 4; ++nt) {
        bf16x8 xcf;
        if (cb < 2) xcf = *(const bf16x8*)(ldsb + ((w * 4 + nt + 1) * 18 + lr + 1) * 80 + cb * 16);
        else        xcf = (bf16x8)(short)0;
        #pragma unroll
        for (int ct = 0; ct < 2; ++ct)
          acc1[ct][nt] = __builtin_amdgcn_mfma_f32_16x16x32_bf16(w1f[ct], xcf, acc1[ct][nt], 0, 0, 0);
      }
      // bn1 + pack co-pairs -> g1 into halo interior (ch = ct*16+cb*4+r)
      #pragma unroll
      for (int ct = 0; ct < 2; ++ct) {
        const float4 s1s = *(const float4*)(P + SC_S1BN1 + ct * 16 + cb * 4);
        const float4 s1h = *(const float4*)(P + SC_S1BN1 + 32 + ct * 16 + cb * 4);
        #pragma unroll
        for (int nt = 0; nt < 4; ++nt) {
          const unsigned base = ((w * 4 + nt + 1) * 18 + lr + 1) * 80 + (ct * 16 + cb * 4) * 2;
          *(unsigned int*)(ldsb + base) =
              pk2(fmaf(s1s.x, relu_f(acc1[ct][nt][0]), s1h.x),
                  fmaf(s1s.y, relu_f(acc1[ct][nt][1]), s1h.y));
          *(unsigned int*)(ldsb + base + 4) =
              pk2(fmaf(s1s.z, relu_f(acc1[ct][nt][2]), s1h.z),
                  fmaf(s1s.w, relu_f(acc1[ct][nt][3]), s1h.w));
        }
      }
    }
    __syncthreads();

    // --- 3x3 as MFMA, co-split: wave = (co-tile ct3, pixel-half ph).
    // Weight fragments streamed 3-at-a-time (dy loop NOT unrolled) to keep
    // the live register set ~40 smaller -> 4 waves/SIMD.
    const int ct3 = w & 1, ph = w >> 1;
    f32x4 acc2[8];
    {
      const float4 bb = *(const float4*)(d2b + ct3 * 16 + cb * 4);
      #pragma unroll
      for (int q = 0; q < 8; ++q) {
        acc2[q][0] = bb.x; acc2[q][1] = bb.y; acc2[q][2] = bb.z; acc2[q][3] = bb.w;
      }
    }
    #pragma clang loop unroll(disable)
    for (int dy = 0; dy < 3; ++dy) {
      bf16x8 bwr[3];
      #pragma unroll
      for (int dx = 0; dx < 3; ++dx)
        bwr[dx] = *(const bf16x8*)(PH + H_S1D2 + ((dy * 3 + dx) * 32 + ct3 * 16 + lr) * 32 + cb * 8);
      const int rb = (ph * 8 + dy) * 18 + lr;
      #pragma unroll
      for (int dx = 0; dx < 3; ++dx)
        #pragma unroll
        for (int q = 0; q < 8; ++q) {
          const bf16x8 af = *(const bf16x8*)(ldsb + (rb + q * 18 + dx) * 80 + cb * 16);
          acc2[q] = __builtin_amdgcn_mfma_f32_16x16x32_bf16(bwr[dx], af, acc2[q], 0, 0, 0);
        }
    }
    __syncthreads();  // all waves done reading g1 tile

    // bn2 + pack co-pairs -> g2 flat [pix][80 B] (scales loaded late)
    {
      const float4 s2s = *(const float4*)(P + SC_S1BN2 + ct3 * 16 + cb * 4);
      const float4 s2h = *(const float4*)(P + SC_S1BN2 + 32 + ct3 * 16 + cb * 4);
      #pragma unroll
      for (int q = 0; q < 8; ++q) {
        const int pix = (ph * 8 + q) * 16 + lr;
        const unsigned base = pix * 80 + (ct3 * 16 + cb * 4) * 2;
        *(unsigned int*)(ldsb + base) =
            pk2(fmaf(s2s.x, relu_f(acc2[q][0]), s2h.x),
                fmaf(s2s.y, relu_f(acc2[q][1]), s2h.y));
        *(unsigned int*)(ldsb + base + 4) =
            pk2(fmaf(s2s.z, relu_f(acc2[q][2]), s2h.z),
                fmaf(s2s.w, relu_f(acc2[q][3]), s2h.w));
      }
    }
    __syncthreads();

    // --- d3: 32->16 as MFMA (A=activations), then bn3 + in-lane pool
    const bf16x8 b3 = *(const bf16x8*)(PH + H_S1D3 + lr * 32 + cb * 8);
    const float bias3v = d3b[lr];
    const float sc3v = P[SC_S1BN3 + lr], sh3v = P[SC_S1BN3 + 16 + lr];
    f32x4 acc3[4];
    #pragma unroll
    for (int mt = 0; mt < 4; ++mt) {
      acc3[mt][0] = bias3v; acc3[mt][1] = bias3v; acc3[mt][2] = bias3v; acc3[mt][3] = bias3v;
      const bf16x8 a3 = *(const bf16x8*)(ldsb + (w * 64 + mt * 16 + lr) * 80 + cb * 16);
      acc3[mt] = __builtin_amdgcn_mfma_f32_16x16x32_bf16(a3, b3, acc3[mt], 0, 0, 0);
    }
    #pragma unroll
    for (int mtp = 0; mtp < 2; ++mtp) {
      float o0[4], o1[4];
      #pragma unroll
      for (int r = 0; r < 4; ++r) {
        o0[r] = fmaf(sc3v, relu_f(acc3[2 * mtp][r]), sh3v);
        o1[r] = fmaf(sc3v, relu_f(acc3[2 * mtp + 1][r]), sh3v);
      }
      #pragma unroll
      for (int rp = 0; rp < 2; ++rp) {
        const float m = fmaxf(fmaxf(o0[2 * rp], o0[2 * rp + 1]),
                              fmaxf(o1[2 * rp], o1[2 * rp + 1]));
        poolf[lr * 68 + (w * 2 + mtp) * 8 + cb * 2 + rp] = m;
      }
    }
  } else {
    // inactive: out = xc; pool via LDS f32 view
    float* ldsf = (float*)ldsb;  // [256][20] = 20480 B
    {
      float* pw = &ldsf[t * 20];
      #pragma unroll
      for (int c = 0; c < 16; ++c) pw[c] = xc[c];
    }
    __syncthreads();
    {
      const int pp = t & 63, cg = t >> 6;
      const int py = pp >> 3, px = pp & 7;
      const float* r0 = &ldsf[((2 * py) * 16 + 2 * px) * 20 + cg * 4];
      const float* r2 = &ldsf[((2 * py + 1) * 16 + 2 * px) * 20 + cg * 4];
      const float4 v0 = *(const float4*)(r0);
      const float4 v1 = *(const float4*)(r0 + 20);
      const float4 v2 = *(const float4*)(r2);
      const float4 v3 = *(const float4*)(r2 + 20);
      poolf[(cg * 4 + 0) * 68 + py * 8 + px] = fmaxf(fmaxf(v0.x, v1.x), fmaxf(v2.x, v3.x));
      poolf[(cg * 4 + 1) * 68 + py * 8 + px] = fmaxf(fmaxf(v0.y, v1.y), fmaxf(v2.y, v3.y));
      poolf[(cg * 4 + 2) * 68 + py * 8 + px] = fmaxf(fmaxf(v0.z, v1.z), fmaxf(v2.z, v3.z));
      poolf[(cg * 4 + 3) * 68 + py * 8 + px] = fmaxf(fmaxf(v0.w, v1.w), fmaxf(v2.w, v3.w));
    }
  }

  __syncthreads();
  // --- coalesced store: [16 ch][8 y][8 x] -> x1p, uint4 per thread
  {
    const int ch = t >> 4, idx = t & 15, yy = idx >> 1, h = idx & 1;
    const uint4 v = *(const uint4*)(poolf + ch * 68 + yy * 8 + h * 4);
    const size_t ob = ((((size_t)n * 16 + (by >> 1)) * 16 + (bx >> 1)) * 16 + ch) * 256
                      + (size_t)((by & 1) * 8 + yy) * 16 + (bx & 1) * 8 + h * 4;
    *(uint4*)(x1p + ob) = v;
  }
}

// ---------------- stage 2: 256x256, 16 -> 8 ch, blocks 16x16 ----------------
// LDS: halo tile bf16 [18][18][24 ch-pad] (48 B/px) 15,552 B; g2 flat
// [256][48 B]; pool staging f32 [8 ch][68 w] at byte 12288.
// Active test from stage1's pre-aggregated msum (no mask reads, no barriers).
__global__ __launch_bounds__(256, 5) void stage2_kernel(
    const float* __restrict__ msum,
    const float* __restrict__ cbv, const float* __restrict__ d1b,
    const float* __restrict__ d2b, const float* __restrict__ d3b,
    const float* __restrict__ P, const float* __restrict__ x1p,
    float* __restrict__ x2) {
  __shared__ __align__(16) unsigned char ldsb2[15552];

  const int t = threadIdx.x;
  const int ty = t >> 4, tx = t & 15;
  const int b = blockIdx.x;
  const int n = b >> 8;
  const int BY = (b >> 4) & 15, BX = b & 15;

  const bool active = msum[b] > 128.0f;  // b == n*256 + BY*16 + BX

  // load x1 (16 ch) from pre-blocked layout
  const float* xb = x1p + (size_t)b * 4096 + ty * 16 + tx;
  float xin[16];
  #pragma unroll
  for (int c = 0; c < 16; ++c) xin[c] = xb[c * 256];

  // conv1x1 16->8 + bias, relu, bn0 (VALU)
  const float* wc = P + WT_S2C;
  const float* sc0 = P + SC_S2BN0;
  float xc[8];
  {
    float a[8];
    #pragma unroll
    for (int o = 0; o < 8; ++o) a[o] = cbv[o];
    #pragma unroll
    for (int c = 0; c < 16; ++c) {
      const float v = xin[c];
      #pragma unroll
      for (int o = 0; o < 8; ++o) a[o] = fmaf(wc[c * 8 + o], v, a[o]);
    }
    #pragma unroll
    for (int o = 0; o < 8; ++o) xc[o] = fmaf(sc0[o], relu_f(a[o]), sc0[8 + o]);
  }

  float* const poolf = (float*)(ldsb2 + 12288);  // [8 ch][68 words]

  if (active) {
    const int w = t >> 6, lane = t & 63;
    const int lr = lane & 15, cb = lane >> 4;
    const unsigned short* PH = (const unsigned short*)(P + PH_F);

    // ring zero (68 px x 32 B = ch 0..15)
    if (t < 68) {
      int row, col;
      if (t < 18)      { row = 0;      col = t;      }
      else if (t < 36) { row = 17;     col = t - 18; }
      else if (t < 52) { row = t - 35; col = 0;      }
      else             { row = t - 51; col = 17;     }
      uint4* z = (uint4*)(ldsb2 + (row * 18 + col) * 48);
      const uint4 z4 = make_uint4(0u, 0u, 0u, 0u);
      z[0] = z4; z[1] = z4;
    }
    // xc (8 ch) -> interior bf16
    {
      unsigned int pk[4];
      #pragma unroll
      for (int i = 0; i < 4; ++i) pk[i] = pk2(xc[2 * i], xc[2 * i + 1]);
      *(uint4*)(ldsb2 + ((ty + 1) * 18 + (tx + 1)) * 48) = make_uint4(pk[0], pk[1], pk[2], pk[3]);
    }

    // d1: 8->16 as MFMA, A=weights, K=8 zero-padded
    {
      const bf16x8 w1f = *(const bf16x8*)(PH + H_S2D1 + lr * 32 + cb * 8);
      f32x4 acc1[4];
      {
        const float4 bb = *(const float4*)(d1b + cb * 4);
        #pragma unroll
        for (int nt = 0; nt < 4; ++nt) {
          acc1[nt][0] = bb.x; acc1[nt][1] = bb.y; acc1[nt][2] = bb.z; acc1[nt][3] = bb.w;
        }
      }
      #pragma unroll
      for (int nt = 0; nt < 4; ++nt) {
        bf16x8 xcf;
        if (cb == 0) xcf = *(const bf16x8*)(ldsb2 + ((w * 4 + nt + 1) * 18 + lr + 1) * 48);
        else         xcf = (bf16x8)(short)0;
        acc1[nt] = __builtin_amdgcn_mfma_f32_16x16x32_bf16(w1f, xcf, acc1[nt], 0, 0, 0);
      }
      {
        const float4 s1s = *(const float4*)(P + SC_S2BN1 + cb * 4);
        const float4 s1h = *(const float4*)(P + SC_S2BN1 + 16 + cb * 4);
        #pragma unroll
        for (int nt = 0; nt < 4; ++nt) {
          const unsigned base = ((w * 4 + nt + 1) * 18 + lr + 1) * 48 + cb * 8;
          *(unsigned int*)(ldsb2 + base) =
              pk2(fmaf(s1s.x, relu_f(acc1[nt][0]), s1h.x),
                  fmaf(s1s.y, relu_f(acc1[nt][1]), s1h.y));
          *(unsigned int*)(ldsb2 + base + 4) =
              pk2(fmaf(s1s.z, relu_f(acc1[nt][2]), s1h.z),
                  fmaf(s1s.w, relu_f(acc1[nt][3]), s1h.w));
        }
      }
    }
    __syncthreads();

    // 3x3 as MFMA: 5 tap-pairs per K=32; lane's tap = 2p + (cb>>1); weights streamed
    f32x4 acc2[4];
    {
      const float4 bb = *(const float4*)(d2b + cb * 4);
      #pragma unroll
      for (int nt = 0; nt < 4; ++nt) {
        acc2[nt][0] = bb.x; acc2[nt][1] = bb.y; acc2[nt][2] = bb.z; acc2[nt][3] = bb.w;
      }
    }
    #pragma clang loop unroll(disable)
    for (int p = 0; p < 5; ++p) {
      const bf16x8 bwp = *(const bf16x8*)(PH + H_S2D2 + (p * 16 + lr) * 32 + cb * 8);
      const int tp = (p < 4) ? (2 * p + (cb >> 1)) : 8;
      const int dy = (tp >= 6) ? 2 : ((tp >= 3) ? 1 : 0);
      const int dx = tp - dy * 3;
      #pragma unroll
      for (int nt = 0; nt < 4; ++nt) {
        const bf16x8 af = *(const bf16x8*)(ldsb2 + ((w * 4 + nt + dy) * 18 + lr + dx) * 48 + (cb & 1) * 16);
        acc2[nt] = __builtin_amdgcn_mfma_f32_16x16x32_bf16(bwp, af, acc2[nt], 0, 0, 0);
      }
    }
    __syncthreads();

    // bn2 + pack -> g2 flat [pix][48 B]
    {
      const float4 s2s = *(const float4*)(P + SC_S2BN2 + cb * 4);
      const float4 s2h = *(const float4*)(P + SC_S2BN2 + 16 + cb * 4);
      #pragma unroll
      for (int nt = 0; nt < 4; ++nt) {
        const int pix = w * 64 + nt * 16 + lr;
        const unsigned base = pix * 48 + cb * 8;
        *(unsigned int*)(ldsb2 + base) =
            pk2(fmaf(s2s.x, relu_f(acc2[nt][0]), s2h.x),
                fmaf(s2s.y, relu_f(acc2[nt][1]), s2h.y));
        *(unsigned int*)(ldsb2 + base + 4) =
            pk2(fmaf(s2s.z, relu_f(acc2[nt][2]), s2h.z),
                fmaf(s2s.w, relu_f(acc2[nt][3]), s2h.w));
      }
    }
    __syncthreads();

    // d3: 16->8 as MFMA (K=16 zero-padded both sides)
    bf16x8 b3;
    if (cb < 2) b3 = *(const bf16x8*)(PH + H_S2D3 + lr * 16 + cb * 8);
    else        b3 = (bf16x8)(short)0;
    const float bias3v = (lr < 8) ? d3b[lr] : 0.f;
    const float sc3v = (lr < 8) ? P[SC_S2BN3 + lr] : 0.f;
    const float sh3v = (lr < 8) ? P[SC_S2BN3 + 8 + lr] : 0.f;
    f32x4 acc3[4];
    #pragma unroll
    for (int mt = 0; mt < 4; ++mt) {
      acc3[mt][0] = bias3v; acc3[mt][1] = bias3v; acc3[mt][2] = bias3v; acc3[mt][3] = bias3v;
      bf16x8 a3;
      if (cb < 2) a3 = *(const bf16x8*)(ldsb2 + (w * 64 + mt * 16 + lr) * 48 + cb * 16);
      else        a3 = (bf16x8)(short)0;
      acc3[mt] = __builtin_amdgcn_mfma_f32_16x16x32_bf16(a3, b3, acc3[mt], 0, 0, 0);
    }
    if (lr < 8) {
      #pragma unroll
      for (int mtp = 0; mtp < 2; ++mtp) {
        float o0[4], o1[4];
        #pragma unroll
        for (int r = 0; r < 4; ++r) {
          o0[r] = fmaf(sc3v, relu_f(acc3[2 * mtp][r]), sh3v);
          o1[r] = fmaf(sc3v, relu_f(acc3[2 * mtp + 1][r]), sh3v);
        }
        #pragma unroll
        for (int rp = 0; rp < 2; ++rp) {
          const float m = fmaxf(fmaxf(o0[2 * rp], o0[2 * rp + 1]),
                                fmaxf(o1[2 * rp], o1[2 * rp + 1]));
          poolf[lr * 68 + (w * 2 + mtp) * 8 + cb * 2 + rp] = m;
        }
      }
    }
  } else {
    float* ldsf = (float*)ldsb2;  // [256][12] = 12288 B
    {
      float* pw = &ldsf[t * 12];
      #pragma unroll
      for (int c = 0; c < 8; ++c) pw[c] = xc[c];
    }
    __syncthreads();
    if (t < 128) {
      const int pp = t & 63, cg = t >> 6;
      const int py = pp >> 3, px = pp & 7;
      const float* r0 = &ldsf[((2 * py) * 16 + 2 * px) * 12 + cg * 4];
      const float* r2 = &ldsf[((2 * py + 1) * 16 + 2 * px) * 12 + cg * 4];
      const float4 v0 = *(const float4*)(r0);
      const float4 v1 = *(const float4*)(r0 + 12);
      const float4 v2 = *(const float4*)(r2);
      const float4 v3 = *(const float4*)(r2 + 12);
      poolf[(cg * 4 + 0) * 68 + py * 8 + px] = fmaxf(fmaxf(v0.x, v1.x), fmaxf(v2.x, v3.x));
      poolf[(cg * 4 + 1) * 68 + py * 8 + px] = fmaxf(fmaxf(v0.y, v1.y), fmaxf(v2.y, v3.y));
      poolf[(cg * 4 + 2) * 68 + py * 8 + px] = fmaxf(fmaxf(v0.z, v1.z), fmaxf(v2.z, v3.z));
      poolf[(cg * 4 + 3) * 68 + py * 8 + px] = fmaxf(fmaxf(v0.w, v1.w), fmaxf(v2.w, v3.w));
    }
  }

  __syncthreads();
  // coalesced store: [8 ch][8 y][8 x] -> x2 NCHW, uint4 per thread
  if (t < 128) {
    const int ch = t >> 4, idx = t & 15, yy = idx >> 1, h = idx & 1;
    const uint4 v = *(const uint4*)(poolf + ch * 68 + yy * 8 + h * 4);
    const size_t ob = ((size_t)(n * 8 + ch) * 128 + (BY * 8 + yy)) * 128 + BX * 8 + h * 4;
    *(uint4*)(x2 + ob) = v;
  }
}

// ---------------- FC (split-K x8, atomicAdd) + softmax ----------------
__global__ __launch_bounds__(256) void fc_kernel(const float* __restrict__ x2,
                                                 const float* __restrict__ fcw,
                                                 const float* __restrict__ fcb,
                                                 float* __restrict__ logits) {
  __shared__ float red[4];
  const int wg = blockIdx.x, t = threadIdx.x;
  const int sp = wg & 7, k = (wg >> 3) % 10, n = wg / 80;
  const float4* xa = (const float4*)(x2 + (size_t)n * 131072) + sp * 4096;
  const float4* wa = (const float4*)(fcw + (size_t)k * 131072) + sp * 4096;
  float s = 0.f;
  #pragma unroll 4
  for (int i = t; i < 4096; i += 256) {
    const float4 a = xa[i], b = wa[i];
    s = fmaf(a.x, b.x, fmaf(a.y, b.y, fmaf(a.z, b.z, fmaf(a.w, b.w, s))));
  }
  #pragma unroll
  for (int off = 32; off > 0; off >>= 1) s += __shfl_down(s, off, 64);
  if ((t & 63) == 0) red[t >> 6] = s;
  __syncthreads();
  if (t == 0) {
    float tot = red[0] + red[1] + red[2] + red[3];
    if (sp == 0) tot += fcb[k];
    atomicAdd(&logits[n * 10 + k], tot);
  }
}

__global__ void softmax_kernel(const float* __restrict__ logits, float* __restrict__ out) {
  const int t = threadIdx.x;
  if (t < 16) {
    float l[10], mx = -1e30f;
    #pragma unroll
    for (int k = 0; k < 10; ++k) { l[k] = logits[t * 10 + k]; mx = fmaxf(mx, l[k]); }
    float sum = 0.f;
    #pragma unroll
    for (int k = 0; k < 10; ++k) { l[k] = expf(l[k] - mx); sum += l[k]; }
    const float inv = 1.f / sum;
    #pragma unroll
    for (int k = 0; k < 10; ++k) out[t * 10 + k] = l[k] * inv;
  }
}

extern "C" void kernel_launch(void* const* d_in, const int* in_sizes, int n_in,
                              void* d_out, int out_size, void* d_ws, size_t ws_size,
                              hipStream_t stream) {
  const float* x      = (const float*)d_in[0];
  const float* mask   = (const float*)d_in[1];
  const float* s1_cw  = (const float*)d_in[2];
  const float* s1_cb  = (const float*)d_in[3];
  const float* s1_bn0 = (const float*)d_in[4];
  const float* s1_d1w = (const float*)d_in[5];
  const float* s1_d1b = (const float*)d_in[6];
  const float* s1_bn1 = (const float*)d_in[7];
  const float* s1_d2w = (const float*)d_in[8];
  const float* s1_d2b = (const float*)d_in[9];
  const float* s1_bn2 = (const float*)d_in[10];
  const float* s1_d3w = (const float*)d_in[11];
  const float* s1_d3b = (const float*)d_in[12];
  const float* s1_bn3 = (const float*)d_in[13];
  const float* s2_cw  = (const float*)d_in[14];
  const float* s2_cb  = (const float*)d_in[15];
  const float* s2_bn0 = (const float*)d_in[16];
  const float* s2_d1w = (const float*)d_in[17];
  const float* s2_d1b = (const float*)d_in[18];
  const float* s2_bn1 = (const float*)d_in[19];
  const float* s2_d2w = (const float*)d_in[20];
  const float* s2_d2b = (const float*)d_in[21];
  const float* s2_bn2 = (const float*)d_in[22];
  const float* s2_d3w = (const float*)d_in[23];
  const float* s2_d3b = (const float*)d_in[24];
  const float* s2_bn3 = (const float*)d_in[25];
  const float* fc_w   = (const float*)d_in[26];
  const float* fc_b   = (const float*)d_in[27];

  float* ws  = (float*)d_ws;
  float* x1p = ws + X1P_OFF;
  float* x2  = ws + X2_OFF;
  float* lg  = ws + LG_OFF;
  float* ms  = ws + MS_OFF;
  float* P   = ws + P_OFF;

  prep_kernel<<<1, 256, 0, stream>>>(s1_cw, s1_d1w, s1_d2w, s1_d3w,
                                     s2_cw, s2_d1w, s2_d2w, s2_d3w,
                                     s1_bn0, s1_bn1, s1_bn2, s1_bn3,
                                     s2_bn0, s2_bn1, s2_bn2, s2_bn3, P, lg, ms);
  stage1_kernel<<<16 * 32 * 32, 256, 0, stream>>>(x, mask, s1_cb, s1_d1b, s1_d2b, s1_d3b, P, x1p, ms);
  stage2_kernel<<<16 * 16 * 16, 256, 0, stream>>>(ms, s2_cb, s2_d1b, s2_d2b, s2_d3b, P, x1p, x2);
  fc_kernel<<<1280, 256, 0, stream>>>(x2, fc_w, fc_b, lg);
  softmax_kernel<<<1, 64, 0, stream>>>(lg, (float*)d_out);
}

// Round 7
// 276.446 us; speedup vs baseline: 3.1799x; 1.0298x over previous
//
#include <hip/hip_runtime.h>
#include <math.h>

// ---------------------------------------------------------------------------
// FastNN: sparse block conv net. MFMA v4 (LDS-traffic round).
// One 256-thread WG per 16x16 block, fused: conv1x1 (VALU) -> [active?
// d1 1x1 (MFMA 16x16) -> 3x3 (MFMA 32x32x16: A=weights, B=activations,
// halves LDS reads + MFMA count vs 16x16x32) -> d3 1x1 (MFMA 16x16)]
// -> maxpool2 -> coalesced uint4 store via LDS staging.
// 32x32 C/D layout (m74/m101-verified): col=lane&31 (=pixel),
// row=(reg&3)+8*(reg>>2)+4*(lane>>5) (=co). A/B k-mapping cancels (symmetric).
// stage1 pre-aggregates maxpool2(mask) sums for stage2 (msum atomicAdd).
// ---------------------------------------------------------------------------

typedef __attribute__((ext_vector_type(8))) short bf16x8;
typedef __attribute__((ext_vector_type(4))) float f32x4;
typedef __attribute__((ext_vector_type(16))) float f32x16;

// ws layout (float offsets)
#define X1P_OFF 0           // [16][16][16][16][16][16] stage1 pooled, pre-blocked
#define X2_OFF  16777216    // [16][8][128][128] stage2 pooled, NCHW
#define LG_OFF  18874368    // 160 logits
#define MS_OFF  18874624    // [16][16][16] stage2-block mask sums (4096)
#define P_OFF   18878720    // prepped params (f32 region, then bf16 region)

// f32 param region offsets (floats, within P)
enum : int {
  WT_S1C  = 0,      // [ci3][co16]  = 48
  WT_S2C  = 48,     // [ci16][co8]  = 128
  SC_S1BN0 = 176,   // scale16+shift16
  SC_S1BN1 = 208,   // 32+32
  SC_S1BN2 = 272,   // 32+32
  SC_S1BN3 = 336,   // 16+16
  SC_S2BN0 = 368,   // 8+8
  SC_S2BN1 = 384,   // 16+16
  SC_S2BN2 = 416,   // 16+16
  SC_S2BN3 = 448,   // 8+8
  PH_F     = 464    // bf16 (ushort) region starts here (float offset)
};
// bf16 region offsets (ushorts, within PH)
enum : int {
  H_S1D2 = 0,       // [9 tap][32 co][32 ci] = 9216
  H_S1D3 = 9216,    // [16 co][32 ci]        = 512
  H_S2D2 = 9728,    // [5 pair][16 co][32 k] = 2560 (k<16: tap 2p, else 2p+1; pair4 hi=0)
  H_S2D3 = 12288,   // [16 n][16 k]          = 256  (n>=8 zero)
  H_S1D1 = 12544,   // [32 co][32 k]         = 1024 (k>=16 zero)
  H_S2D1 = 13568,   // [16 co][32 k]         = 512  (k>=8 zero)
  PH_END = 14080
};

__device__ __forceinline__ float relu_f(float v) { return v > 0.f ? v : 0.f; }

__device__ __forceinline__ unsigned short f2bf(float f) {
  unsigned int u = __float_as_uint(f);
  unsigned int r = (u + 0x7fffu + ((u >> 16) & 1u)) >> 16;  // RNE
  return (unsigned short)r;
}

// packed pair: low half = lo, high half = hi (v_cvt_pk_bf16_f32, RNE)
__device__ __forceinline__ unsigned int pk2(float lo, float hi) {
  unsigned int r;
  asm("v_cvt_pk_bf16_f32 %0, %1, %2" : "=v"(r) : "v"(lo), "v"(hi));
  return r;
}

__device__ __forceinline__ void prep_bn(const float* __restrict__ p, int C,
                                        float* __restrict__ dst, int gid) {
  for (int i = gid; i < C; i += 8192) {
    float g = p[i], b = p[C + i], m = p[2 * C + i], v = p[3 * C + i];
    float s = g / sqrtf(v + 1e-5f);
    dst[i] = s;
    dst[C + i] = b - s * m;
  }
}

// grid = 32 blocks x 256 (stride 8192)
__global__ __launch_bounds__(256) void prep_kernel(
    const float* __restrict__ s1_cw, const float* __restrict__ s1_d1w,
    const float* __restrict__ s1_d2w, const float* __restrict__ s1_d3w,
    const float* __restrict__ s2_cw, const float* __restrict__ s2_d1w,
    const float* __restrict__ s2_d2w, const float* __restrict__ s2_d3w,
    const float* __restrict__ s1_bn0, const float* __restrict__ s1_bn1,
    const float* __restrict__ s1_bn2, const float* __restrict__ s1_bn3,
    const float* __restrict__ s2_bn0, const float* __restrict__ s2_bn1,
    const float* __restrict__ s2_bn2, const float* __restrict__ s2_bn3,
    float* __restrict__ P, float* __restrict__ lg, float* __restrict__ ms) {
  const int gid = blockIdx.x * 256 + threadIdx.x;
  unsigned short* PH = (unsigned short*)(P + PH_F);
  // f32 weights for VALU conv0s
  for (int i = gid; i < 48;  i += 8192) { int co = i / 3,  ci = i % 3;  P[WT_S1C + ci * 16 + co] = s1_cw[i]; }
  for (int i = gid; i < 128; i += 8192) { int co = i / 16, ci = i % 16; P[WT_S2C + ci * 8  + co] = s2_cw[i]; }
  // s1_d2w [32o][32i][3][3] -> [tap][o][i]
  for (int i = gid; i < 9216; i += 8192) {
    int tap = i >> 10, o = (i >> 5) & 31, ci = i & 31;
    PH[H_S1D2 + i] = f2bf(s1_d2w[o * 288 + ci * 9 + tap]);
  }
  // s1_d3w [16o][32i] -> [o][i]
  for (int i = gid; i < 512; i += 8192) PH[H_S1D3 + i] = f2bf(s1_d3w[i]);
  // s2_d2w [16o][16i][3][3] -> [pair][o][k32]
  for (int i = gid; i < 2560; i += 8192) {
    int p = i >> 9, o = (i >> 5) & 15, k = i & 31;
    int tp = 2 * p + (k >> 4);
    PH[H_S2D2 + i] = (tp < 9) ? f2bf(s2_d2w[o * 144 + (k & 15) * 9 + tp]) : 0;
  }
  // s2_d3w [8o][16i] -> [n16][k16], n>=8 zero
  for (int i = gid; i < 256; i += 8192) {
    int nn = i >> 4, k = i & 15;
    PH[H_S2D3 + i] = (nn < 8) ? f2bf(s2_d3w[nn * 16 + k]) : 0;
  }
  // s1_d1w [32o][16i] -> [o][k32], k>=16 zero
  for (int i = gid; i < 1024; i += 8192) {
    int o = i >> 5, k = i & 31;
    PH[H_S1D1 + i] = (k < 16) ? f2bf(s1_d1w[o * 16 + k]) : 0;
  }
  // s2_d1w [16o][8i] -> [o][k32], k>=8 zero
  for (int i = gid; i < 512; i += 8192) {
    int o = i >> 5, k = i & 31;
    PH[H_S2D1 + i] = (k < 8) ? f2bf(s2_d1w[o * 8 + k]) : 0;
  }
  prep_bn(s1_bn0, 16, P + SC_S1BN0, gid);
  prep_bn(s1_bn1, 32, P + SC_S1BN1, gid);
  prep_bn(s1_bn2, 32, P + SC_S1BN2, gid);
  prep_bn(s1_bn3, 16, P + SC_S1BN3, gid);
  prep_bn(s2_bn0, 8,  P + SC_S2BN0, gid);
  prep_bn(s2_bn1, 16, P + SC_S2BN1, gid);
  prep_bn(s2_bn2, 16, P + SC_S2BN2, gid);
  prep_bn(s2_bn3, 8,  P + SC_S2BN3, gid);
  if (gid < 160) lg[gid] = 0.f;                       // fc uses atomicAdd
  for (int i = gid; i < 4096; i += 8192) ms[i] = 0.f;  // stage1 mask pre-agg
}

// ---------------- stage 1: 512x512, 3 -> 16 ch, blocks 16x16 ----------------
// LDS: halo tile bf16 [18][18][40 ch-pad] (80 B/px) 25,920 B; reused flat
// [256 px][80 B] for g2, pool staging f32 [16 ch][68 w] at byte 20480.
__global__ __launch_bounds__(256, 4) void stage1_kernel(
    const float* __restrict__ x, const float* __restrict__ mask,
    const float* __restrict__ cbv, const float* __restrict__ d1b,
    const float* __restrict__ d2b, const float* __restrict__ d3b,
    const float* __restrict__ P, float* __restrict__ x1p,
    float* __restrict__ msum) {
  __shared__ __align__(16) unsigned char ldsb[25920];
  __shared__ float red_s[4], red_v[4];

  const int t = threadIdx.x;
  const int ty = t >> 4, tx = t & 15;
  const int b = blockIdx.x;
  const int n = b >> 10;
  const int by = (b >> 5) & 31, bx = b & 31;
  const int gy = by * 16 + ty, gx = bx * 16 + tx;

  // --- mask reductions: block sum (active test) + 2x2-max quadrant sum (for stage2)
  {
    const float m = mask[(size_t)(n * 512 + gy) * 512 + gx];
    float v = fmaxf(m, __shfl_xor(m, 1, 64));
    v = fmaxf(v, __shfl_xor(v, 16, 64));
    float s = m;
    #pragma unroll
    for (int off = 32; off > 0; off >>= 1) {
      s += __shfl_down(s, off, 64);
      v += __shfl_down(v, off, 64);
    }
    if ((t & 63) == 0) { red_s[t >> 6] = s; red_v[t >> 6] = v; }
  }
  __syncthreads();

  // --- input pixel (3 ch) + conv1x1 3->16 + bias, relu, bn0 (VALU)
  float xin[3];
  #pragma unroll
  for (int c = 0; c < 3; ++c)
    xin[c] = x[(size_t)((n * 3 + c) * 512 + gy) * 512 + gx];

  const float* wc = P + WT_S1C;
  const float* sc0 = P + SC_S1BN0;
  float xc[16];
  {
    float a[16];
    #pragma unroll
    for (int o = 0; o < 16; ++o) a[o] = cbv[o];
    #pragma unroll
    for (int c = 0; c < 3; ++c) {
      const float v = xin[c];
      #pragma unroll
      for (int o = 0; o < 16; ++o) a[o] = fmaf(wc[c * 16 + o], v, a[o]);
    }
    #pragma unroll
    for (int o = 0; o < 16; ++o) xc[o] = fmaf(sc0[o], relu_f(a[o]), sc0[16 + o]);
  }

  const bool active = (red_s[0] + red_s[1] + red_s[2] + red_s[3]) > 128.0f;
  if (t == 0)
    atomicAdd(&msum[n * 256 + (by >> 1) * 16 + (bx >> 1)],
              (red_v[0] + red_v[1] + red_v[2] + red_v[3]) * 0.25f);

  float* const poolf = (float*)(ldsb + 20480);  // [16 ch][68 words]

  if (active) {
    const int w = t >> 6, lane = t & 63;
    const int lr = lane & 15, cb = lane >> 4;
    const unsigned short* PH = (const unsigned short*)(P + PH_F);

    // --- zero only the halo ring (68 px x 64 B = ch 0..31)
    if (t < 68) {
      int row, col;
      if (t < 18)      { row = 0;      col = t;      }
      else if (t < 36) { row = 17;     col = t - 18; }
      else if (t < 52) { row = t - 35; col = 0;      }
      else             { row = t - 51; col = 17;     }
      uint4* z = (uint4*)(ldsb + (row * 18 + col) * 80);
      const uint4 z4 = make_uint4(0u, 0u, 0u, 0u);
      z[0] = z4; z[1] = z4; z[2] = z4; z[3] = z4;
    }
    // --- xc -> interior ch 0..15 bf16 (wave-local consumption by d1)
    {
      unsigned int pk[8];
      #pragma unroll
      for (int i = 0; i < 8; ++i) pk[i] = pk2(xc[2 * i], xc[2 * i + 1]);
      uint4* dst = (uint4*)(ldsb + ((ty + 1) * 18 + (tx + 1)) * 80);
      dst[0] = make_uint4(pk[0], pk[1], pk[2], pk[3]);
      dst[1] = make_uint4(pk[4], pk[5], pk[6], pk[7]);
    }

    // --- d1: 16->32 as MFMA 16x16x32, A=weights. K=16 zero-padded.
    {
      bf16x8 w1f[2];
      #pragma unroll
      for (int ct = 0; ct < 2; ++ct)
        w1f[ct] = *(const bf16x8*)(PH + H_S1D1 + (ct * 16 + lr) * 32 + cb * 8);
      f32x4 acc1[2][4];
      #pragma unroll
      for (int ct = 0; ct < 2; ++ct) {
        const float4 bb = *(const float4*)(d1b + ct * 16 + cb * 4);
        #pragma unroll
        for (int nt = 0; nt < 4; ++nt) {
          acc1[ct][nt][0] = bb.x; acc1[ct][nt][1] = bb.y;
          acc1[ct][nt][2] = bb.z; acc1[ct][nt][3] = bb.w;
        }
      }
      #pragma unroll
      for (int nt = 0; nt < 4; ++nt) {
        bf16x8 xcf;
        if (cb < 2) xcf = *(const bf16x8*)(ldsb + ((w * 4 + nt + 1) * 18 + lr + 1) * 80 + cb * 16);
        else        xcf = (bf16x8)(short)0;
        #pragma unroll
        for (int ct = 0; ct < 2; ++ct)
          acc1[ct][nt] = __builtin_amdgcn_mfma_f32_16x16x32_bf16(w1f[ct], xcf, acc1[ct][nt], 0, 0, 0);
      }
      // bn1 + pack co-pairs -> g1 into halo interior (ch = ct*16+cb*4+r), b64
      #pragma unroll
      for (int ct = 0; ct < 2; ++ct) {
        const float4 s1s = *(const float4*)(P + SC_S1BN1 + ct * 16 + cb * 4);
        const float4 s1h = *(const float4*)(P + SC_S1BN1 + 32 + ct * 16 + cb * 4);
        #pragma unroll
        for (int nt = 0; nt < 4; ++nt) {
          const unsigned base = ((w * 4 + nt + 1) * 18 + lr + 1) * 80 + (ct * 16 + cb * 4) * 2;
          uint2 wv;
          wv.x = pk2(fmaf(s1s.x, relu_f(acc1[ct][nt][0]), s1h.x),
                     fmaf(s1s.y, relu_f(acc1[ct][nt][1]), s1h.y));
          wv.y = pk2(fmaf(s1s.z, relu_f(acc1[ct][nt][2]), s1h.z),
                     fmaf(s1s.w, relu_f(acc1[ct][nt][3]), s1h.w));
          *(uint2*)(ldsb + base) = wv;
        }
      }
    }
    __syncthreads();

    // --- 3x3 as MFMA 32x32x16: A=weights (M=32 co), B=activations (N=32 px).
    // Wave w owns m-tiles {2w,2w+1} = pixel rows 4w..4w+3. K-step = ci half.
    const int lane31 = lane & 31;
    const int prow = lane31 >> 4, pcol = lane & 15, kh = lane >> 5;
    f32x16 acc2[2];
    {
      float4 bb2[4];
      #pragma unroll
      for (int g = 0; g < 4; ++g) bb2[g] = *(const float4*)(d2b + 8 * g + 4 * kh);
      #pragma unroll
      for (int mti = 0; mti < 2; ++mti) {
        #pragma unroll
        for (int g = 0; g < 4; ++g) {
          acc2[mti][4 * g + 0] = bb2[g].x; acc2[mti][4 * g + 1] = bb2[g].y;
          acc2[mti][4 * g + 2] = bb2[g].z; acc2[mti][4 * g + 3] = bb2[g].w;
        }
      }
    }
    #pragma clang loop unroll(disable)
    for (int dy = 0; dy < 3; ++dy) {
      bf16x8 aw[3][2];
      #pragma unroll
      for (int dx = 0; dx < 3; ++dx)
        #pragma unroll
        for (int ch = 0; ch < 2; ++ch)
          aw[dx][ch] = *(const bf16x8*)(PH + H_S1D2 + ((dy * 3 + dx) * 32 + lane31) * 32 + ch * 16 + kh * 8);
      const unsigned char* bp = ldsb + ((w * 4 + prow + dy) * 18 + pcol) * 80 + kh * 16;
      #pragma unroll
      for (int dx = 0; dx < 3; ++dx)
        #pragma unroll
        for (int mti = 0; mti < 2; ++mti)
          #pragma unroll
          for (int ch = 0; ch < 2; ++ch) {
            const bf16x8 bf = *(const bf16x8*)(bp + mti * 2880 + dx * 80 + ch * 32);
            acc2[mti] = __builtin_amdgcn_mfma_f32_32x32x16_bf16(aw[dx][ch], bf, acc2[mti], 0, 0, 0);
          }
    }
    __syncthreads();  // all waves done reading g1 tile

    // bn2 + pack -> g2 flat [pix][80 B]; lane holds pixel=lane31, co=e+8g+4kh
    #pragma unroll
    for (int mti = 0; mti < 2; ++mti) {
      const int pix = (w * 2 + mti) * 32 + lane31;
      #pragma unroll
      for (int g = 0; g < 4; ++g) {
        const float4 ss = *(const float4*)(P + SC_S1BN2 + 8 * g + 4 * kh);
        const float4 sh = *(const float4*)(P + SC_S1BN2 + 32 + 8 * g + 4 * kh);
        uint2 wv;
        wv.x = pk2(fmaf(ss.x, relu_f(acc2[mti][4 * g + 0]), sh.x),
                   fmaf(ss.y, relu_f(acc2[mti][4 * g + 1]), sh.y));
        wv.y = pk2(fmaf(ss.z, relu_f(acc2[mti][4 * g + 2]), sh.z),
                   fmaf(ss.w, relu_f(acc2[mti][4 * g + 3]), sh.w));
        *(uint2*)(ldsb + pix * 80 + (8 * g + 4 * kh) * 2) = wv;
      }
    }
    __syncthreads();

    // --- d3: 32->16 as MFMA 16x16x32 (A=activations), then bn3 + in-lane pool
    const bf16x8 b3 = *(const bf16x8*)(PH + H_S1D3 + lr * 32 + cb * 8);
    const float bias3v = d3b[lr];
    const float sc3v = P[SC_S1BN3 + lr], sh3v = P[SC_S1BN3 + 16 + lr];
    f32x4 acc3[4];
    #pragma unroll
    for (int mt = 0; mt < 4; ++mt) {
      acc3[mt][0] = bias3v; acc3[mt][1] = bias3v; acc3[mt][2] = bias3v; acc3[mt][3] = bias3v;
      const bf16x8 a3 = *(const bf16x8*)(ldsb + (w * 64 + mt * 16 + lr) * 80 + cb * 16);
      acc3[mt] = __builtin_amdgcn_mfma_f32_16x16x32_bf16(a3, b3, acc3[mt], 0, 0, 0);
    }
    #pragma unroll
    for (int mtp = 0; mtp < 2; ++mtp) {
      float o0[4], o1[4];
      #pragma unroll
      for (int r = 0; r < 4; ++r) {
        o0[r] = fmaf(sc3v, relu_f(acc3[2 * mtp][r]), sh3v);
        o1[r] = fmaf(sc3v, relu_f(acc3[2 * mtp + 1][r]), sh3v);
      }
      #pragma unroll
      for (int rp = 0; rp < 2; ++rp) {
        const float m = fmaxf(fmaxf(o0[2 * rp], o0[2 * rp + 1]),
                              fmaxf(o1[2 * rp], o1[2 * rp + 1]));
        poolf[lr * 68 + (w * 2 + mtp) * 8 + cb * 2 + rp] = m;
      }
    }
  } else {
    // inactive: out = xc; pool via LDS f32 view
    float* ldsf = (float*)ldsb;  // [256][20] = 20480 B
    {
      float* pw = &ldsf[t * 20];
      #pragma unroll
      for (int c = 0; c < 16; ++c) pw[c] = xc[c];
    }
    __syncthreads();
    {
      const int pp = t & 63, cg = t >> 6;
      const int py = pp >> 3, px = pp & 7;
      const float* r0 = &ldsf[((2 * py) * 16 + 2 * px) * 20 + cg * 4];
      const float* r2 = &ldsf[((2 * py + 1) * 16 + 2 * px) * 20 + cg * 4];
      const float4 v0 = *(const float4*)(r0);
      const float4 v1 = *(const float4*)(r0 + 20);
      const float4 v2 = *(const float4*)(r2);
      const float4 v3 = *(const float4*)(r2 + 20);
      poolf[(cg * 4 + 0) * 68 + py * 8 + px] = fmaxf(fmaxf(v0.x, v1.x), fmaxf(v2.x, v3.x));
      poolf[(cg * 4 + 1) * 68 + py * 8 + px] = fmaxf(fmaxf(v0.y, v1.y), fmaxf(v2.y, v3.y));
      poolf[(cg * 4 + 2) * 68 + py * 8 + px] = fmaxf(fmaxf(v0.z, v1.z), fmaxf(v2.z, v3.z));
      poolf[(cg * 4 + 3) * 68 + py * 8 + px] = fmaxf(fmaxf(v0.w, v1.w), fmaxf(v2.w, v3.w));
    }
  }

  __syncthreads();
  // --- coalesced store: [16 ch][8 y][8 x] -> x1p, uint4 per thread
  {
    const int ch = t >> 4, idx = t & 15, yy = idx >> 1, h = idx & 1;
    const uint4 v = *(const uint4*)(poolf + ch * 68 + yy * 8 + h * 4);
    const size_t ob = ((((size_t)n * 16 + (by >> 1)) * 16 + (bx >> 1)) * 16 + ch) * 256
                      + (size_t)((by & 1) * 8 + yy) * 16 + (bx & 1) * 8 + h * 4;
    *(uint4*)(x1p + ob) = v;
  }
}

// ---------------- stage 2: 256x256, 16 -> 8 ch, blocks 16x16 ----------------
// LDS: halo tile bf16 [18][18][24 ch-pad] (48 B/px) 15,552 B; g2 flat
// [256][48 B]; pool staging f32 [8 ch][68 w] at byte 12288.
// Active test from stage1's pre-aggregated msum (no mask reads, no barriers).
__global__ __launch_bounds__(256, 5) void stage2_kernel(
    const float* __restrict__ msum,
    const float* __restrict__ cbv, const float* __restrict__ d1b,
    const float* __restrict__ d2b, const float* __restrict__ d3b,
    const float* __restrict__ P, const float* __restrict__ x1p,
    float* __restrict__ x2) {
  __shared__ __align__(16) unsigned char ldsb2[15552];

  const int t = threadIdx.x;
  const int ty = t >> 4, tx = t & 15;
  const int b = blockIdx.x;
  const int n = b >> 8;
  const int BY = (b >> 4) & 15, BX = b & 15;

  const bool active = msum[b] > 128.0f;  // b == n*256 + BY*16 + BX

  // load x1 (16 ch) from pre-blocked layout
  const float* xb = x1p + (size_t)b * 4096 + ty * 16 + tx;
  float xin[16];
  #pragma unroll
  for (int c = 0; c < 16; ++c) xin[c] = xb[c * 256];

  // conv1x1 16->8 + bias, relu, bn0 (VALU)
  const float* wc = P + WT_S2C;
  const float* sc0 = P + SC_S2BN0;
  float xc[8];
  {
    float a[8];
    #pragma unroll
    for (int o = 0; o < 8; ++o) a[o] = cbv[o];
    #pragma unroll
    for (int c = 0; c < 16; ++c) {
      const float v = xin[c];
      #pragma unroll
      for (int o = 0; o < 8; ++o) a[o] = fmaf(wc[c * 8 + o], v, a[o]);
    }
    #pragma unroll
    for (int o = 0; o < 8; ++o) xc[o] = fmaf(sc0[o], relu_f(a[o]), sc0[8 + o]);
  }

  float* const poolf = (float*)(ldsb2 + 12288);  // [8 ch][68 words]

  if (active) {
    const int w = t >> 6, lane = t & 63;
    const int lr = lane & 15, cb = lane >> 4;
    const unsigned short* PH = (const unsigned short*)(P + PH_F);

    // ring zero (68 px x 32 B = ch 0..15)
    if (t < 68) {
      int row, col;
      if (t < 18)      { row = 0;      col = t;      }
      else if (t < 36) { row = 17;     col = t - 18; }
      else if (t < 52) { row = t - 35; col = 0;      }
      else             { row = t - 51; col = 17;     }
      uint4* z = (uint4*)(ldsb2 + (row * 18 + col) * 48);
      const uint4 z4 = make_uint4(0u, 0u, 0u, 0u);
      z[0] = z4; z[1] = z4;
    }
    // xc (8 ch) -> interior bf16
    {
      unsigned int pk[4];
      #pragma unroll
      for (int i = 0; i < 4; ++i) pk[i] = pk2(xc[2 * i], xc[2 * i + 1]);
      *(uint4*)(ldsb2 + ((ty + 1) * 18 + (tx + 1)) * 48) = make_uint4(pk[0], pk[1], pk[2], pk[3]);
    }

    // d1: 8->16 as MFMA, A=weights, K=8 zero-padded
    {
      const bf16x8 w1f = *(const bf16x8*)(PH + H_S2D1 + lr * 32 + cb * 8);
      f32x4 acc1[4];
      {
        const float4 bb = *(const float4*)(d1b + cb * 4);
        #pragma unroll
        for (int nt = 0; nt < 4; ++nt) {
          acc1[nt][0] = bb.x; acc1[nt][1] = bb.y; acc1[nt][2] = bb.z; acc1[nt][3] = bb.w;
        }
      }
      #pragma unroll
      for (int nt = 0; nt < 4; ++nt) {
        bf16x8 xcf;
        if (cb == 0) xcf = *(const bf16x8*)(ldsb2 + ((w * 4 + nt + 1) * 18 + lr + 1) * 48);
        else         xcf = (bf16x8)(short)0;
        acc1[nt] = __builtin_amdgcn_mfma_f32_16x16x32_bf16(w1f, xcf, acc1[nt], 0, 0, 0);
      }
      {
        const float4 s1s = *(const float4*)(P + SC_S2BN1 + cb * 4);
        const float4 s1h = *(const float4*)(P + SC_S2BN1 + 16 + cb * 4);
        #pragma unroll
        for (int nt = 0; nt < 4; ++nt) {
          const unsigned base = ((w * 4 + nt + 1) * 18 + lr + 1) * 48 + cb * 8;
          uint2 wv;
          wv.x = pk2(fmaf(s1s.x, relu_f(acc1[nt][0]), s1h.x),
                     fmaf(s1s.y, relu_f(acc1[nt][1]), s1h.y));
          wv.y = pk2(fmaf(s1s.z, relu_f(acc1[nt][2]), s1h.z),
                     fmaf(s1s.w, relu_f(acc1[nt][3]), s1h.w));
          *(uint2*)(ldsb2 + base) = wv;
        }
      }
    }
    __syncthreads();

    // 3x3 as MFMA: 5 tap-pairs per K=32; lane's tap = 2p + (cb>>1); weights streamed
    f32x4 acc2[4];
    {
      const float4 bb = *(const float4*)(d2b + cb * 4);
      #pragma unroll
      for (int nt = 0; nt < 4; ++nt) {
        acc2[nt][0] = bb.x; acc2[nt][1] = bb.y; acc2[nt][2] = bb.z; acc2[nt][3] = bb.w;
      }
    }
    #pragma clang loop unroll(disable)
    for (int p = 0; p < 5; ++p) {
      const bf16x8 bwp = *(const bf16x8*)(PH + H_S2D2 + (p * 16 + lr) * 32 + cb * 8);
      const int tp = (p < 4) ? (2 * p + (cb >> 1)) : 8;
      const int dy = (tp >= 6) ? 2 : ((tp >= 3) ? 1 : 0);
      const int dx = tp - dy * 3;
      #pragma unroll
      for (int nt = 0; nt < 4; ++nt) {
        const bf16x8 af = *(const bf16x8*)(ldsb2 + ((w * 4 + nt + dy) * 18 + lr + dx) * 48 + (cb & 1) * 16);
        acc2[nt] = __builtin_amdgcn_mfma_f32_16x16x32_bf16(bwp, af, acc2[nt], 0, 0, 0);
      }
    }
    __syncthreads();

    // bn2 + pack -> g2 flat [pix][48 B]
    {
      const float4 s2s = *(const float4*)(P + SC_S2BN2 + cb * 4);
      const float4 s2h = *(const float4*)(P + SC_S2BN2 + 16 + cb * 4);
      #pragma unroll
      for (int nt = 0; nt < 4; ++nt) {
        const int pix = w * 64 + nt * 16 + lr;
        const unsigned base = pix * 48 + cb * 8;
        uint2 wv;
        wv.x = pk2(fmaf(s2s.x, relu_f(acc2[nt][0]), s2h.x),
                   fmaf(s2s.y, relu_f(acc2[nt][1]), s2h.y));
        wv.y = pk2(fmaf(s2s.z, relu_f(acc2[nt][2]), s2h.z),
                   fmaf(s2s.w, relu_f(acc2[nt][3]), s2h.w));
        *(uint2*)(ldsb2 + base) = wv;
      }
    }
    __syncthreads();

    // d3: 16->8 as MFMA (K=16 zero-padded both sides)
    bf16x8 b3;
    if (cb < 2) b3 = *(const bf16x8*)(PH + H_S2D3 + lr * 16 + cb * 8);
    else        b3 = (bf16x8)(short)0;
    const float bias3v = (lr < 8) ? d3b[lr] : 0.f;
    const float sc3v = (lr < 8) ? P[SC_S2BN3 + lr] : 0.f;
    const float sh3v = (lr < 8) ? P[SC_S2BN3 + 8 + lr] : 0.f;
    f32x4 acc3[4];
    #pragma unroll
    for (int mt = 0; mt < 4; ++mt) {
      acc3[mt][0] = bias3v; acc3[mt][1] = bias3v; acc3[mt][2] = bias3v; acc3[mt][3] = bias3v;
      bf16x8 a3;
      if (cb < 2) a3 = *(const bf16x8*)(ldsb2 + (w * 64 + mt * 16 + lr) * 48 + cb * 16);
      else        a3 = (bf16x8)(short)0;
      acc3[mt] = __builtin_amdgcn_mfma_f32_16x16x32_bf16(a3, b3, acc3[mt], 0, 0, 0);
    }
    if (lr < 8) {
      #pragma unroll
      for (int mtp = 0; mtp < 2; ++mtp) {
        float o0[4], o1[4];
        #pragma unroll
        for (int r = 0; r < 4; ++r) {
          o0[r] = fmaf(sc3v, relu_f(acc3[2 * mtp][r]), sh3v);
          o1[r] = fmaf(sc3v, relu_f(acc3[2 * mtp + 1][r]), sh3v);
        }
        #pragma unroll
        for (int rp = 0; rp < 2; ++rp) {
          const float m = fmaxf(fmaxf(o0[2 * rp], o0[2 * rp + 1]),
                                fmaxf(o1[2 * rp], o1[2 * rp + 1]));
          poolf[lr * 68 + (w * 2 + mtp) * 8 + cb * 2 + rp] = m;
        }
      }
    }
  } else {
    float* ldsf = (float*)ldsb2;  // [256][12] = 12288 B
    {
      float* pw = &ldsf[t * 12];
      #pragma unroll
      for (int c = 0; c < 8; ++c) pw[c] = xc[c];
    }
    __syncthreads();
    if (t < 128) {
      const int pp = t & 63, cg = t >> 6;
      const int py = pp >> 3, px = pp & 7;
      const float* r0 = &ldsf[((2 * py) * 16 + 2 * px) * 12 + cg * 4];
      const float* r2 = &ldsf[((2 * py + 1) * 16 + 2 * px) * 12 + cg * 4];
      const float4 v0 = *(const float4*)(r0);
      const float4 v1 = *(const float4*)(r0 + 12);
      const float4 v2 = *(const float4*)(r2);
      const float4 v3 = *(const float4*)(r2 + 12);
      poolf[(cg * 4 + 0) * 68 + py * 8 + px] = fmaxf(fmaxf(v0.x, v1.x), fmaxf(v2.x, v3.x));
      poolf[(cg * 4 + 1) * 68 + py * 8 + px] = fmaxf(fmaxf(v0.y, v1.y), fmaxf(v2.y, v3.y));
      poolf[(cg * 4 + 2) * 68 + py * 8 + px] = fmaxf(fmaxf(v0.z, v1.z), fmaxf(v2.z, v3.z));
      poolf[(cg * 4 + 3) * 68 + py * 8 + px] = fmaxf(fmaxf(v0.w, v1.w), fmaxf(v2.w, v3.w));
    }
  }

  __syncthreads();
  // coalesced store: [8 ch][8 y][8 x] -> x2 NCHW, uint4 per thread
  if (t < 128) {
    const int ch = t >> 4, idx = t & 15, yy = idx >> 1, h = idx & 1;
    const uint4 v = *(const uint4*)(poolf + ch * 68 + yy * 8 + h * 4);
    const size_t ob = ((size_t)(n * 8 + ch) * 128 + (BY * 8 + yy)) * 128 + BX * 8 + h * 4;
    *(uint4*)(x2 + ob) = v;
  }
}

// ---------------- FC (split-K x8, atomicAdd) + softmax ----------------
__global__ __launch_bounds__(256) void fc_kernel(const float* __restrict__ x2,
                                                 const float* __restrict__ fcw,
                                                 const float* __restrict__ fcb,
                                                 float* __restrict__ logits) {
  __shared__ float red[4];
  const int wg = blockIdx.x, t = threadIdx.x;
  const int sp = wg & 7, k = (wg >> 3) % 10, n = wg / 80;
  const float4* xa = (const float4*)(x2 + (size_t)n * 131072) + sp * 4096;
  const float4* wa = (const float4*)(fcw + (size_t)k * 131072) + sp * 4096;
  float s = 0.f;
  #pragma unroll 4
  for (int i = t; i < 4096; i += 256) {
    const float4 a = xa[i], b = wa[i];
    s = fmaf(a.x, b.x, fmaf(a.y, b.y, fmaf(a.z, b.z, fmaf(a.w, b.w, s))));
  }
  #pragma unroll
  for (int off = 32; off > 0; off >>= 1) s += __shfl_down(s, off, 64);
  if ((t & 63) == 0) red[t >> 6] = s;
  __syncthreads();
  if (t == 0) {
    float tot = red[0] + red[1] + red[2] + red[3];
    if (sp == 0) tot += fcb[k];
    atomicAdd(&logits[n * 10 + k], tot);
  }
}

__global__ void softmax_kernel(const float* __restrict__ logits, float* __restrict__ out) {
  const int t = threadIdx.x;
  if (t < 16) {
    float l[10], mx = -1e30f;
    #pragma unroll
    for (int k = 0; k < 10; ++k) { l[k] = logits[t * 10 + k]; mx = fmaxf(mx, l[k]); }
    float sum = 0.f;
    #pragma unroll
    for (int k = 0; k < 10; ++k) { l[k] = expf(l[k] - mx); sum += l[k]; }
    const float inv = 1.f / sum;
    #pragma unroll
    for (int k = 0; k < 10; ++k) out[t * 10 + k] = l[k] * inv;
  }
}

extern "C" void kernel_launch(void* const* d_in, const int* in_sizes, int n_in,
                              void* d_out, int out_size, void* d_ws, size_t ws_size,
                              hipStream_t stream) {
  const float* x      = (const float*)d_in[0];
  const float* mask   = (const float*)d_in[1];
  const float* s1_cw  = (const float*)d_in[2];
  const float* s1_cb  = (const float*)d_in[3];
  const float* s1_bn0 = (const float*)d_in[4];
  const float* s1_d1w = (const float*)d_in[5];
  const float* s1_d1b = (const float*)d_in[6];
  const float* s1_bn1 = (const float*)d_in[7];
  const float* s1_d2w = (const float*)d_in[8];
  const float* s1_d2b = (const float*)d_in[9];
  const float* s1_bn2 = (const float*)d_in[10];
  const float* s1_d3w = (const float*)d_in[11];
  const float* s1_d3b = (const float*)d_in[12];
  const float* s1_bn3 = (const float*)d_in[13];
  const float* s2_cw  = (const float*)d_in[14];
  const float* s2_cb  = (const float*)d_in[15];
  const float* s2_bn0 = (const float*)d_in[16];
  const float* s2_d1w = (const float*)d_in[17];
  const float* s2_d1b = (const float*)d_in[18];
  const float* s2_bn1 = (const float*)d_in[19];
  const float* s2_d2w = (const float*)d_in[20];
  const float* s2_d2b = (const float*)d_in[21];
  const float* s2_bn2 = (const float*)d_in[22];
  const float* s2_d3w = (const float*)d_in[23];
  const float* s2_d3b = (const float*)d_in[24];
  const float* s2_bn3 = (const float*)d_in[25];
  const float* fc_w   = (const float*)d_in[26];
  const float* fc_b   = (const float*)d_in[27];

  float* ws  = (float*)d_ws;
  float* x1p = ws + X1P_OFF;
  float* x2  = ws + X2_OFF;
  float* lg  = ws + LG_OFF;
  float* ms  = ws + MS_OFF;
  float* P   = ws + P_OFF;

  prep_kernel<<<32, 256, 0, stream>>>(s1_cw, s1_d1w, s1_d2w, s1_d3w,
                                      s2_cw, s2_d1w, s2_d2w, s2_d3w,
                                      s1_bn0, s1_bn1, s1_bn2, s1_bn3,
                                      s2_bn0, s2_bn1, s2_bn2, s2_bn3, P, lg, ms);
  stage1_kernel<<<16 * 32 * 32, 256, 0, stream>>>(x, mask, s1_cb, s1_d1b, s1_d2b, s1_d3b, P, x1p, ms);
  stage2_kernel<<<16 * 16 * 16, 256, 0, stream>>>(ms, s2_cb, s2_d1b, s2_d2b, s2_d3b, P, x1p, x2);
  fc_kernel<<<1280, 256, 0, stream>>>(x2, fc_w, fc_b, lg);
  softmax_kernel<<<1, 64, 0, stream>>>(lg, (float*)d_out);
}

// Round 8
// 270.749 us; speedup vs baseline: 3.2468x; 1.0210x over previous
//
#include <hip/hip_runtime.h>
#include <math.h>

// ---------------------------------------------------------------------------
// FastNN: sparse block conv net. MFMA v5 (bf16 interstage + 32x32 d1).
// One 256-thread WG per 16x16 block, fused: conv1x1 (VALU) -> [active?
// d1 1x1 (MFMA 32x32x16, K=16 native) -> 3x3 (MFMA 32x32x16) -> d3 1x1
// (MFMA 16x16, in-lane pool)] -> maxpool2 -> coalesced bf16 store.
// x1p is bf16 (halves stage1 write + stage2 read HBM traffic).
// 32x32 layouts (m74/m101-verified): D col=lane&31, row=(reg&3)+8*(reg>>2)
// +4*(lane>>5); A/B: row/col=lane&31, k=(lane>>5)*8+j (symmetric, cancels).
// stage1 pre-aggregates maxpool2(mask) sums for stage2 (msum atomicAdd).
// ---------------------------------------------------------------------------

typedef __attribute__((ext_vector_type(8))) short bf16x8;
typedef __attribute__((ext_vector_type(4))) float f32x4;
typedef __attribute__((ext_vector_type(16))) float f32x16;

// ws layout
#define X1P_USH_OFF 0       // ush[16*256*4096] stage1 pooled bf16, pre-blocked (8,388,608 floats)
#define X2_OFF  8388608     // float [16][8][128][128] stage2 pooled, NCHW
#define LG_OFF  10485760    // 160 logits
#define MS_OFF  10486016    // [16][16][16] stage2-block mask sums (4096)
#define P_OFF   10490112    // prepped params (f32 region, then bf16 region)

// f32 param region offsets (floats, within P)
enum : int {
  WT_S1C  = 0,      // [ci3][co16]  = 48
  WT_S2C  = 48,     // [ci16][co8]  = 128
  SC_S1BN0 = 176,   // scale16+shift16
  SC_S1BN1 = 208,   // 32+32
  SC_S1BN2 = 272,   // 32+32
  SC_S1BN3 = 336,   // 16+16
  SC_S2BN0 = 368,   // 8+8
  SC_S2BN1 = 384,   // 16+16
  SC_S2BN2 = 416,   // 16+16
  SC_S2BN3 = 448,   // 8+8
  PH_F     = 464    // bf16 (ushort) region starts here (float offset)
};
// bf16 region offsets (ushorts, within PH)
enum : int {
  H_S1D2 = 0,       // [9 tap][32 co][32 ci] = 9216
  H_S1D3 = 9216,    // [16 co][32 ci]        = 512
  H_S2D2 = 9728,    // [5 pair][16 co][32 k] = 2560 (k<16: tap 2p, else 2p+1; pair4 hi=0)
  H_S2D3 = 12288,   // [16 n][16 k]          = 256  (n>=8 zero)
  H_S1D1 = 12544,   // [32 co][16 k]         = 512  (32x32x16 A operand)
  H_S2D1 = 13568,   // [32 co][16 k]         = 512  (co>=16 or k>=8 zero)
  PH_END = 14080
};

__device__ __forceinline__ float relu_f(float v) { return v > 0.f ? v : 0.f; }

__device__ __forceinline__ unsigned short f2bf(float f) {
  unsigned int u = __float_as_uint(f);
  unsigned int r = (u + 0x7fffu + ((u >> 16) & 1u)) >> 16;  // RNE
  return (unsigned short)r;
}

// packed pair: low half = lo, high half = hi (v_cvt_pk_bf16_f32, RNE)
__device__ __forceinline__ unsigned int pk2(float lo, float hi) {
  unsigned int r;
  asm("v_cvt_pk_bf16_f32 %0, %1, %2" : "=v"(r) : "v"(lo), "v"(hi));
  return r;
}

__device__ __forceinline__ float bf2f(unsigned short u) {
  return __uint_as_float((unsigned int)u << 16);
}

__device__ __forceinline__ void prep_bn(const float* __restrict__ p, int C,
                                        float* __restrict__ dst, int gid) {
  for (int i = gid; i < C; i += 8192) {
    float g = p[i], b = p[C + i], m = p[2 * C + i], v = p[3 * C + i];
    float s = g / sqrtf(v + 1e-5f);
    dst[i] = s;
    dst[C + i] = b - s * m;
  }
}

// grid = 32 blocks x 256 (stride 8192)
__global__ __launch_bounds__(256) void prep_kernel(
    const float* __restrict__ s1_cw, const float* __restrict__ s1_d1w,
    const float* __restrict__ s1_d2w, const float* __restrict__ s1_d3w,
    const float* __restrict__ s2_cw, const float* __restrict__ s2_d1w,
    const float* __restrict__ s2_d2w, const float* __restrict__ s2_d3w,
    const float* __restrict__ s1_bn0, const float* __restrict__ s1_bn1,
    const float* __restrict__ s1_bn2, const float* __restrict__ s1_bn3,
    const float* __restrict__ s2_bn0, const float* __restrict__ s2_bn1,
    const float* __restrict__ s2_bn2, const float* __restrict__ s2_bn3,
    float* __restrict__ P, float* __restrict__ lg, float* __restrict__ ms) {
  const int gid = blockIdx.x * 256 + threadIdx.x;
  unsigned short* PH = (unsigned short*)(P + PH_F);
  // f32 weights for VALU conv0s
  for (int i = gid; i < 48;  i += 8192) { int co = i / 3,  ci = i % 3;  P[WT_S1C + ci * 16 + co] = s1_cw[i]; }
  for (int i = gid; i < 128; i += 8192) { int co = i / 16, ci = i % 16; P[WT_S2C + ci * 8  + co] = s2_cw[i]; }
  // s1_d2w [32o][32i][3][3] -> [tap][o][i]
  for (int i = gid; i < 9216; i += 8192) {
    int tap = i >> 10, o = (i >> 5) & 31, ci = i & 31;
    PH[H_S1D2 + i] = f2bf(s1_d2w[o * 288 + ci * 9 + tap]);
  }
  // s1_d3w [16o][32i] -> [o][i]
  for (int i = gid; i < 512; i += 8192) PH[H_S1D3 + i] = f2bf(s1_d3w[i]);
  // s2_d2w [16o][16i][3][3] -> [pair][o][k32]
  for (int i = gid; i < 2560; i += 8192) {
    int p = i >> 9, o = (i >> 5) & 15, k = i & 31;
    int tp = 2 * p + (k >> 4);
    PH[H_S2D2 + i] = (tp < 9) ? f2bf(s2_d2w[o * 144 + (k & 15) * 9 + tp]) : 0;
  }
  // s2_d3w [8o][16i] -> [n16][k16], n>=8 zero
  for (int i = gid; i < 256; i += 8192) {
    int nn = i >> 4, k = i & 15;
    PH[H_S2D3 + i] = (nn < 8) ? f2bf(s2_d3w[nn * 16 + k]) : 0;
  }
  // s1_d1w [32o][16i] -> [co][16k] direct bf16 copy (32x32x16 A operand)
  for (int i = gid; i < 512; i += 8192) PH[H_S1D1 + i] = f2bf(s1_d1w[i]);
  // s2_d1w [16o][8i] -> [32co][16k], co>=16 or k>=8 zero
  for (int i = gid; i < 512; i += 8192) {
    int co = i >> 4, k = i & 15;
    PH[H_S2D1 + i] = (co < 16 && k < 8) ? f2bf(s2_d1w[co * 8 + k]) : 0;
  }
  prep_bn(s1_bn0, 16, P + SC_S1BN0, gid);
  prep_bn(s1_bn1, 32, P + SC_S1BN1, gid);
  prep_bn(s1_bn2, 32, P + SC_S1BN2, gid);
  prep_bn(s1_bn3, 16, P + SC_S1BN3, gid);
  prep_bn(s2_bn0, 8,  P + SC_S2BN0, gid);
  prep_bn(s2_bn1, 16, P + SC_S2BN1, gid);
  prep_bn(s2_bn2, 16, P + SC_S2BN2, gid);
  prep_bn(s2_bn3, 8,  P + SC_S2BN3, gid);
  if (gid < 160) lg[gid] = 0.f;                       // fc uses atomicAdd
  for (int i = gid; i < 4096; i += 8192) ms[i] = 0.f;  // stage1 mask pre-agg
}

// ---------------- stage 1: 512x512, 3 -> 16 ch, blocks 16x16 ----------------
// LDS: halo tile bf16 [18][18][40 ch-pad] (80 B/px) 25,920 B; reused flat
// [256 px][80 B] for g2, pool staging f32 [16 ch][68 w] at byte 20480.
__global__ __launch_bounds__(256, 4) void stage1_kernel(
    const float* __restrict__ x, const float* __restrict__ mask,
    const float* __restrict__ cbv, const float* __restrict__ d1b,
    const float* __restrict__ d2b, const float* __restrict__ d3b,
    const float* __restrict__ P, unsigned short* __restrict__ x1p,
    float* __restrict__ msum) {
  __shared__ __align__(16) unsigned char ldsb[25920];
  __shared__ float red_s[4], red_v[4];

  const int t = threadIdx.x;
  const int ty = t >> 4, tx = t & 15;
  const int b = blockIdx.x;
  const int n = b >> 10;
  const int by = (b >> 5) & 31, bx = b & 31;
  const int gy = by * 16 + ty, gx = bx * 16 + tx;

  // --- mask reductions: block sum (active test) + 2x2-max quadrant sum (for stage2)
  {
    const float m = mask[(size_t)(n * 512 + gy) * 512 + gx];
    float v = fmaxf(m, __shfl_xor(m, 1, 64));
    v = fmaxf(v, __shfl_xor(v, 16, 64));
    float s = m;
    #pragma unroll
    for (int off = 32; off > 0; off >>= 1) {
      s += __shfl_down(s, off, 64);
      v += __shfl_down(v, off, 64);
    }
    if ((t & 63) == 0) { red_s[t >> 6] = s; red_v[t >> 6] = v; }
  }
  __syncthreads();

  // --- input pixel (3 ch) + conv1x1 3->16 + bias, relu, bn0 (VALU)
  float xin[3];
  #pragma unroll
  for (int c = 0; c < 3; ++c)
    xin[c] = x[(size_t)((n * 3 + c) * 512 + gy) * 512 + gx];

  const float* wc = P + WT_S1C;
  const float* sc0 = P + SC_S1BN0;
  float xc[16];
  {
    float a[16];
    #pragma unroll
    for (int o = 0; o < 16; ++o) a[o] = cbv[o];
    #pragma unroll
    for (int c = 0; c < 3; ++c) {
      const float v = xin[c];
      #pragma unroll
      for (int o = 0; o < 16; ++o) a[o] = fmaf(wc[c * 16 + o], v, a[o]);
    }
    #pragma unroll
    for (int o = 0; o < 16; ++o) xc[o] = fmaf(sc0[o], relu_f(a[o]), sc0[16 + o]);
  }

  const bool active = (red_s[0] + red_s[1] + red_s[2] + red_s[3]) > 128.0f;
  if (t == 0)
    atomicAdd(&msum[n * 256 + (by >> 1) * 16 + (bx >> 1)],
              (red_v[0] + red_v[1] + red_v[2] + red_v[3]) * 0.25f);

  float* const poolf = (float*)(ldsb + 20480);  // [16 ch][68 words]

  if (active) {
    const int w = t >> 6, lane = t & 63;
    const int lr = lane & 15, cb = lane >> 4;
    const int lane31 = lane & 31, kh = lane >> 5;
    const unsigned short* PH = (const unsigned short*)(P + PH_F);

    // --- zero only the halo ring (68 px x 64 B = ch 0..31)
    if (t < 68) {
      int row, col;
      if (t < 18)      { row = 0;      col = t;      }
      else if (t < 36) { row = 17;     col = t - 18; }
      else if (t < 52) { row = t - 35; col = 0;      }
      else             { row = t - 51; col = 17;     }
      uint4* z = (uint4*)(ldsb + (row * 18 + col) * 80);
      const uint4 z4 = make_uint4(0u, 0u, 0u, 0u);
      z[0] = z4; z[1] = z4; z[2] = z4; z[3] = z4;
    }
    // --- xc -> interior ch 0..15 bf16 (wave-local consumption by d1)
    {
      unsigned int pk[8];
      #pragma unroll
      for (int i = 0; i < 8; ++i) pk[i] = pk2(xc[2 * i], xc[2 * i + 1]);
      uint4* dst = (uint4*)(ldsb + ((ty + 1) * 18 + (tx + 1)) * 80);
      dst[0] = make_uint4(pk[0], pk[1], pk[2], pk[3]);
      dst[1] = make_uint4(pk[4], pk[5], pk[6], pk[7]);
    }

    // --- d1: 16->32 as MFMA 32x32x16 (K=16 native). A=weights [32co][16k],
    // B=xc (col=pixel, k=ci). Wave w owns pixels 64w..64w+63 (2 n-tiles).
    {
      const bf16x8 w1f = *(const bf16x8*)(PH + H_S1D1 + lane31 * 16 + kh * 8);
      f32x16 acc1[2];
      #pragma unroll
      for (int nt = 0; nt < 2; ++nt)
        #pragma unroll
        for (int g = 0; g < 4; ++g) {
          const float4 bb = *(const float4*)(d1b + 8 * g + 4 * kh);
          acc1[nt][4 * g + 0] = bb.x; acc1[nt][4 * g + 1] = bb.y;
          acc1[nt][4 * g + 2] = bb.z; acc1[nt][4 * g + 3] = bb.w;
        }
      #pragma unroll
      for (int nt = 0; nt < 2; ++nt) {
        const int p = w * 64 + nt * 32 + lane31;
        const bf16x8 xcf = *(const bf16x8*)(ldsb + (((p >> 4) + 1) * 18 + (p & 15) + 1) * 80 + kh * 16);
        acc1[nt] = __builtin_amdgcn_mfma_f32_32x32x16_bf16(w1f, xcf, acc1[nt], 0, 0, 0);
      }
      // bn1 + pack -> g1 into halo interior (co = e + 8g + 4kh)
      #pragma unroll
      for (int nt = 0; nt < 2; ++nt) {
        const int p = w * 64 + nt * 32 + lane31;
        const unsigned pbase = (((p >> 4) + 1) * 18 + (p & 15) + 1) * 80;
        #pragma unroll
        for (int g = 0; g < 4; ++g) {
          const float4 ss = *(const float4*)(P + SC_S1BN1 + 8 * g + 4 * kh);
          const float4 sh = *(const float4*)(P + SC_S1BN1 + 32 + 8 * g + 4 * kh);
          uint2 wv;
          wv.x = pk2(fmaf(ss.x, relu_f(acc1[nt][4 * g + 0]), sh.x),
                     fmaf(ss.y, relu_f(acc1[nt][4 * g + 1]), sh.y));
          wv.y = pk2(fmaf(ss.z, relu_f(acc1[nt][4 * g + 2]), sh.z),
                     fmaf(ss.w, relu_f(acc1[nt][4 * g + 3]), sh.w));
          *(uint2*)(ldsb + pbase + (8 * g + 4 * kh) * 2) = wv;
        }
      }
    }
    __syncthreads();

    // --- 3x3 as MFMA 32x32x16: A=weights (M=32 co), B=activations (N=32 px).
    // Wave w owns m-tiles {2w,2w+1} = pixel rows 4w..4w+3. K-step = ci half.
    const int prow = lane31 >> 4, pcol = lane & 15;
    f32x16 acc2[2];
    {
      float4 bb2[4];
      #pragma unroll
      for (int g = 0; g < 4; ++g) bb2[g] = *(const float4*)(d2b + 8 * g + 4 * kh);
      #pragma unroll
      for (int mti = 0; mti < 2; ++mti) {
        #pragma unroll
        for (int g = 0; g < 4; ++g) {
          acc2[mti][4 * g + 0] = bb2[g].x; acc2[mti][4 * g + 1] = bb2[g].y;
          acc2[mti][4 * g + 2] = bb2[g].z; acc2[mti][4 * g + 3] = bb2[g].w;
        }
      }
    }
    #pragma clang loop unroll(disable)
    for (int dy = 0; dy < 3; ++dy) {
      bf16x8 aw[3][2];
      #pragma unroll
      for (int dx = 0; dx < 3; ++dx)
        #pragma unroll
        for (int ch = 0; ch < 2; ++ch)
          aw[dx][ch] = *(const bf16x8*)(PH + H_S1D2 + ((dy * 3 + dx) * 32 + lane31) * 32 + ch * 16 + kh * 8);
      const unsigned char* bp = ldsb + ((w * 4 + prow + dy) * 18 + pcol) * 80 + kh * 16;
      #pragma unroll
      for (int dx = 0; dx < 3; ++dx)
        #pragma unroll
        for (int mti = 0; mti < 2; ++mti)
          #pragma unroll
          for (int ch = 0; ch < 2; ++ch) {
            const bf16x8 bf = *(const bf16x8*)(bp + mti * 2880 + dx * 80 + ch * 32);
            acc2[mti] = __builtin_amdgcn_mfma_f32_32x32x16_bf16(aw[dx][ch], bf, acc2[mti], 0, 0, 0);
          }
    }
    __syncthreads();  // all waves done reading g1 tile

    // bn2 + pack -> g2 flat [pix][80 B]; lane holds pixel=lane31, co=e+8g+4kh
    #pragma unroll
    for (int mti = 0; mti < 2; ++mti) {
      const int pix = (w * 2 + mti) * 32 + lane31;
      #pragma unroll
      for (int g = 0; g < 4; ++g) {
        const float4 ss = *(const float4*)(P + SC_S1BN2 + 8 * g + 4 * kh);
        const float4 sh = *(const float4*)(P + SC_S1BN2 + 32 + 8 * g + 4 * kh);
        uint2 wv;
        wv.x = pk2(fmaf(ss.x, relu_f(acc2[mti][4 * g + 0]), sh.x),
                   fmaf(ss.y, relu_f(acc2[mti][4 * g + 1]), sh.y));
        wv.y = pk2(fmaf(ss.z, relu_f(acc2[mti][4 * g + 2]), sh.z),
                   fmaf(ss.w, relu_f(acc2[mti][4 * g + 3]), sh.w));
        *(uint2*)(ldsb + pix * 80 + (8 * g + 4 * kh) * 2) = wv;
      }
    }
    __syncthreads();

    // --- d3: 32->16 as MFMA 16x16x32 (A=activations), then bn3 + in-lane pool
    const bf16x8 b3 = *(const bf16x8*)(PH + H_S1D3 + lr * 32 + cb * 8);
    const float bias3v = d3b[lr];
    const float sc3v = P[SC_S1BN3 + lr], sh3v = P[SC_S1BN3 + 16 + lr];
    f32x4 acc3[4];
    #pragma unroll
    for (int mt = 0; mt < 4; ++mt) {
      acc3[mt][0] = bias3v; acc3[mt][1] = bias3v; acc3[mt][2] = bias3v; acc3[mt][3] = bias3v;
      const bf16x8 a3 = *(const bf16x8*)(ldsb + (w * 64 + mt * 16 + lr) * 80 + cb * 16);
      acc3[mt] = __builtin_amdgcn_mfma_f32_16x16x32_bf16(a3, b3, acc3[mt], 0, 0, 0);
    }
    #pragma unroll
    for (int mtp = 0; mtp < 2; ++mtp) {
      float o0[4], o1[4];
      #pragma unroll
      for (int r = 0; r < 4; ++r) {
        o0[r] = fmaf(sc3v, relu_f(acc3[2 * mtp][r]), sh3v);
        o1[r] = fmaf(sc3v, relu_f(acc3[2 * mtp + 1][r]), sh3v);
      }
      #pragma unroll
      for (int rp = 0; rp < 2; ++rp) {
        const float m = fmaxf(fmaxf(o0[2 * rp], o0[2 * rp + 1]),
                              fmaxf(o1[2 * rp], o1[2 * rp + 1]));
        poolf[lr * 68 + (w * 2 + mtp) * 8 + cb * 2 + rp] = m;
      }
    }
  } else {
    // inactive: out = xc; pool via LDS f32 view
    float* ldsf = (float*)ldsb;  // [256][20] = 20480 B
    {
      float* pw = &ldsf[t * 20];
      #pragma unroll
      for (int c = 0; c < 16; ++c) pw[c] = xc[c];
    }
    __syncthreads();
    {
      const int pp = t & 63, cg = t >> 6;
      const int py = pp >> 3, px = pp & 7;
      const float* r0 = &ldsf[((2 * py) * 16 + 2 * px) * 20 + cg * 4];
      const float* r2 = &ldsf[((2 * py + 1) * 16 + 2 * px) * 20 + cg * 4];
      const float4 v0 = *(const float4*)(r0);
      const float4 v1 = *(const float4*)(r0 + 20);
      const float4 v2 = *(const float4*)(r2);
      const float4 v3 = *(const float4*)(r2 + 20);
      poolf[(cg * 4 + 0) * 68 + py * 8 + px] = fmaxf(fmaxf(v0.x, v1.x), fmaxf(v2.x, v3.x));
      poolf[(cg * 4 + 1) * 68 + py * 8 + px] = fmaxf(fmaxf(v0.y, v1.y), fmaxf(v2.y, v3.y));
      poolf[(cg * 4 + 2) * 68 + py * 8 + px] = fmaxf(fmaxf(v0.z, v1.z), fmaxf(v2.z, v3.z));
      poolf[(cg * 4 + 3) * 68 + py * 8 + px] = fmaxf(fmaxf(v0.w, v1.w), fmaxf(v2.w, v3.w));
    }
  }

  __syncthreads();
  // --- coalesced bf16 store: [16 ch][8 y] threads, 8 px packed as uint4
  if (t < 128) {
    const int ch = t >> 3, yy = t & 7;
    const float* pr = poolf + ch * 68 + yy * 8;
    uint4 v;
    v.x = pk2(pr[0], pr[1]); v.y = pk2(pr[2], pr[3]);
    v.z = pk2(pr[4], pr[5]); v.w = pk2(pr[6], pr[7]);
    unsigned short* dst = x1p
        + ((((size_t)n * 16 + (by >> 1)) * 16 + (bx >> 1)) * 16 + ch) * 256
        + (size_t)((by & 1) * 8 + yy) * 16 + (bx & 1) * 8;
    *(uint4*)dst = v;
  }
}

// ---------------- stage 2: 256x256, 16 -> 8 ch, blocks 16x16 ----------------
// LDS: halo tile bf16 [18][18][24 ch-pad] (48 B/px) 15,552 B; g2 flat
// [256][48 B]; pool staging f32 [8 ch][68 w] at byte 12288.
// Active test from stage1's pre-aggregated msum; x1p read as bf16.
__global__ __launch_bounds__(256, 5) void stage2_kernel(
    const float* __restrict__ msum,
    const float* __restrict__ cbv, const float* __restrict__ d1b,
    const float* __restrict__ d2b, const float* __restrict__ d3b,
    const float* __restrict__ P, const unsigned short* __restrict__ x1p,
    float* __restrict__ x2) {
  __shared__ __align__(16) unsigned char ldsb2[15552];

  const int t = threadIdx.x;
  const int ty = t >> 4, tx = t & 15;
  const int b = blockIdx.x;
  const int n = b >> 8;
  const int BY = (b >> 4) & 15, BX = b & 15;

  const bool active = msum[b] > 128.0f;  // b == n*256 + BY*16 + BX

  // load x1 (16 ch, bf16) from pre-blocked layout
  const unsigned short* xb = x1p + (size_t)b * 4096 + ty * 16 + tx;
  float xin[16];
  #pragma unroll
  for (int c = 0; c < 16; ++c) xin[c] = bf2f(xb[c * 256]);

  // conv1x1 16->8 + bias, relu, bn0 (VALU)
  const float* wc = P + WT_S2C;
  const float* sc0 = P + SC_S2BN0;
  float xc[8];
  {
    float a[8];
    #pragma unroll
    for (int o = 0; o < 8; ++o) a[o] = cbv[o];
    #pragma unroll
    for (int c = 0; c < 16; ++c) {
      const float v = xin[c];
      #pragma unroll
      for (int o = 0; o < 8; ++o) a[o] = fmaf(wc[c * 8 + o], v, a[o]);
    }
    #pragma unroll
    for (int o = 0; o < 8; ++o) xc[o] = fmaf(sc0[o], relu_f(a[o]), sc0[8 + o]);
  }

  float* const poolf = (float*)(ldsb2 + 12288);  // [8 ch][68 words]

  if (active) {
    const int w = t >> 6, lane = t & 63;
    const int lr = lane & 15, cb = lane >> 4;
    const int lane31 = lane & 31, kh = lane >> 5;
    const unsigned short* PH = (const unsigned short*)(P + PH_F);

    // ring zero (68 px x 32 B = ch 0..15)
    if (t < 68) {
      int row, col;
      if (t < 18)      { row = 0;      col = t;      }
      else if (t < 36) { row = 17;     col = t - 18; }
      else if (t < 52) { row = t - 35; col = 0;      }
      else             { row = t - 51; col = 17;     }
      uint4* z = (uint4*)(ldsb2 + (row * 18 + col) * 48);
      const uint4 z4 = make_uint4(0u, 0u, 0u, 0u);
      z[0] = z4; z[1] = z4;
    }
    // xc (8 ch) -> interior bf16
    {
      unsigned int pk[4];
      #pragma unroll
      for (int i = 0; i < 4; ++i) pk[i] = pk2(xc[2 * i], xc[2 * i + 1]);
      *(uint4*)(ldsb2 + ((ty + 1) * 18 + (tx + 1)) * 48) = make_uint4(pk[0], pk[1], pk[2], pk[3]);
    }

    // d1: 8->16 as MFMA 32x32x16. A=weights [32co][16k] (co>=16,k>=8 zero);
    // B=xc (col=pixel, k=ci; kh=1 lanes zeroed — ci 8..15 don't exist).
    {
      const bf16x8 w1f = *(const bf16x8*)(PH + H_S2D1 + lane31 * 16 + kh * 8);
      f32x16 acc1[2];
      #pragma unroll
      for (int nt = 0; nt < 2; ++nt)
        #pragma unroll
        for (int g = 0; g < 2; ++g) {
          const float4 bb = *(const float4*)(d1b + 8 * g + 4 * kh);
          acc1[nt][4 * g + 0] = bb.x; acc1[nt][4 * g + 1] = bb.y;
          acc1[nt][4 * g + 2] = bb.z; acc1[nt][4 * g + 3] = bb.w;
        }
      #pragma unroll
      for (int nt = 0; nt < 2; ++nt) {
        #pragma unroll
        for (int g = 2; g < 4; ++g) {
          acc1[nt][4 * g + 0] = 0.f; acc1[nt][4 * g + 1] = 0.f;
          acc1[nt][4 * g + 2] = 0.f; acc1[nt][4 * g + 3] = 0.f;
        }
      }
      #pragma unroll
      for (int nt = 0; nt < 2; ++nt) {
        const int p = w * 64 + nt * 32 + lane31;
        bf16x8 xcf;
        if (kh == 0) xcf = *(const bf16x8*)(ldsb2 + (((p >> 4) + 1) * 18 + (p & 15) + 1) * 48);
        else         xcf = (bf16x8)(short)0;
        acc1[nt] = __builtin_amdgcn_mfma_f32_32x32x16_bf16(w1f, xcf, acc1[nt], 0, 0, 0);
      }
      // bn1 + pack -> g1 (co = e + 8g + 4kh, g<2 real -> ch 0..15)
      #pragma unroll
      for (int nt = 0; nt < 2; ++nt) {
        const int p = w * 64 + nt * 32 + lane31;
        const unsigned pbase = (((p >> 4) + 1) * 18 + (p & 15) + 1) * 48;
        #pragma unroll
        for (int g = 0; g < 2; ++g) {
          const float4 ss = *(const float4*)(P + SC_S2BN1 + 8 * g + 4 * kh);
          const float4 sh = *(const float4*)(P + SC_S2BN1 + 16 + 8 * g + 4 * kh);
          uint2 wv;
          wv.x = pk2(fmaf(ss.x, relu_f(acc1[nt][4 * g + 0]), sh.x),
                     fmaf(ss.y, relu_f(acc1[nt][4 * g + 1]), sh.y));
          wv.y = pk2(fmaf(ss.z, relu_f(acc1[nt][4 * g + 2]), sh.z),
                     fmaf(ss.w, relu_f(acc1[nt][4 * g + 3]), sh.w));
          *(uint2*)(ldsb2 + pbase + (8 * g + 4 * kh) * 2) = wv;
        }
      }
    }
    __syncthreads();

    // 3x3 as MFMA 16x16x32: 5 tap-pairs per K=32; lane's tap = 2p + (cb>>1)
    f32x4 acc2[4];
    {
      const float4 bb = *(const float4*)(d2b + cb * 4);
      #pragma unroll
      for (int nt = 0; nt < 4; ++nt) {
        acc2[nt][0] = bb.x; acc2[nt][1] = bb.y; acc2[nt][2] = bb.z; acc2[nt][3] = bb.w;
      }
    }
    #pragma clang loop unroll(disable)
    for (int p = 0; p < 5; ++p) {
      const bf16x8 bwp = *(const bf16x8*)(PH + H_S2D2 + (p * 16 + lr) * 32 + cb * 8);
      const int tp = (p < 4) ? (2 * p + (cb >> 1)) : 8;
      const int dy = (tp >= 6) ? 2 : ((tp >= 3) ? 1 : 0);
      const int dx = tp - dy * 3;
      #pragma unroll
      for (int nt = 0; nt < 4; ++nt) {
        const bf16x8 af = *(const bf16x8*)(ldsb2 + ((w * 4 + nt + dy) * 18 + lr + dx) * 48 + (cb & 1) * 16);
        acc2[nt] = __builtin_amdgcn_mfma_f32_16x16x32_bf16(bwp, af, acc2[nt], 0, 0, 0);
      }
    }
    __syncthreads();

    // bn2 + pack -> g2 flat [pix][48 B]
    {
      const float4 s2s = *(const float4*)(P + SC_S2BN2 + cb * 4);
      const float4 s2h = *(const float4*)(P + SC_S2BN2 + 16 + cb * 4);
      #pragma unroll
      for (int nt = 0; nt < 4; ++nt) {
        const int pix = w * 64 + nt * 16 + lr;
        const unsigned base = pix * 48 + cb * 8;
        uint2 wv;
        wv.x = pk2(fmaf(s2s.x, relu_f(acc2[nt][0]), s2h.x),
                   fmaf(s2s.y, relu_f(acc2[nt][1]), s2h.y));
        wv.y = pk2(fmaf(s2s.z, relu_f(acc2[nt][2]), s2h.z),
                   fmaf(s2s.w, relu_f(acc2[nt][3]), s2h.w));
        *(uint2*)(ldsb2 + base) = wv;
      }
    }
    __syncthreads();

    // d3: 16->8 as MFMA (K=16 zero-padded both sides)
    bf16x8 b3;
    if (cb < 2) b3 = *(const bf16x8*)(PH + H_S2D3 + lr * 16 + cb * 8);
    else        b3 = (bf16x8)(short)0;
    const float bias3v = (lr < 8) ? d3b[lr] : 0.f;
    const float sc3v = (lr < 8) ? P[SC_S2BN3 + lr] : 0.f;
    const float sh3v = (lr < 8) ? P[SC_S2BN3 + 8 + lr] : 0.f;
    f32x4 acc3[4];
    #pragma unroll
    for (int mt = 0; mt < 4; ++mt) {
      acc3[mt][0] = bias3v; acc3[mt][1] = bias3v; acc3[mt][2] = bias3v; acc3[mt][3] = bias3v;
      bf16x8 a3;
      if (cb < 2) a3 = *(const bf16x8*)(ldsb2 + (w * 64 + mt * 16 + lr) * 48 + cb * 16);
      else        a3 = (bf16x8)(short)0;
      acc3[mt] = __builtin_amdgcn_mfma_f32_16x16x32_bf16(a3, b3, acc3[mt], 0, 0, 0);
    }
    if (lr < 8) {
      #pragma unroll
      for (int mtp = 0; mtp < 2; ++mtp) {
        float o0[4], o1[4];
        #pragma unroll
        for (int r = 0; r < 4; ++r) {
          o0[r] = fmaf(sc3v, relu_f(acc3[2 * mtp][r]), sh3v);
          o1[r] = fmaf(sc3v, relu_f(acc3[2 * mtp + 1][r]), sh3v);
        }
        #pragma unroll
        for (int rp = 0; rp < 2; ++rp) {
          const float m = fmaxf(fmaxf(o0[2 * rp], o0[2 * rp + 1]),
                                fmaxf(o1[2 * rp], o1[2 * rp + 1]));
          poolf[lr * 68 + (w * 2 + mtp) * 8 + cb * 2 + rp] = m;
        }
      }
    }
  } else {
    float* ldsf = (float*)ldsb2;  // [256][12] = 12288 B
    {
      float* pw = &ldsf[t * 12];
      #pragma unroll
      for (int c = 0; c < 8; ++c) pw[c] = xc[c];
    }
    __syncthreads();
    if (t < 128) {
      const int pp = t & 63, cg = t >> 6;
      const int py = pp >> 3, px = pp & 7;
      const float* r0 = &ldsf[((2 * py) * 16 + 2 * px) * 12 + cg * 4];
      const float* r2 = &ldsf[((2 * py + 1) * 16 + 2 * px) * 12 + cg * 4];
      const float4 v0 = *(const float4*)(r0);
      const float4 v1 = *(const float4*)(r0 + 12);
      const float4 v2 = *(const float4*)(r2);
      const float4 v3 = *(const float4*)(r2 + 12);
      poolf[(cg * 4 + 0) * 68 + py * 8 + px] = fmaxf(fmaxf(v0.x, v1.x), fmaxf(v2.x, v3.x));
      poolf[(cg * 4 + 1) * 68 + py * 8 + px] = fmaxf(fmaxf(v0.y, v1.y), fmaxf(v2.y, v3.y));
      poolf[(cg * 4 + 2) * 68 + py * 8 + px] = fmaxf(fmaxf(v0.z, v1.z), fmaxf(v2.z, v3.z));
      poolf[(cg * 4 + 3) * 68 + py * 8 + px] = fmaxf(fmaxf(v0.w, v1.w), fmaxf(v2.w, v3.w));
    }
  }

  __syncthreads();
  // coalesced store: [8 ch][8 y][8 x] -> x2 NCHW (f32), uint4 per thread
  if (t < 128) {
    const int ch = t >> 4, idx = t & 15, yy = idx >> 1, h = idx & 1;
    const uint4 v = *(const uint4*)(poolf + ch * 68 + yy * 8 + h * 4);
    const size_t ob = ((size_t)(n * 8 + ch) * 128 + (BY * 8 + yy)) * 128 + BX * 8 + h * 4;
    *(uint4*)(x2 + ob) = v;
  }
}

// ---------------- FC (split-K x8, atomicAdd) + softmax ----------------
__global__ __launch_bounds__(256) void fc_kernel(const float* __restrict__ x2,
                                                 const float* __restrict__ fcw,
                                                 const float* __restrict__ fcb,
                                                 float* __restrict__ logits) {
  __shared__ float red[4];
  const int wg = blockIdx.x, t = threadIdx.x;
  const int sp = wg & 7, k = (wg >> 3) % 10, n = wg / 80;
  const float4* xa = (const float4*)(x2 + (size_t)n * 131072) + sp * 4096;
  const float4* wa = (const float4*)(fcw + (size_t)k * 131072) + sp * 4096;
  float s = 0.f;
  #pragma unroll 4
  for (int i = t; i < 4096; i += 256) {
    const float4 a = xa[i], b = wa[i];
    s = fmaf(a.x, b.x, fmaf(a.y, b.y, fmaf(a.z, b.z, fmaf(a.w, b.w, s))));
  }
  #pragma unroll
  for (int off = 32; off > 0; off >>= 1) s += __shfl_down(s, off, 64);
  if ((t & 63) == 0) red[t >> 6] = s;
  __syncthreads();
  if (t == 0) {
    float tot = red[0] + red[1] + red[2] + red[3];
    if (sp == 0) tot += fcb[k];
    atomicAdd(&logits[n * 10 + k], tot);
  }
}

__global__ void softmax_kernel(const float* __restrict__ logits, float* __restrict__ out) {
  const int t = threadIdx.x;
  if (t < 16) {
    float l[10], mx = -1e30f;
    #pragma unroll
    for (int k = 0; k < 10; ++k) { l[k] = logits[t * 10 + k]; mx = fmaxf(mx, l[k]); }
    float sum = 0.f;
    #pragma unroll
    for (int k = 0; k < 10; ++k) { l[k] = expf(l[k] - mx); sum += l[k]; }
    const float inv = 1.f / sum;
    #pragma unroll
    for (int k = 0; k < 10; ++k) out[t * 10 + k] = l[k] * inv;
  }
}

extern "C" void kernel_launch(void* const* d_in, const int* in_sizes, int n_in,
                              void* d_out, int out_size, void* d_ws, size_t ws_size,
                              hipStream_t stream) {
  const float* x      = (const float*)d_in[0];
  const float* mask   = (const float*)d_in[1];
  const float* s1_cw  = (const float*)d_in[2];
  const float* s1_cb  = (const float*)d_in[3];
  const float* s1_bn0 = (const float*)d_in[4];
  const float* s1_d1w = (const float*)d_in[5];
  const float* s1_d1b = (const float*)d_in[6];
  const float* s1_bn1 = (const float*)d_in[7];
  const float* s1_d2w = (const float*)d_in[8];
  const float* s1_d2b = (const float*)d_in[9];
  const float* s1_bn2 = (const float*)d_in[10];
  const float* s1_d3w = (const float*)d_in[11];
  const float* s1_d3b = (const float*)d_in[12];
  const float* s1_bn3 = (const float*)d_in[13];
  const float* s2_cw  = (const float*)d_in[14];
  const float* s2_cb  = (const float*)d_in[15];
  const float* s2_bn0 = (const float*)d_in[16];
  const float* s2_d1w = (const float*)d_in[17];
  const float* s2_d1b = (const float*)d_in[18];
  const float* s2_bn1 = (const float*)d_in[19];
  const float* s2_d2w = (const float*)d_in[20];
  const float* s2_d2b = (const float*)d_in[21];
  const float* s2_bn2 = (const float*)d_in[22];
  const float* s2_d3w = (const float*)d_in[23];
  const float* s2_d3b = (const float*)d_in[24];
  const float* s2_bn3 = (const float*)d_in[25];
  const float* fc_w   = (const float*)d_in[26];
  const float* fc_b   = (const float*)d_in[27];

  float* ws  = (float*)d_ws;
  unsigned short* x1p = (unsigned short*)d_ws;  // bf16 region, 16.7M ush
  float* x2  = ws + X2_OFF;
  float* lg  = ws + LG_OFF;
  float* ms  = ws + MS_OFF;
  float* P   = ws + P_OFF;

  prep_kernel<<<32, 256, 0, stream>>>(s1_cw, s1_d1w, s1_d2w, s1_d3w,
                                      s2_cw, s2_d1w, s2_d2w, s2_d3w,
                                      s1_bn0, s1_bn1, s1_bn2, s1_bn3,
                                      s2_bn0, s2_bn1, s2_bn2, s2_bn3, P, lg, ms);
  stage1_kernel<<<16 * 32 * 32, 256, 0, stream>>>(x, mask, s1_cb, s1_d1b, s1_d2b, s1_d3b, P, x1p, ms);
  stage2_kernel<<<16 * 16 * 16, 256, 0, stream>>>(ms, s2_cb, s2_d1b, s2_d2b, s2_d3b, P, x1p, x2);
  fc_kernel<<<1280, 256, 0, stream>>>(x2, fc_w, fc_b, lg);
  softmax_kernel<<<1, 64, 0, stream>>>(lg, (float*)d_out);
}